// Round 6
// baseline (779.366 us; speedup 1.0000x reference)
//
#include <hip/hip_runtime.h>
#include <math.h>

#define KC 512
#define DD 128

typedef __attribute__((ext_vector_type(8))) short short8;
typedef __attribute__((ext_vector_type(4))) short short4v;
typedef __attribute__((ext_vector_type(4))) float f32x4;

#define MFMA(a, b, c) __builtin_amdgcn_mfma_f32_16x16x32_bf16(a, b, c, 0, 0, 0)

__device__ __forceinline__ short f2bf(float f) {
  unsigned u = __float_as_uint(f);
  u = (u + 0x7FFFu + ((u >> 16) & 1u)) >> 16;
  return (short)u;
}
__device__ __forceinline__ float bf2f(short s) {
  return __uint_as_float(((unsigned)(unsigned short)s) << 16);
}

// ============================================================================
// weight permutation kernels (A-fragment order)
// ============================================================================
__global__ __launch_bounds__(256) void k_perm_c2(const float* __restrict__ w,
                                                 short* __restrict__ dst) {
  int e = blockIdx.x * 256 + threadIdx.x;  // < 131072
  int j = e & 7, l = (e >> 3) & 63, ot = (e >> 9) & 7, kc = e >> 12;
  int o = ot * 16 + (l & 15), g = l >> 4;
  int tap = kc >> 1, ci = (kc & 1) * 32 + 8 * g + j;
  dst[e] = f2bf(w[(o * 64 + ci) * 16 + tap]);
}

__global__ __launch_bounds__(256) void k_perm_r3(const float* __restrict__ w,
                                                 short* __restrict__ dst) {
  int e = blockIdx.x * 256 + threadIdx.x;  // < 36864
  int j = e & 7, l = (e >> 3) & 63, ot = (e >> 9) & 1, kc = e >> 10;
  int o = ot * 16 + (l & 15), g = l >> 4;
  int tap = kc >> 2, ci = (kc & 3) * 32 + 8 * g + j;
  dst[e] = f2bf(w[(o * 128 + ci) * 9 + tap]);
}

__global__ __launch_bounds__(256) void k_perm_r1(const float* __restrict__ w,
                                                 short* __restrict__ dst) {
  int e = blockIdx.x * 256 + threadIdx.x;  // < 4096
  int j = e & 7, l = (e >> 3) & 63, ot = e >> 9;
  int o = ot * 16 + (l & 15), g = l >> 4;
  int ci = 8 * g + j;
  dst[e] = f2bf(w[o * 32 + ci]);
}

__global__ __launch_bounds__(256) void k_perm_pre(const float* __restrict__ w,
                                                  short* __restrict__ dst) {
  int e = blockIdx.x * 256 + threadIdx.x;  // < 16384
  int j = e & 7, l = (e >> 3) & 63, ot = (e >> 9) & 7, kc = e >> 12;
  int o = ot * 16 + (l & 15), g = l >> 4;
  int ci = kc * 32 + 8 * g + j;
  dst[e] = f2bf(w[o * 128 + ci]);
}

__global__ __launch_bounds__(256) void k_perm_t1(const float* __restrict__ w,
                                                 short* __restrict__ dst) {
  int e = blockIdx.x * 256 + threadIdx.x;  // < 131072
  int j = e & 7, l = (e >> 3) & 63, ot = (e >> 9) & 3, kc = (e >> 11) & 15,
      pp = e >> 15;
  int pyr = pp >> 1, pxr = pp & 1;
  int o = ot * 16 + (l & 15), g = l >> 4;
  int tt = kc >> 2, dy = tt >> 1, dx = tt & 1;
  int ky = (1 - pyr) + 2 * dy, kx = (1 - pxr) + 2 * dx;
  int ci = (kc & 3) * 32 + 8 * g + j;
  dst[e] = f2bf(w[(ci * 64 + o) * 16 + ky * 4 + kx]);
}

// ============================================================================
// Ecat permute: emb[512][128] f32 -> Ecat bf16 in A-fragment order over K=384:
// K [0:256) = eh (duplicated), [256:384) = el. e=((kc*32+ot)*64+l)*8+j
// grid 768 x 256 (196608 elems)
// ============================================================================
__global__ __launch_bounds__(256) void k_perm_E(const float* __restrict__ emb,
                                                short* __restrict__ dst) {
  int e = blockIdx.x * 256 + threadIdx.x;
  int j = e & 7, l = (e >> 3) & 63, ot = (e >> 9) & 31, kc = e >> 14;
  int c = ot * 16 + (l & 15);
  int k = kc * 32 + 8 * (l >> 4) + j;
  float v = emb[c * DD + (k & 127)];
  short hi = f2bf(v);
  dst[e] = (k < 256) ? hi : f2bf(v - bf2f(hi));
}

// ============================================================================
// emb norms (exact f32)
// ============================================================================
__global__ __launch_bounds__(64) void k_embnorm(const float* __restrict__ emb,
                                                float* __restrict__ en) {
  int c = blockIdx.x, l = threadIdx.x;
  float a = emb[c * DD + l], b = emb[c * DD + 64 + l];
  float s = a * a + b * b;
#pragma unroll
  for (int m = 32; m >= 1; m >>= 1) s += __shfl_xor(s, m);
  if (l == 0) en[c] = s;
}

// ============================================================================
// border zero: A1[32,130,130,64] and XrP[32,66,66,128] padding rings only
// (replaces 104 MB of full-buffer memset with 8.4 MB of border writes).
// grid 256 = 32 b x 8 slices, 256 thr.
// ============================================================================
__global__ __launch_bounds__(256) void k_border(short* __restrict__ A1,
                                                short* __restrict__ XrP) {
  int blk = blockIdx.x;
  int b = blk >> 3;
  int tid = ((blk & 7) << 8) + threadIdx.x;  // 0..2047
  short8 z8 = {};
  long baseA = (long)b * 1081600;  // 130*130*64
  // A1 top/bottom rows: 2 x 1040 short8
  for (int e = tid; e < 2080; e += 2048) {
    int r = e >= 1040;
    int rem = r ? e - 1040 : e;
    *(short8*)(A1 + baseA + (r ? 129L * 130 * 64 : 0) + rem * 8) = z8;
  }
  // A1 left/right cols, rows 1..128: 2048 short8 (exactly one per tid)
  {
    int c = tid >> 10, rem = tid & 1023;
    int row = 1 + (rem >> 3), s8 = rem & 7;
    *(short8*)(A1 + baseA + (row * 130L + (c ? 129 : 0)) * 64 + s8 * 8) = z8;
  }
  long baseX = (long)b * 557568;  // 66*66*128
  // XrP top/bottom rows: 2 x 1056 short8
  for (int e = tid; e < 2112; e += 2048) {
    int r = e >= 1056;
    int rem = r ? e - 1056 : e;
    *(short8*)(XrP + baseX + (r ? 65L * 66 * 128 : 0) + rem * 8) = z8;
  }
  // XrP left/right cols, rows 1..64: 2048 short8
  {
    int c = tid >> 10, rem = tid & 1023;
    int row = 1 + (rem >> 4), s8 = rem & 15;
    *(short8*)(XrP + baseX + (row * 66L + (c ? 65 : 0)) * 128 + s8 * 8) = z8;
  }
}

// ============================================================================
// conv1: x[32,1,256,256] f32 -> A1[32,130,130,64] bf16 relu (padded, ch-last)
// grid 4096 = 32 b x 128 y
// ============================================================================
__global__ __launch_bounds__(256) void k_conv1(const float* __restrict__ x,
    const float* __restrict__ w, const float* __restrict__ bias,
    short* __restrict__ A1) {
  __shared__ float sXp[4 * 260];
  __shared__ float sWt[16 * 64];
  int blk = blockIdx.x;
  int y = blk & 127, b = blk >> 7;
  int t = threadIdx.x;
  for (int e = t; e < 1024; e += 256) sWt[e] = w[(e & 63) * 16 + (e >> 6)];
  if (t < 4) {
    sXp[t * 260] = 0.f;
    sXp[t * 260 + 257] = 0.f;
    sXp[t * 260 + 258] = 0.f;
    sXp[t * 260 + 259] = 0.f;
  }
  for (int e = t; e < 1024; e += 256) {
    int r = e >> 8, col = e & 255;
    int giy = 2 * y - 1 + r;
    float v = 0.f;
    if ((unsigned)giy < 256u) v = x[(b * 256 + giy) * 256 + col];
    sXp[r * 260 + col + 1] = v;
  }
  __syncthreads();
  int og = t >> 6, l = t & 63, o0 = og * 16;
  float acc0[16], acc1[16];
#pragma unroll
  for (int oo = 0; oo < 16; ++oo) { acc0[oo] = 0.f; acc1[oo] = 0.f; }
  int xA = 2 * l, xB = 2 * l + 128;
#pragma unroll
  for (int ky = 0; ky < 4; ++ky) {
#pragma unroll
    for (int kx = 0; kx < 4; ++kx) {
      float a0 = sXp[ky * 260 + xA + kx];
      float a1 = sXp[ky * 260 + xB + kx];
      const float* wrow = &sWt[(ky * 4 + kx) * 64 + o0];
#pragma unroll
      for (int oo = 0; oo < 16; ++oo) {
        float wv = wrow[oo];
        acc0[oo] = fmaf(a0, wv, acc0[oo]);
        acc1[oo] = fmaf(a1, wv, acc1[oo]);
      }
    }
  }
  long base0 = (((long)(b * 130 + y + 1)) * 130 + l + 1) * 64 + o0;
  long base1 = base0 + 64 * 64;
  short8 s0a, s0b, s1a, s1b;
#pragma unroll
  for (int oo = 0; oo < 8; ++oo) {
    s0a[oo] = f2bf(fmaxf(acc0[oo] + bias[o0 + oo], 0.f));
    s0b[oo] = f2bf(fmaxf(acc0[oo + 8] + bias[o0 + oo + 8], 0.f));
    s1a[oo] = f2bf(fmaxf(acc1[oo] + bias[o0 + oo], 0.f));
    s1b[oo] = f2bf(fmaxf(acc1[oo + 8] + bias[o0 + oo + 8], 0.f));
  }
  *(short8*)(A1 + base0) = s0a;
  *(short8*)(A1 + base0 + 8) = s0b;
  *(short8*)(A1 + base1) = s1a;
  *(short8*)(A1 + base1 + 8) = s1b;
}

// ============================================================================
// conv2 MFMA v2 (LDS-staged): A1[130,130,64] bf16 -> relu -> Xf[64,64,128] f32
// + XrP[66,66,128] bf16. Block = 8x8 out-px, input tile 18x18x64 staged into
// LDS once (whole K-loop reuses it). Pixel stride 136 B -> conflict-free
// ds_read_b128 (bank = 2*pix+4g mod 32: 8 quads x 2-way).
// grid 2048 = 32 b x 8 by x 8 bx
// ============================================================================
__global__ __launch_bounds__(256) void k_conv2m(const short* __restrict__ A1,
    const short* __restrict__ wA, const float* __restrict__ bias,
    float* __restrict__ Xf, short* __restrict__ XrP) {
  __shared__ short sX[22032];  // 324 px * 68 shorts (136 B) = 44,064 B
  int blk = blockIdx.x;
  int bx = blk & 7, by = (blk >> 3) & 7, b = blk >> 6;
  int t = threadIdx.x;
  int R0 = by * 16, C0 = bx * 16;
  for (int q = t; q < 2592; q += 256) {
    int p = q >> 3, seg = q & 7;
    int iy = p / 18, ix = p - iy * 18;
    short8 v = *(const short8*)(A1 +
        (((long)b * 130 + R0 + iy) * 130 + C0 + ix) * 64 + seg * 8);
    *(short8*)((char*)sX + p * 136 + seg * 16) = v;
  }
  __syncthreads();
  int w = t >> 6, l = t & 63, lr = l & 15, g = l >> 4;
  int Bb[4];
#pragma unroll
  for (int pt = 0; pt < 4; ++pt) {
    int p = pt * 16 + lr;
    int lp = 2 * (p >> 3) * 18 + 2 * (p & 7);
    Bb[pt] = lp * 136 + g * 16;
  }
  const short* pA0 = wA + (2 * w * 64 + l) * 8;
  const short* pA1 = pA0 + 512;
  f32x4 acc[2][4] = {};
  short8 a0 = *(const short8*)pA0;
  short8 a1 = *(const short8*)pA1;
  short8 bv[4];
#pragma unroll
  for (int i = 0; i < 4; ++i)
    bv[i] = *(const short8*)((const char*)sX + Bb[i]);
  for (int kc = 0; kc < 31; ++kc) {
    int nk = kc + 1;
    int tap = nk >> 1;
    int off = ((tap >> 2) * 18 + (tap & 3)) * 136 + (nk & 1) * 64;
    short8 na0 = *(const short8*)(pA0 + nk * 4096);
    short8 na1 = *(const short8*)(pA1 + nk * 4096);
    short8 nb[4];
#pragma unroll
    for (int i = 0; i < 4; ++i)
      nb[i] = *(const short8*)((const char*)sX + Bb[i] + off);
#pragma unroll
    for (int i = 0; i < 4; ++i) {
      acc[0][i] = MFMA(a0, bv[i], acc[0][i]);
      acc[1][i] = MFMA(a1, bv[i], acc[1][i]);
    }
    a0 = na0; a1 = na1;
#pragma unroll
    for (int i = 0; i < 4; ++i) bv[i] = nb[i];
  }
#pragma unroll
  for (int i = 0; i < 4; ++i) {
    acc[0][i] = MFMA(a0, bv[i], acc[0][i]);
    acc[1][i] = MFMA(a1, bv[i], acc[1][i]);
  }
#pragma unroll
  for (int oi = 0; oi < 2; ++oi) {
    int o0 = (2 * w + oi) * 16 + 4 * g;
#pragma unroll
    for (int pt = 0; pt < 4; ++pt) {
      int p = pt * 16 + lr;
      int y = by * 8 + (p >> 3), x = bx * 8 + (p & 7);
      f32x4 nv; short4v sv;
#pragma unroll
      for (int r = 0; r < 4; ++r) {
        float v = fmaxf(acc[oi][pt][r] + bias[o0 + r], 0.f);
        nv[r] = v; sv[r] = f2bf(v);
      }
      *(f32x4*)(Xf + ((b * 64 + y) * 64 + x) * 128 + o0) = nv;
      *(short4v*)(XrP + ((b * 66 + y + 1) * 66 + x + 1) * 128 + o0) = sv;
    }
  }
}

// ============================================================================
// res3 MFMA v2 (LDS-staged): XrP[66,66,128] -> Hr[64,64,32] bf16 relu
// Block = 8x16 out-px; input tile 10x18x128 staged into LDS with XOR swizzle
// (inner ^ ((pix&7)<<4)) -> conflict-free ds_read_b128. Wave w owns rows
// 2w,2w+1; 4 MFMA / 2 ds_read per K-step, 36 steps.
// grid 1024 = 32 b x 8 yt x 4 tx
// ============================================================================
__global__ __launch_bounds__(256) void k_res3m(const short* __restrict__ XrP,
    const short* __restrict__ wA, short* __restrict__ Hr) {
  __shared__ short sX[23040];  // 180 px * 128 shorts (256 B swizzled) = 46,080 B
  int blk = blockIdx.x;
  int tx = blk & 3, yt = (blk >> 2) & 7, b = blk >> 5;
  int t = threadIdx.x;
  int r0 = yt * 8, c0 = tx * 16;
  for (int q = t; q < 2880; q += 256) {
    int p = q >> 4, seg = q & 15;
    int iy = p / 18, ix = p - iy * 18;
    short8 v = *(const short8*)(XrP +
        (((long)b * 66 + r0 + iy) * 66 + c0 + ix) * 128 + seg * 8);
    *(short8*)((char*)sX + p * 256 + ((seg * 16) ^ ((p & 7) << 4))) = v;
  }
  __syncthreads();
  int w = t >> 6, l = t & 63, lr = l & 15, g = l >> 4;
  const short* pA0 = wA + l * 8;
  const short* pA1 = pA0 + 512;
  f32x4 acc[2][2] = {};
  short8 a0 = *(const short8*)pA0;
  short8 a1 = *(const short8*)pA1;
  short8 bv[2];
#pragma unroll
  for (int j = 0; j < 2; ++j) {
    int lp = (2 * w + j) * 18 + lr;
    bv[j] = *(const short8*)((const char*)sX + lp * 256 +
                             ((g * 16) ^ ((lp & 7) << 4)));
  }
  for (int kc = 0; kc < 35; ++kc) {
    int nk = kc + 1;
    int tap = nk >> 2;
    int ky = tap / 3, kx = tap - ky * 3;
    int inner = g * 16 + (nk & 3) * 64;
    short8 na0 = *(const short8*)(pA0 + nk * 1024);
    short8 na1 = *(const short8*)(pA1 + nk * 1024);
    short8 nb[2];
#pragma unroll
    for (int j = 0; j < 2; ++j) {
      int lp = (2 * w + j + ky) * 18 + lr + kx;
      nb[j] = *(const short8*)((const char*)sX + lp * 256 +
                               (inner ^ ((lp & 7) << 4)));
    }
#pragma unroll
    for (int j = 0; j < 2; ++j) {
      acc[0][j] = MFMA(a0, bv[j], acc[0][j]);
      acc[1][j] = MFMA(a1, bv[j], acc[1][j]);
    }
    a0 = na0; a1 = na1;
    bv[0] = nb[0]; bv[1] = nb[1];
  }
#pragma unroll
  for (int j = 0; j < 2; ++j) {
    acc[0][j] = MFMA(a0, bv[j], acc[0][j]);
    acc[1][j] = MFMA(a1, bv[j], acc[1][j]);
  }
#pragma unroll
  for (int oi = 0; oi < 2; ++oi) {
    int o0 = oi * 16 + 4 * g;
#pragma unroll
    for (int j = 0; j < 2; ++j) {
      int y = r0 + 2 * w + j, x = c0 + lr;
      short4v sv;
#pragma unroll
      for (int r = 0; r < 4; ++r) sv[r] = f2bf(fmaxf(acc[oi][j][r], 0.f));
      *(short4v*)(Hr + ((b * 64 + y) * 64 + x) * 32 + o0) = sv;
    }
  }
}

// ============================================================================
// res1+add MFMA: Hr[64,64,32] -> Xf += conv1x1 ; XrP = relu(Xf) bf16
// ============================================================================
__global__ __launch_bounds__(256) void k_res1addm(const short* __restrict__ Hr,
    const short* __restrict__ wA, float* __restrict__ Xf,
    short* __restrict__ XrP) {
  int blk = blockIdx.x;
  int bx = blk & 7, by = (blk >> 3) & 7, b = blk >> 6;
  int t = threadIdx.x, w = t >> 6, l = t & 63, lr = l & 15, g = l >> 4;
  f32x4 acc[2][4] = {};
  short8 a0 = *(const short8*)(wA + (2 * w * 64 + l) * 8);
  short8 a1 = *(const short8*)(wA + ((2 * w + 1) * 64 + l) * 8);
#pragma unroll
  for (int i = 0; i < 4; ++i) {
    int p = i * 16 + lr;
    int y = by * 8 + (p >> 3), x = bx * 8 + (p & 7);
    short8 bv = *(const short8*)(Hr + ((b * 64 + y) * 64 + x) * 32 + 8 * g);
    acc[0][i] = MFMA(a0, bv, acc[0][i]);
    acc[1][i] = MFMA(a1, bv, acc[1][i]);
  }
#pragma unroll
  for (int oi = 0; oi < 2; ++oi) {
    int o0 = (2 * w + oi) * 16 + 4 * g;
#pragma unroll
    for (int i = 0; i < 4; ++i) {
      int p = i * 16 + lr;
      int y = by * 8 + (p >> 3), x = bx * 8 + (p & 7);
      float* xp = Xf + ((b * 64 + y) * 64 + x) * 128 + o0;
      f32x4 old = *(f32x4*)xp;
      f32x4 nv; short4v sv;
#pragma unroll
      for (int r = 0; r < 4; ++r) {
        nv[r] = old[r] + acc[oi][i][r];
        sv[r] = f2bf(fmaxf(nv[r], 0.f));
      }
      *(f32x4*)xp = nv;
      *(short4v*)(XrP + ((b * 66 + y + 1) * 66 + x + 1) * 128 + o0) = sv;
    }
  }
}

// ============================================================================
// pre 1x1 MFMA: XrP[66,66,128] -> Zcat[pix][256] bf16 = [zhi(128) | zlo(128)]
// grid 2048 (8x8 pixels).
// ============================================================================
__global__ __launch_bounds__(256) void k_prem(const short* __restrict__ XrP,
    const short* __restrict__ wA, const float* __restrict__ bias,
    short* __restrict__ Zc) {
  int blk = blockIdx.x;
  int bx = blk & 7, by = (blk >> 3) & 7, b = blk >> 6;
  int t = threadIdx.x, w = t >> 6, l = t & 63, lr = l & 15, g = l >> 4;
  const short* pB[4];
#pragma unroll
  for (int pt = 0; pt < 4; ++pt) {
    int p = pt * 16 + lr;
    int y = by * 8 + (p >> 3), x = bx * 8 + (p & 7);
    pB[pt] = XrP + ((b * 66 + y + 1) * 66 + x + 1) * 128 + 8 * g;
  }
  const short* pA0 = wA + (2 * w * 64 + l) * 8;
  const short* pA1 = pA0 + 512;
  f32x4 acc[2][4] = {};
  short8 a0 = *(const short8*)pA0;
  short8 a1 = *(const short8*)pA1;
  short8 bv[4];
#pragma unroll
  for (int i = 0; i < 4; ++i) bv[i] = *(const short8*)pB[i];
  for (int kc = 0; kc < 3; ++kc) {
    int nk = kc + 1;
    int off = nk * 32;
    short8 na0 = *(const short8*)(pA0 + nk * 4096);
    short8 na1 = *(const short8*)(pA1 + nk * 4096);
    short8 nb[4];
#pragma unroll
    for (int i = 0; i < 4; ++i) nb[i] = *(const short8*)(pB[i] + off);
#pragma unroll
    for (int i = 0; i < 4; ++i) {
      acc[0][i] = MFMA(a0, bv[i], acc[0][i]);
      acc[1][i] = MFMA(a1, bv[i], acc[1][i]);
    }
    a0 = na0; a1 = na1;
#pragma unroll
    for (int i = 0; i < 4; ++i) bv[i] = nb[i];
  }
#pragma unroll
  for (int i = 0; i < 4; ++i) {
    acc[0][i] = MFMA(a0, bv[i], acc[0][i]);
    acc[1][i] = MFMA(a1, bv[i], acc[1][i]);
  }
#pragma unroll
  for (int oi = 0; oi < 2; ++oi) {
    int o0 = (2 * w + oi) * 16 + 4 * g;
#pragma unroll
    for (int pt = 0; pt < 4; ++pt) {
      int p = pt * 16 + lr;
      int y = by * 8 + (p >> 3), x = bx * 8 + (p & 7);
      long pix = (long)(b * 64 + y) * 64 + x;
      short4v hv, lv;
#pragma unroll
      for (int r = 0; r < 4; ++r) {
        float v = acc[oi][pt][r] + bias[o0 + r];
        short hi = f2bf(v);
        hv[r] = hi;
        lv[r] = f2bf(v - bf2f(hi));
      }
      *(short4v*)(Zc + pix * 256 + o0) = hv;
      *(short4v*)(Zc + pix * 256 + 128 + o0) = lv;
    }
  }
}

// ============================================================================
// VQ MFMA v6 (arithmetic-intensity): Block = 128 px x 512 codes (grid 1024).
// Halves total Ecat L2 stream (each block's 393 KB E-read now covers 128 px).
// Z tile 64 KB LDS (XOR swizzle), shared by 4 waves. Wave w: codes
// [w*128,(w+1)*128) as 2 chunks of 64; acc[4 code-tiles][8 px-tiles] = 128
// regs; per K-step 4 A-loads + 8 B ds_reads + 32 MFMA. Fused argmin + hist +
// loss + gather.
// ============================================================================
__global__ __launch_bounds__(256) void k_vqm6(const short* __restrict__ Zc,
    const short* __restrict__ Ec, const float* __restrict__ en,
    const float* __restrict__ emb, int* __restrict__ counts,
    float* __restrict__ partials, float* __restrict__ Q,
    short* __restrict__ QrP) {
  __shared__ short sZ[32768];  // 128 px * 256 sh, swizzled = 64 KB
  __shared__ float sV[4][128];
  __shared__ int sC[4][128];
  __shared__ float sZn[128];
  __shared__ int sIdx[128];
  __shared__ int sHist[KC];
  int blk = blockIdx.x;
  long pix0 = (long)blk * 128;
  int t = threadIdx.x, w = t >> 6, l = t & 63, c16 = l & 15, g = l >> 4;
  for (int e = t; e < KC; e += 256) sHist[e] = 0;

  // stage Z tile: swizzle inner-byte ^ ((pix&7)<<4)
  for (int q = t; q < 4096; q += 256) {
    int p = q >> 5, seg = q & 31;
    short8 v = *(const short8*)(Zc + (pix0 + p) * 256 + seg * 8);
    *(short8*)((char*)sZ + p * 512 + ((seg * 16) ^ ((p & 7) << 4))) = v;
  }
  __syncthreads();

  // ||z||^2 per pixel from LDS: 2 threads/pixel, each 64 dims
  {
    int pz = t >> 1, sg = t & 1;
    const char* zb = (const char*)sZ + pz * 512;
    int swp = (pz & 7) << 4;
    float s = 0.f;
#pragma unroll
    for (int qq = 0; qq < 8; ++qq) {
      int ih = sg * 128 + 16 * qq;  // zh inner byte
      short8 h8 = *(const short8*)(zb + (ih ^ swp));
      short8 l8 = *(const short8*)(zb + ((ih + 256) ^ swp));
#pragma unroll
      for (int j = 0; j < 8; ++j) {
        float zv = bf2f(h8[j]) + bf2f(l8[j]);
        s = fmaf(zv, zv, s);
      }
    }
    s += __shfl_xor(s, 1);
    if (sg == 0) sZn[pz] = s;
  }

  // GEMM: 2 chunks of 64 codes; 12 K-steps of 32; 8 pixel-tiles.
  int sw = (c16 & 7) << 4;
  int zrow = c16 * 512;
  float bvv[8];
  int bcc[8];
#pragma unroll
  for (int pt = 0; pt < 8; ++pt) { bvv[pt] = 3.4e38f; bcc[pt] = 0; }
  const short* pE = Ec + (w * 8) * 512 + l * 8;
  for (int cc = 0; cc < 2; ++cc) {
    const short* pA = pE + cc * 2048;
    f32x4 acc[4][8] = {};
#pragma unroll
    for (int kc = 0; kc < 12; ++kc) {
      int koff = kc < 8 ? kc : kc - 8;
      int inn = ((koff * 64 + g * 16) ^ sw);
      const char* zb = (const char*)sZ + zrow + inn;
      short8 a0 = *(const short8*)(pA + kc * 16384);
      short8 a1 = *(const short8*)(pA + kc * 16384 + 512);
      short8 a2 = *(const short8*)(pA + kc * 16384 + 1024);
      short8 a3 = *(const short8*)(pA + kc * 16384 + 1536);
#pragma unroll
      for (int pt = 0; pt < 8; ++pt) {
        short8 bb = *(const short8*)(zb + pt * 8192);
        acc[0][pt] = MFMA(a0, bb, acc[0][pt]);
        acc[1][pt] = MFMA(a1, bb, acc[1][pt]);
        acc[2][pt] = MFMA(a2, bb, acc[2][pt]);
        acc[3][pt] = MFMA(a3, bb, acc[3][pt]);
      }
    }
    // running argmin update for this chunk (codes ascend: cc, ct, r)
#pragma unroll
    for (int ct = 0; ct < 4; ++ct) {
      f32x4 en4 = *(const f32x4*)(en + w * 128 + cc * 64 + ct * 16 + 4 * g);
#pragma unroll
      for (int pt = 0; pt < 8; ++pt) {
#pragma unroll
        for (int r = 0; r < 4; ++r) {
          float d = en4[r] - 2.f * acc[ct][pt][r];
          int code = w * 128 + cc * 64 + ct * 16 + 4 * g + r;
          if (d < bvv[pt]) { bvv[pt] = d; bcc[pt] = code; }
        }
      }
    }
  }
  // cross-lane reduce (over g) per pixel
#pragma unroll
  for (int pt = 0; pt < 8; ++pt) {
    float bv = bvv[pt];
    int bc = bcc[pt];
#pragma unroll
    for (int m = 16; m <= 32; m <<= 1) {
      float ov = __shfl_xor(bv, m);
      int oc = __shfl_xor(bc, m);
      if (ov < bv || (ov == bv && oc < bc)) { bv = ov; bc = oc; }
    }
    if (g == 0) {
      sV[w][pt * 16 + c16] = bv;
      sC[w][pt * 16 + c16] = bc;
    }
  }
  __syncthreads();
  if (t < 128) {
    float bv = sV[0][t];
    int bc = sC[0][t];
#pragma unroll
    for (int w2 = 1; w2 < 4; ++w2) {
      float v = sV[w2][t];
      int c = sC[w2][t];
      if (v < bv || (v == bv && c < bc)) { bv = v; bc = c; }
    }
    sIdx[t] = bc;
    atomicAdd(&sHist[bc], 1);
    sV[0][t] = bv + sZn[t];
  }
  __syncthreads();
  if (t < 64) {
    float ls = sV[0][t] + sV[0][t + 64];
#pragma unroll
    for (int m = 32; m >= 1; m >>= 1) ls += __shfl_xor(ls, m);
    if (t == 0) partials[blk] = ls;
  }
  for (int e = t; e < KC; e += 256) {
    int c = sHist[e];
    if (c) atomicAdd(&counts[e], c);
  }
  // fused gather: Q = emb[idx] f32 (overwrites this block's Zc bytes),
  // QrP = relu bf16 (padded layout)
  for (int e = t; e < 4096; e += 256) {
    int p = e >> 5, d4 = (e & 31) << 2;
    int c = sIdx[p];
    f32x4 q = *(const f32x4*)(emb + c * DD + d4);
    *(f32x4*)(Q + (pix0 + p) * DD + d4) = q;
    short4v sv;
#pragma unroll
    for (int r = 0; r < 4; ++r) sv[r] = f2bf(fmaxf(q[r], 0.f));
    long pixg = pix0 + p;
    int xx = (int)(pixg & 63), yy = (int)((pixg >> 6) & 63),
        bb = (int)(pixg >> 12);
    *(short4v*)(QrP + (((long)(bb * 66 + yy + 1)) * 66 + xx + 1) * 128 + d4) =
        sv;
  }
}

// ============================================================================
// tconv1 MFMA v2 (LDS-staged): QrP[66,66,128] -> T1[130,130,64] bf16 relu
// Block = 8x8 m-tile, all 4 parities (wave = parity), all 64 out-ch.
// Input tile 10x10x128 staged coalesced into LDS, pixel stride padded to
// 272 B (conflict-free ds_read_b128). Per wave: acc[4 ot][4 nt], 16 MFMA
// per K-step, K = 16 steps of 32 (4 taps x 128 ch).
// grid 2048 = 32 b x 8 tyt x 8 txt
// ============================================================================
__global__ __launch_bounds__(256) void k_tconv1m(const short* __restrict__ QrP,
    const short* __restrict__ wA, const float* __restrict__ bias,
    short* __restrict__ T1) {
  __shared__ short sX[13600];  // 100 pixels x 136 shorts (128 + 8 pad) = 27.2 KB
  int blk = blockIdx.x;
  int txt = blk & 7, tyt = (blk >> 3) & 7, b = blk >> 6;
  int my0 = tyt * 8, mx0 = txt * 8;
  int t = threadIdx.x;
  // stage QrP rows my0..my0+9, cols mx0..mx0+9 (coalesced short8 reads)
  for (int q = t; q < 1600; q += 256) {
    int p = q >> 4, seg = q & 15;
    int iy = p / 10, ix = p - iy * 10;
    short8 v = *(const short8*)(QrP +
        ((b * 66 + my0 + iy) * 66 + mx0 + ix) * 128 + seg * 8);
    *(short8*)((char*)sX + p * 272 + seg * 16) = v;
  }
  __syncthreads();
  int w = t >> 6, l = t & 63, lr = l & 15, g = l >> 4;
  int pyr = w >> 1, pxr = w & 1;
  // per-nt LDS byte base (tap dy=dx=0, ch-group 0)
  int Bb[4];
#pragma unroll
  for (int nt = 0; nt < 4; ++nt) {
    int p = nt * 16 + lr;
    int my = p >> 3, mx = p & 7;
    Bb[nt] = ((my + pyr + 1) * 10 + (mx + pxr + 1)) * 272 + g * 16;
  }
  const short* pAw = wA + w * 32768 + l * 8;  // parity-major weight block
  f32x4 acc[4][4] = {};
  short8 a[4], bfr[4], na[4], nb[4];
#pragma unroll
  for (int ot = 0; ot < 4; ++ot) a[ot] = *(const short8*)(pAw + ot * 512);
#pragma unroll
  for (int nt = 0; nt < 4; ++nt)
    bfr[nt] = *(const short8*)((const char*)sX + Bb[nt]);
  for (int kc = 0; kc < 15; ++kc) {
    int nk = kc + 1;
    int tt = nk >> 2, dy = tt >> 1, dx = tt & 1;
    int off = -(dy * 10 + dx) * 272 + (nk & 3) * 64;
#pragma unroll
    for (int ot = 0; ot < 4; ++ot)
      na[ot] = *(const short8*)(pAw + nk * 2048 + ot * 512);
#pragma unroll
    for (int nt = 0; nt < 4; ++nt)
      nb[nt] = *(const short8*)((const char*)sX + Bb[nt] + off);
#pragma unroll
    for (int ot = 0; ot < 4; ++ot)
#pragma unroll
      for (int nt = 0; nt < 4; ++nt)
        acc[ot][nt] = MFMA(a[ot], bfr[nt], acc[ot][nt]);
#pragma unroll
    for (int ot = 0; ot < 4; ++ot) a[ot] = na[ot];
#pragma unroll
    for (int nt = 0; nt < 4; ++nt) bfr[nt] = nb[nt];
  }
#pragma unroll
  for (int ot = 0; ot < 4; ++ot)
#pragma unroll
    for (int nt = 0; nt < 4; ++nt)
      acc[ot][nt] = MFMA(a[ot], bfr[nt], acc[ot][nt]);
  // epilogue: bias + relu + bf16 store
#pragma unroll
  for (int ot = 0; ot < 4; ++ot) {
    int o0 = ot * 16 + 4 * g;
    f32x4 b4 = *(const f32x4*)(bias + o0);
#pragma unroll
    for (int nt = 0; nt < 4; ++nt) {
      int p = nt * 16 + lr;
      int my = my0 + (p >> 3), mx = mx0 + (p & 7);
      int oy = 2 * my + pyr, ox = 2 * mx + pxr;
      short4v sv;
#pragma unroll
      for (int r = 0; r < 4; ++r)
        sv[r] = f2bf(fmaxf(acc[ot][nt][r] + b4[r], 0.f));
      *(short4v*)(T1 + ((b * 130 + oy + 1) * 130 + ox + 1) * 64 + o0) = sv;
    }
  }
}

// ============================================================================
// tconv2 VALU: T1[130,130,64] bf16 -> x_recon[32,256,256] f32
// ============================================================================
__global__ __launch_bounds__(256) void k_tconv2(const short* __restrict__ T1,
    const float* __restrict__ w, const float* __restrict__ bias,
    float* __restrict__ xrec) {
  __shared__ float sW[1024];
  int t = threadIdx.x;
  for (int e = t; e < 1024; e += 256) sW[e] = w[e];
  __syncthreads();
  int blk = blockIdx.x;
  int tx = blk & 15, ty = (blk >> 4) & 15, b = blk >> 8;
  int row = t >> 4, col = t & 15;
  int oy = ty * 16 + row, ox = tx * 16 + col;
  int pyr = oy & 1, pxr = ox & 1;
  int kye = 1 - pyr, kxe = 1 - pxr;
  int m = oy >> 1, n = ox >> 1;
  float acc = bias[0];
#pragma unroll
  for (int dy = 0; dy < 2; ++dy) {
#pragma unroll
    for (int dx = 0; dx < 2; ++dx) {
      const short* ip =
          T1 + ((b * 130 + m + pyr - dy + 1) * 130 + (n + pxr - dx + 1)) * 64;
      int tap = (kye + 2 * dy) * 4 + (kxe + 2 * dx);
#pragma unroll
      for (int c8 = 0; c8 < 8; ++c8) {
        short8 v = *(const short8*)(ip + c8 * 8);
#pragma unroll
        for (int i = 0; i < 8; ++i)
          acc = fmaf(bf2f(v[i]), sW[(c8 * 8 + i) * 16 + tap], acc);
      }
    }
  }
  xrec[(b * 256 + oy) * 256 + ox] = acc;
}

// ============================================================================
// finalize: loss from 1024 partials; perplexity from counts
// ============================================================================
__global__ __launch_bounds__(256) void k_final(const float* __restrict__ partials,
    const int* __restrict__ counts, float* __restrict__ out) {
  int t = threadIdx.x;
  float s = 0.f;
  for (int i = t; i < 1024; i += 256) s += partials[i];
#pragma unroll
  for (int m = 32; m >= 1; m >>= 1) s += __shfl_xor(s, m);
  __shared__ float sr[4];
  if ((t & 63) == 0) sr[t >> 6] = s;
  __syncthreads();
  if (t == 0) {
    float tot = sr[0] + sr[1] + sr[2] + sr[3];
    out[0] = 1.25f * tot / 16777216.0f;
  }
  float h = 0.f;
  for (int c = t; c < KC; c += 256) {
    float avg = (float)counts[c] / 131072.0f;
    h += avg * logf(avg + 1e-10f);
  }
#pragma unroll
  for (int m = 32; m >= 1; m >>= 1) h += __shfl_xor(h, m);
  __shared__ float sr2[4];
  if ((t & 63) == 0) sr2[t >> 6] = h;
  __syncthreads();
  if (t == 0) out[1 + 32 * 256 * 256] = expf(-(sr2[0] + sr2[1] + sr2[2] + sr2[3]));
}

// ============================================================================
extern "C" void kernel_launch(void* const* d_in, const int* in_sizes, int n_in,
                              void* d_out, int out_size, void* d_ws, size_t ws_size,
                              hipStream_t stream) {
  const float* x    = (const float*)d_in[0];
  const float* c1w  = (const float*)d_in[1];
  const float* c1b  = (const float*)d_in[2];
  const float* c2w  = (const float*)d_in[3];
  const float* c2b  = (const float*)d_in[4];
  const float* r1w3 = (const float*)d_in[5];
  const float* r1w1 = (const float*)d_in[6];
  const float* r2w3 = (const float*)d_in[7];
  const float* r2w1 = (const float*)d_in[8];
  const float* prew = (const float*)d_in[9];
  const float* preb = (const float*)d_in[10];
  const float* emb  = (const float*)d_in[11];
  const float* d1w3 = (const float*)d_in[12];
  const float* d1w1 = (const float*)d_in[13];
  const float* d2w3 = (const float*)d_in[14];
  const float* d2w1 = (const float*)d_in[15];
  const float* t1w  = (const float*)d_in[16];
  const float* t1b  = (const float*)d_in[17];
  const float* t2w  = (const float*)d_in[18];
  const float* t2b  = (const float*)d_in[19];
  float* out = (float*)d_out;

  char* ws = (char*)d_ws;
  short* buf0 = (short*)(ws);                      // A1 / T1 : 69,222,400 B
  float* bufX = (float*)(ws + 69222400);           // Xf / Zcat / Q : 67,108,864 B
  short* bufR = (short*)(ws + 136331264);          // XrP / QrP : 35,684,352 B
  short* Hr   = (short*)(ws + 172015616);          // 8,388,608 B -> ends 180404224
  int*   counts = (int*)(ws + 180928512);          // 2,048 B
  float* partials = (float*)(ws + 180930560);      // 8,192 B
  float* en   = (float*)(ws + 180938752);          // 2,048 B
  short* wAc2 = (short*)(ws + 180940800);          // 262,144 B
  short* wAr3 = (short*)(ws + 181202944);          // 294,912 B
  short* wAr1 = (short*)(ws + 181497856);          // 32,768 B
  short* wApre= (short*)(ws + 181530624);          // 32,768 B
  short* wAt1 = (short*)(ws + 181563392);          // 262,144 B
  short* Ecat = (short*)(ws + 181825536);          // 393,216 B -> ends 182,218,752

  short* Zcat = (short*)bufX;  // 67,108,864 B (Xf dead after enc res1addm#2;
                               // Q gather overwrites Zcat block-locally)

  short* wAr3_e1 = wAr3;
  short* wAr3_e2 = wAr3 + 36864;
  short* wAr3_d1 = wAr3 + 2 * 36864;
  short* wAr3_d2 = wAr3 + 3 * 36864;
  short* wAr1_e1 = wAr1;
  short* wAr1_e2 = wAr1 + 4096;
  short* wAr1_d1 = wAr1 + 2 * 4096;
  short* wAr1_d2 = wAr1 + 3 * 4096;

  hipMemsetAsync(counts, 0, KC * sizeof(int), stream);

  k_border  <<<256, 256, 0, stream>>>(buf0, bufR);
  k_perm_c2 <<<512, 256, 0, stream>>>(c2w, wAc2);
  k_perm_r3 <<<144, 256, 0, stream>>>(r1w3, wAr3_e1);
  k_perm_r3 <<<144, 256, 0, stream>>>(r2w3, wAr3_e2);
  k_perm_r3 <<<144, 256, 0, stream>>>(d1w3, wAr3_d1);
  k_perm_r3 <<<144, 256, 0, stream>>>(d2w3, wAr3_d2);
  k_perm_r1 <<<16, 256, 0, stream>>>(r1w1, wAr1_e1);
  k_perm_r1 <<<16, 256, 0, stream>>>(r2w1, wAr1_e2);
  k_perm_r1 <<<16, 256, 0, stream>>>(d1w1, wAr1_d1);
  k_perm_r1 <<<16, 256, 0, stream>>>(d2w1, wAr1_d2);
  k_perm_pre<<<64, 256, 0, stream>>>(prew, wApre);
  k_perm_t1 <<<512, 256, 0, stream>>>(t1w, wAt1);
  k_perm_E  <<<768, 256, 0, stream>>>(emb, Ecat);
  k_embnorm <<<512, 64, 0, stream>>>(emb, en);

  k_conv1   <<<4096, 256, 0, stream>>>(x, c1w, c1b, buf0);
  k_conv2m  <<<2048, 256, 0, stream>>>(buf0, wAc2, c2b, bufX, bufR);
  k_res3m   <<<1024, 256, 0, stream>>>(bufR, wAr3_e1, Hr);
  k_res1addm<<<2048, 256, 0, stream>>>(Hr, wAr1_e1, bufX, bufR);
  k_res3m   <<<1024, 256, 0, stream>>>(bufR, wAr3_e2, Hr);
  k_res1addm<<<2048, 256, 0, stream>>>(Hr, wAr1_e2, bufX, bufR);
  k_prem    <<<2048, 256, 0, stream>>>(bufR, wApre, preb, Zcat);
  k_vqm6    <<<1024, 256, 0, stream>>>(Zcat, Ecat, en, emb, counts, partials,
                                       bufX, bufR);
  k_res3m   <<<1024, 256, 0, stream>>>(bufR, wAr3_d1, Hr);
  k_res1addm<<<2048, 256, 0, stream>>>(Hr, wAr1_d1, bufX, bufR);
  k_res3m   <<<1024, 256, 0, stream>>>(bufR, wAr3_d2, Hr);
  k_res1addm<<<2048, 256, 0, stream>>>(Hr, wAr1_d2, bufX, bufR);
  k_tconv1m <<<2048, 256, 0, stream>>>(bufR, wAt1, t1b, buf0);
  k_tconv2  <<<8192, 256, 0, stream>>>(buf0, t2w, t2b, out + 1);
  k_final   <<<1, 256, 0, stream>>>(partials, counts, out);
}

// Round 7
// 779.101 us; speedup vs baseline: 1.0003x; 1.0003x over previous
//
#include <hip/hip_runtime.h>
#include <math.h>

#define KC 512
#define DD 128

typedef __attribute__((ext_vector_type(8))) short short8;
typedef __attribute__((ext_vector_type(4))) short short4v;
typedef __attribute__((ext_vector_type(4))) float f32x4;

#define MFMA(a, b, c) __builtin_amdgcn_mfma_f32_16x16x32_bf16(a, b, c, 0, 0, 0)

__device__ __forceinline__ short f2bf(float f) {
  unsigned u = __float_as_uint(f);
  u = (u + 0x7FFFu + ((u >> 16) & 1u)) >> 16;
  return (short)u;
}
__device__ __forceinline__ float bf2f(short s) {
  return __uint_as_float(((unsigned)(unsigned short)s) << 16);
}

// ============================================================================
// weight permutation kernels (A-fragment order)
// ============================================================================
__global__ __launch_bounds__(256) void k_perm_c2(const float* __restrict__ w,
                                                 short* __restrict__ dst) {
  int e = blockIdx.x * 256 + threadIdx.x;  // < 131072
  int j = e & 7, l = (e >> 3) & 63, ot = (e >> 9) & 7, kc = e >> 12;
  int o = ot * 16 + (l & 15), g = l >> 4;
  int tap = kc >> 1, ci = (kc & 1) * 32 + 8 * g + j;
  dst[e] = f2bf(w[(o * 64 + ci) * 16 + tap]);
}

__global__ __launch_bounds__(256) void k_perm_r3(const float* __restrict__ w,
                                                 short* __restrict__ dst) {
  int e = blockIdx.x * 256 + threadIdx.x;  // < 36864
  int j = e & 7, l = (e >> 3) & 63, ot = (e >> 9) & 1, kc = e >> 10;
  int o = ot * 16 + (l & 15), g = l >> 4;
  int tap = kc >> 2, ci = (kc & 3) * 32 + 8 * g + j;
  dst[e] = f2bf(w[(o * 128 + ci) * 9 + tap]);
}

__global__ __launch_bounds__(256) void k_perm_r1(const float* __restrict__ w,
                                                 short* __restrict__ dst) {
  int e = blockIdx.x * 256 + threadIdx.x;  // < 4096
  int j = e & 7, l = (e >> 3) & 63, ot = e >> 9;
  int o = ot * 16 + (l & 15), g = l >> 4;
  int ci = 8 * g + j;
  dst[e] = f2bf(w[o * 32 + ci]);
}

__global__ __launch_bounds__(256) void k_perm_pre(const float* __restrict__ w,
                                                  short* __restrict__ dst) {
  int e = blockIdx.x * 256 + threadIdx.x;  // < 16384
  int j = e & 7, l = (e >> 3) & 63, ot = (e >> 9) & 7, kc = e >> 12;
  int o = ot * 16 + (l & 15), g = l >> 4;
  int ci = kc * 32 + 8 * g + j;
  dst[e] = f2bf(w[o * 128 + ci]);
}

__global__ __launch_bounds__(256) void k_perm_t1(const float* __restrict__ w,
                                                 short* __restrict__ dst) {
  int e = blockIdx.x * 256 + threadIdx.x;  // < 131072
  int j = e & 7, l = (e >> 3) & 63, ot = (e >> 9) & 3, kc = (e >> 11) & 15,
      pp = e >> 15;
  int pyr = pp >> 1, pxr = pp & 1;
  int o = ot * 16 + (l & 15), g = l >> 4;
  int tt = kc >> 2, dy = tt >> 1, dx = tt & 1;
  int ky = (1 - pyr) + 2 * dy, kx = (1 - pxr) + 2 * dx;
  int ci = (kc & 3) * 32 + 8 * g + j;
  dst[e] = f2bf(w[(ci * 64 + o) * 16 + ky * 4 + kx]);
}

// ============================================================================
// Ecat permute: emb[512][128] f32 -> Ecat bf16 in A-fragment order over K=384:
// K [0:256) = eh (duplicated), [256:384) = el. e=((kc*32+ot)*64+l)*8+j
// grid 768 x 256 (196608 elems)
// ============================================================================
__global__ __launch_bounds__(256) void k_perm_E(const float* __restrict__ emb,
                                                short* __restrict__ dst) {
  int e = blockIdx.x * 256 + threadIdx.x;
  int j = e & 7, l = (e >> 3) & 63, ot = (e >> 9) & 31, kc = e >> 14;
  int c = ot * 16 + (l & 15);
  int k = kc * 32 + 8 * (l >> 4) + j;
  float v = emb[c * DD + (k & 127)];
  short hi = f2bf(v);
  dst[e] = (k < 256) ? hi : f2bf(v - bf2f(hi));
}

// ============================================================================
// emb norms (exact f32)
// ============================================================================
__global__ __launch_bounds__(64) void k_embnorm(const float* __restrict__ emb,
                                                float* __restrict__ en) {
  int c = blockIdx.x, l = threadIdx.x;
  float a = emb[c * DD + l], b = emb[c * DD + 64 + l];
  float s = a * a + b * b;
#pragma unroll
  for (int m = 32; m >= 1; m >>= 1) s += __shfl_xor(s, m);
  if (l == 0) en[c] = s;
}

// ============================================================================
// border zero: A1[32,130,130,64] and XrP[32,66,66,128] padding rings only
// (replaces 104 MB of full-buffer memset with 8.4 MB of border writes).
// grid 256 = 32 b x 8 slices, 256 thr.
// ============================================================================
__global__ __launch_bounds__(256) void k_border(short* __restrict__ A1,
                                                short* __restrict__ XrP) {
  int blk = blockIdx.x;
  int b = blk >> 3;
  int tid = ((blk & 7) << 8) + threadIdx.x;  // 0..2047
  short8 z8 = {};
  long baseA = (long)b * 1081600;  // 130*130*64
  // A1 top/bottom rows: 2 x 1040 short8
  for (int e = tid; e < 2080; e += 2048) {
    int r = e >= 1040;
    int rem = r ? e - 1040 : e;
    *(short8*)(A1 + baseA + (r ? 129L * 130 * 64 : 0) + rem * 8) = z8;
  }
  // A1 left/right cols, rows 1..128: 2048 short8 (exactly one per tid)
  {
    int c = tid >> 10, rem = tid & 1023;
    int row = 1 + (rem >> 3), s8 = rem & 7;
    *(short8*)(A1 + baseA + (row * 130L + (c ? 129 : 0)) * 64 + s8 * 8) = z8;
  }
  long baseX = (long)b * 557568;  // 66*66*128
  // XrP top/bottom rows: 2 x 1056 short8
  for (int e = tid; e < 2112; e += 2048) {
    int r = e >= 1056;
    int rem = r ? e - 1056 : e;
    *(short8*)(XrP + baseX + (r ? 65L * 66 * 128 : 0) + rem * 8) = z8;
  }
  // XrP left/right cols, rows 1..64: 2048 short8
  {
    int c = tid >> 10, rem = tid & 1023;
    int row = 1 + (rem >> 4), s8 = rem & 15;
    *(short8*)(XrP + baseX + (row * 66L + (c ? 65 : 0)) * 128 + s8 * 8) = z8;
  }
}

// ============================================================================
// conv1: x[32,1,256,256] f32 -> A1[32,130,130,64] bf16 relu (padded, ch-last)
// grid 4096 = 32 b x 128 y
// ============================================================================
__global__ __launch_bounds__(256) void k_conv1(const float* __restrict__ x,
    const float* __restrict__ w, const float* __restrict__ bias,
    short* __restrict__ A1) {
  __shared__ float sXp[4 * 260];
  __shared__ float sWt[16 * 64];
  int blk = blockIdx.x;
  int y = blk & 127, b = blk >> 7;
  int t = threadIdx.x;
  for (int e = t; e < 1024; e += 256) sWt[e] = w[(e & 63) * 16 + (e >> 6)];
  if (t < 4) {
    sXp[t * 260] = 0.f;
    sXp[t * 260 + 257] = 0.f;
    sXp[t * 260 + 258] = 0.f;
    sXp[t * 260 + 259] = 0.f;
  }
  for (int e = t; e < 1024; e += 256) {
    int r = e >> 8, col = e & 255;
    int giy = 2 * y - 1 + r;
    float v = 0.f;
    if ((unsigned)giy < 256u) v = x[(b * 256 + giy) * 256 + col];
    sXp[r * 260 + col + 1] = v;
  }
  __syncthreads();
  int og = t >> 6, l = t & 63, o0 = og * 16;
  float acc0[16], acc1[16];
#pragma unroll
  for (int oo = 0; oo < 16; ++oo) { acc0[oo] = 0.f; acc1[oo] = 0.f; }
  int xA = 2 * l, xB = 2 * l + 128;
#pragma unroll
  for (int ky = 0; ky < 4; ++ky) {
#pragma unroll
    for (int kx = 0; kx < 4; ++kx) {
      float a0 = sXp[ky * 260 + xA + kx];
      float a1 = sXp[ky * 260 + xB + kx];
      const float* wrow = &sWt[(ky * 4 + kx) * 64 + o0];
#pragma unroll
      for (int oo = 0; oo < 16; ++oo) {
        float wv = wrow[oo];
        acc0[oo] = fmaf(a0, wv, acc0[oo]);
        acc1[oo] = fmaf(a1, wv, acc1[oo]);
      }
    }
  }
  long base0 = (((long)(b * 130 + y + 1)) * 130 + l + 1) * 64 + o0;
  long base1 = base0 + 64 * 64;
  short8 s0a, s0b, s1a, s1b;
#pragma unroll
  for (int oo = 0; oo < 8; ++oo) {
    s0a[oo] = f2bf(fmaxf(acc0[oo] + bias[o0 + oo], 0.f));
    s0b[oo] = f2bf(fmaxf(acc0[oo + 8] + bias[o0 + oo + 8], 0.f));
    s1a[oo] = f2bf(fmaxf(acc1[oo] + bias[o0 + oo], 0.f));
    s1b[oo] = f2bf(fmaxf(acc1[oo + 8] + bias[o0 + oo + 8], 0.f));
  }
  *(short8*)(A1 + base0) = s0a;
  *(short8*)(A1 + base0 + 8) = s0b;
  *(short8*)(A1 + base1) = s1a;
  *(short8*)(A1 + base1 + 8) = s1b;
}

// ============================================================================
// conv2 MFMA v2 (LDS-staged): A1[130,130,64] bf16 -> relu -> Xf[64,64,128] f32
// + XrP[66,66,128] bf16. Block = 8x8 out-px, input tile 18x18x64 staged into
// LDS once (whole K-loop reuses it). Pixel stride 136 B -> conflict-free
// ds_read_b128 (bank = 2*pix+4g mod 32: 8 quads x 2-way).
// grid 2048 = 32 b x 8 by x 8 bx
// ============================================================================
__global__ __launch_bounds__(256) void k_conv2m(const short* __restrict__ A1,
    const short* __restrict__ wA, const float* __restrict__ bias,
    float* __restrict__ Xf, short* __restrict__ XrP) {
  __shared__ short sX[22032];  // 324 px * 68 shorts (136 B) = 44,064 B
  int blk = blockIdx.x;
  int bx = blk & 7, by = (blk >> 3) & 7, b = blk >> 6;
  int t = threadIdx.x;
  int R0 = by * 16, C0 = bx * 16;
  for (int q = t; q < 2592; q += 256) {
    int p = q >> 3, seg = q & 7;
    int iy = p / 18, ix = p - iy * 18;
    short8 v = *(const short8*)(A1 +
        (((long)b * 130 + R0 + iy) * 130 + C0 + ix) * 64 + seg * 8);
    *(short8*)((char*)sX + p * 136 + seg * 16) = v;
  }
  __syncthreads();
  int w = t >> 6, l = t & 63, lr = l & 15, g = l >> 4;
  int Bb[4];
#pragma unroll
  for (int pt = 0; pt < 4; ++pt) {
    int p = pt * 16 + lr;
    int lp = 2 * (p >> 3) * 18 + 2 * (p & 7);
    Bb[pt] = lp * 136 + g * 16;
  }
  const short* pA0 = wA + (2 * w * 64 + l) * 8;
  const short* pA1 = pA0 + 512;
  f32x4 acc[2][4] = {};
  short8 a0 = *(const short8*)pA0;
  short8 a1 = *(const short8*)pA1;
  short8 bv[4];
#pragma unroll
  for (int i = 0; i < 4; ++i)
    bv[i] = *(const short8*)((const char*)sX + Bb[i]);
  for (int kc = 0; kc < 31; ++kc) {
    int nk = kc + 1;
    int tap = nk >> 1;
    int off = ((tap >> 2) * 18 + (tap & 3)) * 136 + (nk & 1) * 64;
    short8 na0 = *(const short8*)(pA0 + nk * 4096);
    short8 na1 = *(const short8*)(pA1 + nk * 4096);
    short8 nb[4];
#pragma unroll
    for (int i = 0; i < 4; ++i)
      nb[i] = *(const short8*)((const char*)sX + Bb[i] + off);
#pragma unroll
    for (int i = 0; i < 4; ++i) {
      acc[0][i] = MFMA(a0, bv[i], acc[0][i]);
      acc[1][i] = MFMA(a1, bv[i], acc[1][i]);
    }
    a0 = na0; a1 = na1;
#pragma unroll
    for (int i = 0; i < 4; ++i) bv[i] = nb[i];
  }
#pragma unroll
  for (int i = 0; i < 4; ++i) {
    acc[0][i] = MFMA(a0, bv[i], acc[0][i]);
    acc[1][i] = MFMA(a1, bv[i], acc[1][i]);
  }
#pragma unroll
  for (int oi = 0; oi < 2; ++oi) {
    int o0 = (2 * w + oi) * 16 + 4 * g;
#pragma unroll
    for (int pt = 0; pt < 4; ++pt) {
      int p = pt * 16 + lr;
      int y = by * 8 + (p >> 3), x = bx * 8 + (p & 7);
      f32x4 nv; short4v sv;
#pragma unroll
      for (int r = 0; r < 4; ++r) {
        float v = fmaxf(acc[oi][pt][r] + bias[o0 + r], 0.f);
        nv[r] = v; sv[r] = f2bf(v);
      }
      *(f32x4*)(Xf + ((b * 64 + y) * 64 + x) * 128 + o0) = nv;
      *(short4v*)(XrP + ((b * 66 + y + 1) * 66 + x + 1) * 128 + o0) = sv;
    }
  }
}

// ============================================================================
// res3 MFMA v2 (LDS-staged): XrP[66,66,128] -> Hr[64,64,32] bf16 relu
// Block = 8x16 out-px; input tile 10x18x128 staged into LDS with XOR swizzle
// (inner ^ ((pix&7)<<4)) -> conflict-free ds_read_b128. Wave w owns rows
// 2w,2w+1; 4 MFMA / 2 ds_read per K-step, 36 steps.
// grid 1024 = 32 b x 8 yt x 4 tx
// ============================================================================
__global__ __launch_bounds__(256) void k_res3m(const short* __restrict__ XrP,
    const short* __restrict__ wA, short* __restrict__ Hr) {
  __shared__ short sX[23040];  // 180 px * 128 shorts (256 B swizzled) = 46,080 B
  int blk = blockIdx.x;
  int tx = blk & 3, yt = (blk >> 2) & 7, b = blk >> 5;
  int t = threadIdx.x;
  int r0 = yt * 8, c0 = tx * 16;
  for (int q = t; q < 2880; q += 256) {
    int p = q >> 4, seg = q & 15;
    int iy = p / 18, ix = p - iy * 18;
    short8 v = *(const short8*)(XrP +
        (((long)b * 66 + r0 + iy) * 66 + c0 + ix) * 128 + seg * 8);
    *(short8*)((char*)sX + p * 256 + ((seg * 16) ^ ((p & 7) << 4))) = v;
  }
  __syncthreads();
  int w = t >> 6, l = t & 63, lr = l & 15, g = l >> 4;
  const short* pA0 = wA + l * 8;
  const short* pA1 = pA0 + 512;
  f32x4 acc[2][2] = {};
  short8 a0 = *(const short8*)pA0;
  short8 a1 = *(const short8*)pA1;
  short8 bv[2];
#pragma unroll
  for (int j = 0; j < 2; ++j) {
    int lp = (2 * w + j) * 18 + lr;
    bv[j] = *(const short8*)((const char*)sX + lp * 256 +
                             ((g * 16) ^ ((lp & 7) << 4)));
  }
  for (int kc = 0; kc < 35; ++kc) {
    int nk = kc + 1;
    int tap = nk >> 2;
    int ky = tap / 3, kx = tap - ky * 3;
    int inner = g * 16 + (nk & 3) * 64;
    short8 na0 = *(const short8*)(pA0 + nk * 1024);
    short8 na1 = *(const short8*)(pA1 + nk * 1024);
    short8 nb[2];
#pragma unroll
    for (int j = 0; j < 2; ++j) {
      int lp = (2 * w + j + ky) * 18 + lr + kx;
      nb[j] = *(const short8*)((const char*)sX + lp * 256 +
                               (inner ^ ((lp & 7) << 4)));
    }
#pragma unroll
    for (int j = 0; j < 2; ++j) {
      acc[0][j] = MFMA(a0, bv[j], acc[0][j]);
      acc[1][j] = MFMA(a1, bv[j], acc[1][j]);
    }
    a0 = na0; a1 = na1;
    bv[0] = nb[0]; bv[1] = nb[1];
  }
#pragma unroll
  for (int j = 0; j < 2; ++j) {
    acc[0][j] = MFMA(a0, bv[j], acc[0][j]);
    acc[1][j] = MFMA(a1, bv[j], acc[1][j]);
  }
#pragma unroll
  for (int oi = 0; oi < 2; ++oi) {
    int o0 = oi * 16 + 4 * g;
#pragma unroll
    for (int j = 0; j < 2; ++j) {
      int y = r0 + 2 * w + j, x = c0 + lr;
      short4v sv;
#pragma unroll
      for (int r = 0; r < 4; ++r) sv[r] = f2bf(fmaxf(acc[oi][j][r], 0.f));
      *(short4v*)(Hr + ((b * 64 + y) * 64 + x) * 32 + o0) = sv;
    }
  }
}

// ============================================================================
// res1+add MFMA: Hr[64,64,32] -> Xf += conv1x1 ; XrP = relu(Xf) bf16
// ============================================================================
__global__ __launch_bounds__(256) void k_res1addm(const short* __restrict__ Hr,
    const short* __restrict__ wA, float* __restrict__ Xf,
    short* __restrict__ XrP) {
  int blk = blockIdx.x;
  int bx = blk & 7, by = (blk >> 3) & 7, b = blk >> 6;
  int t = threadIdx.x, w = t >> 6, l = t & 63, lr = l & 15, g = l >> 4;
  f32x4 acc[2][4] = {};
  short8 a0 = *(const short8*)(wA + (2 * w * 64 + l) * 8);
  short8 a1 = *(const short8*)(wA + ((2 * w + 1) * 64 + l) * 8);
#pragma unroll
  for (int i = 0; i < 4; ++i) {
    int p = i * 16 + lr;
    int y = by * 8 + (p >> 3), x = bx * 8 + (p & 7);
    short8 bv = *(const short8*)(Hr + ((b * 64 + y) * 64 + x) * 32 + 8 * g);
    acc[0][i] = MFMA(a0, bv, acc[0][i]);
    acc[1][i] = MFMA(a1, bv, acc[1][i]);
  }
#pragma unroll
  for (int oi = 0; oi < 2; ++oi) {
    int o0 = (2 * w + oi) * 16 + 4 * g;
#pragma unroll
    for (int i = 0; i < 4; ++i) {
      int p = i * 16 + lr;
      int y = by * 8 + (p >> 3), x = bx * 8 + (p & 7);
      float* xp = Xf + ((b * 64 + y) * 64 + x) * 128 + o0;
      f32x4 old = *(f32x4*)xp;
      f32x4 nv; short4v sv;
#pragma unroll
      for (int r = 0; r < 4; ++r) {
        nv[r] = old[r] + acc[oi][i][r];
        sv[r] = f2bf(fmaxf(nv[r], 0.f));
      }
      *(f32x4*)xp = nv;
      *(short4v*)(XrP + ((b * 66 + y + 1) * 66 + x + 1) * 128 + o0) = sv;
    }
  }
}

// ============================================================================
// pre 1x1 MFMA: XrP[66,66,128] -> Zcat[pix][256] bf16 = [zhi(128) | zlo(128)]
// grid 2048 (8x8 pixels).
// ============================================================================
__global__ __launch_bounds__(256) void k_prem(const short* __restrict__ XrP,
    const short* __restrict__ wA, const float* __restrict__ bias,
    short* __restrict__ Zc) {
  int blk = blockIdx.x;
  int bx = blk & 7, by = (blk >> 3) & 7, b = blk >> 6;
  int t = threadIdx.x, w = t >> 6, l = t & 63, lr = l & 15, g = l >> 4;
  const short* pB[4];
#pragma unroll
  for (int pt = 0; pt < 4; ++pt) {
    int p = pt * 16 + lr;
    int y = by * 8 + (p >> 3), x = bx * 8 + (p & 7);
    pB[pt] = XrP + ((b * 66 + y + 1) * 66 + x + 1) * 128 + 8 * g;
  }
  const short* pA0 = wA + (2 * w * 64 + l) * 8;
  const short* pA1 = pA0 + 512;
  f32x4 acc[2][4] = {};
  short8 a0 = *(const short8*)pA0;
  short8 a1 = *(const short8*)pA1;
  short8 bv[4];
#pragma unroll
  for (int i = 0; i < 4; ++i) bv[i] = *(const short8*)pB[i];
  for (int kc = 0; kc < 3; ++kc) {
    int nk = kc + 1;
    int off = nk * 32;
    short8 na0 = *(const short8*)(pA0 + nk * 4096);
    short8 na1 = *(const short8*)(pA1 + nk * 4096);
    short8 nb[4];
#pragma unroll
    for (int i = 0; i < 4; ++i) nb[i] = *(const short8*)(pB[i] + off);
#pragma unroll
    for (int i = 0; i < 4; ++i) {
      acc[0][i] = MFMA(a0, bv[i], acc[0][i]);
      acc[1][i] = MFMA(a1, bv[i], acc[1][i]);
    }
    a0 = na0; a1 = na1;
#pragma unroll
    for (int i = 0; i < 4; ++i) bv[i] = nb[i];
  }
#pragma unroll
  for (int i = 0; i < 4; ++i) {
    acc[0][i] = MFMA(a0, bv[i], acc[0][i]);
    acc[1][i] = MFMA(a1, bv[i], acc[1][i]);
  }
#pragma unroll
  for (int oi = 0; oi < 2; ++oi) {
    int o0 = (2 * w + oi) * 16 + 4 * g;
#pragma unroll
    for (int pt = 0; pt < 4; ++pt) {
      int p = pt * 16 + lr;
      int y = by * 8 + (p >> 3), x = bx * 8 + (p & 7);
      long pix = (long)(b * 64 + y) * 64 + x;
      short4v hv, lv;
#pragma unroll
      for (int r = 0; r < 4; ++r) {
        float v = acc[oi][pt][r] + bias[o0 + r];
        short hi = f2bf(v);
        hv[r] = hi;
        lv[r] = f2bf(v - bf2f(hi));
      }
      *(short4v*)(Zc + pix * 256 + o0) = hv;
      *(short4v*)(Zc + pix * 256 + 128 + o0) = lv;
    }
  }
}

// ============================================================================
// VQ MFMA v7: 128 px x 512 codes (grid 1024, half the Ecat L2 stream of the
// 64-px variants) with the vqm2-proven explicit depth-1 prefetch (rolled
// 11-iter K-loop, a[4]/na[4] + b[8]/nb[8] = 96 operand regs, acc[4][8] in
// AGPRs). vqm6's full unroll hoisted 48 A-loads -> 256 arch VGPR + spill;
// this form compiled to 132 arch VGPR at the same budget in vqm2.
// Z tile 64 KB LDS (XOR swizzle). Fused argmin + hist + loss + gather.
// ============================================================================
__global__ __launch_bounds__(256) void k_vqm7(const short* __restrict__ Zc,
    const short* __restrict__ Ec, const float* __restrict__ en,
    const float* __restrict__ emb, int* __restrict__ counts,
    float* __restrict__ partials, float* __restrict__ Q,
    short* __restrict__ QrP) {
  __shared__ short sZ[32768];  // 128 px * 256 sh, swizzled = 64 KB
  __shared__ float sV[4][128];
  __shared__ int sC[4][128];
  __shared__ float sZn[128];
  __shared__ int sIdx[128];
  __shared__ int sHist[KC];
  int blk = blockIdx.x;
  long pix0 = (long)blk * 128;
  int t = threadIdx.x, w = t >> 6, l = t & 63, c16 = l & 15, g = l >> 4;
  for (int e = t; e < KC; e += 256) sHist[e] = 0;

  // stage Z tile: swizzle inner-byte ^ ((pix&7)<<4)
  for (int q = t; q < 4096; q += 256) {
    int p = q >> 5, seg = q & 31;
    short8 v = *(const short8*)(Zc + (pix0 + p) * 256 + seg * 8);
    *(short8*)((char*)sZ + p * 512 + ((seg * 16) ^ ((p & 7) << 4))) = v;
  }
  __syncthreads();

  // ||z||^2 per pixel from LDS: 2 threads/pixel, each 64 dims
  {
    int pz = t >> 1, sg = t & 1;
    const char* zb = (const char*)sZ + pz * 512;
    int swp = (pz & 7) << 4;
    float s = 0.f;
#pragma unroll
    for (int qq = 0; qq < 8; ++qq) {
      int ih = sg * 128 + 16 * qq;  // zh inner byte
      short8 h8 = *(const short8*)(zb + (ih ^ swp));
      short8 l8 = *(const short8*)(zb + ((ih + 256) ^ swp));
#pragma unroll
      for (int j = 0; j < 8; ++j) {
        float zv = bf2f(h8[j]) + bf2f(l8[j]);
        s = fmaf(zv, zv, s);
      }
    }
    s += __shfl_xor(s, 1);
    if (sg == 0) sZn[pz] = s;
  }

  // GEMM: 2 chunks of 64 codes; 12 K-steps of 32; 8 pixel-tiles.
  // Explicit depth-1 prefetch, rolled loop (reg-safe: vqm2 idiom).
  int sw = (c16 & 7) << 4;
  int zrow = c16 * 512;
  float bvv[8];
  int bcc[8];
#pragma unroll
  for (int pt = 0; pt < 8; ++pt) { bvv[pt] = 3.4e38f; bcc[pt] = 0; }
  const short* pE = Ec + (w * 8) * 512 + l * 8;
  for (int cc = 0; cc < 2; ++cc) {
    const short* pA = pE + cc * 2048;
    f32x4 acc[4][8] = {};
    short8 a[4], b[8], na[4], nb[8];
#pragma unroll
    for (int ct = 0; ct < 4; ++ct) a[ct] = *(const short8*)(pA + ct * 512);
    {
      const char* zb = (const char*)sZ + zrow + ((g * 16) ^ sw);
#pragma unroll
      for (int pt = 0; pt < 8; ++pt)
        b[pt] = *(const short8*)(zb + pt * 8192);
    }
    for (int kc = 0; kc < 11; ++kc) {
      int nk = kc + 1;
      int inn = (((nk < 8 ? nk : nk - 8) * 64 + g * 16) ^ sw);
      const char* zb = (const char*)sZ + zrow + inn;
#pragma unroll
      for (int ct = 0; ct < 4; ++ct)
        na[ct] = *(const short8*)(pA + nk * 16384 + ct * 512);
#pragma unroll
      for (int pt = 0; pt < 8; ++pt)
        nb[pt] = *(const short8*)(zb + pt * 8192);
#pragma unroll
      for (int ct = 0; ct < 4; ++ct)
#pragma unroll
        for (int pt = 0; pt < 8; ++pt)
          acc[ct][pt] = MFMA(a[ct], b[pt], acc[ct][pt]);
#pragma unroll
      for (int ct = 0; ct < 4; ++ct) a[ct] = na[ct];
#pragma unroll
      for (int pt = 0; pt < 8; ++pt) b[pt] = nb[pt];
    }
#pragma unroll
    for (int ct = 0; ct < 4; ++ct)
#pragma unroll
      for (int pt = 0; pt < 8; ++pt)
        acc[ct][pt] = MFMA(a[ct], b[pt], acc[ct][pt]);
    // running argmin update for this chunk (codes ascend: cc, ct, r)
#pragma unroll
    for (int ct = 0; ct < 4; ++ct) {
      f32x4 en4 = *(const f32x4*)(en + w * 128 + cc * 64 + ct * 16 + 4 * g);
#pragma unroll
      for (int pt = 0; pt < 8; ++pt) {
#pragma unroll
        for (int r = 0; r < 4; ++r) {
          float d = en4[r] - 2.f * acc[ct][pt][r];
          int code = w * 128 + cc * 64 + ct * 16 + 4 * g + r;
          if (d < bvv[pt]) { bvv[pt] = d; bcc[pt] = code; }
        }
      }
    }
  }
  // cross-lane reduce (over g) per pixel
#pragma unroll
  for (int pt = 0; pt < 8; ++pt) {
    float bv = bvv[pt];
    int bc = bcc[pt];
#pragma unroll
    for (int m = 16; m <= 32; m <<= 1) {
      float ov = __shfl_xor(bv, m);
      int oc = __shfl_xor(bc, m);
      if (ov < bv || (ov == bv && oc < bc)) { bv = ov; bc = oc; }
    }
    if (g == 0) {
      sV[w][pt * 16 + c16] = bv;
      sC[w][pt * 16 + c16] = bc;
    }
  }
  __syncthreads();
  if (t < 128) {
    float bv = sV[0][t];
    int bc = sC[0][t];
#pragma unroll
    for (int w2 = 1; w2 < 4; ++w2) {
      float v = sV[w2][t];
      int c = sC[w2][t];
      if (v < bv || (v == bv && c < bc)) { bv = v; bc = c; }
    }
    sIdx[t] = bc;
    atomicAdd(&sHist[bc], 1);
    sV[0][t] = bv + sZn[t];
  }
  __syncthreads();
  if (t < 64) {
    float ls = sV[0][t] + sV[0][t + 64];
#pragma unroll
    for (int m = 32; m >= 1; m >>= 1) ls += __shfl_xor(ls, m);
    if (t == 0) partials[blk] = ls;
  }
  for (int e = t; e < KC; e += 256) {
    int c = sHist[e];
    if (c) atomicAdd(&counts[e], c);
  }
  // fused gather: Q = emb[idx] f32 (overwrites this block's Zc bytes),
  // QrP = relu bf16 (padded layout)
  for (int e = t; e < 4096; e += 256) {
    int p = e >> 5, d4 = (e & 31) << 2;
    int c = sIdx[p];
    f32x4 q = *(const f32x4*)(emb + c * DD + d4);
    *(f32x4*)(Q + (pix0 + p) * DD + d4) = q;
    short4v sv;
#pragma unroll
    for (int r = 0; r < 4; ++r) sv[r] = f2bf(fmaxf(q[r], 0.f));
    long pixg = pix0 + p;
    int xx = (int)(pixg & 63), yy = (int)((pixg >> 6) & 63),
        bb = (int)(pixg >> 12);
    *(short4v*)(QrP + (((long)(bb * 66 + yy + 1)) * 66 + xx + 1) * 128 + d4) =
        sv;
  }
}

// ============================================================================
// tconv1 MFMA v2 (LDS-staged): QrP[66,66,128] -> T1[130,130,64] bf16 relu
// Block = 8x8 m-tile, all 4 parities (wave = parity), all 64 out-ch.
// Input tile 10x10x128 staged coalesced into LDS, pixel stride padded to
// 272 B (conflict-free ds_read_b128). Per wave: acc[4 ot][4 nt], 16 MFMA
// per K-step, K = 16 steps of 32 (4 taps x 128 ch).
// grid 2048 = 32 b x 8 tyt x 8 txt
// ============================================================================
__global__ __launch_bounds__(256) void k_tconv1m(const short* __restrict__ QrP,
    const short* __restrict__ wA, const float* __restrict__ bias,
    short* __restrict__ T1) {
  __shared__ short sX[13600];  // 100 pixels x 136 shorts (128 + 8 pad) = 27.2 KB
  int blk = blockIdx.x;
  int txt = blk & 7, tyt = (blk >> 3) & 7, b = blk >> 6;
  int my0 = tyt * 8, mx0 = txt * 8;
  int t = threadIdx.x;
  // stage QrP rows my0..my0+9, cols mx0..mx0+9 (coalesced short8 reads)
  for (int q = t; q < 1600; q += 256) {
    int p = q >> 4, seg = q & 15;
    int iy = p / 10, ix = p - iy * 10;
    short8 v = *(const short8*)(QrP +
        ((b * 66 + my0 + iy) * 66 + mx0 + ix) * 128 + seg * 8);
    *(short8*)((char*)sX + p * 272 + seg * 16) = v;
  }
  __syncthreads();
  int w = t >> 6, l = t & 63, lr = l & 15, g = l >> 4;
  int pyr = w >> 1, pxr = w & 1;
  // per-nt LDS byte base (tap dy=dx=0, ch-group 0)
  int Bb[4];
#pragma unroll
  for (int nt = 0; nt < 4; ++nt) {
    int p = nt * 16 + lr;
    int my = p >> 3, mx = p & 7;
    Bb[nt] = ((my + pyr + 1) * 10 + (mx + pxr + 1)) * 272 + g * 16;
  }
  const short* pAw = wA + w * 32768 + l * 8;  // parity-major weight block
  f32x4 acc[4][4] = {};
  short8 a[4], bfr[4], na[4], nb[4];
#pragma unroll
  for (int ot = 0; ot < 4; ++ot) a[ot] = *(const short8*)(pAw + ot * 512);
#pragma unroll
  for (int nt = 0; nt < 4; ++nt)
    bfr[nt] = *(const short8*)((const char*)sX + Bb[nt]);
  for (int kc = 0; kc < 15; ++kc) {
    int nk = kc + 1;
    int tt = nk >> 2, dy = tt >> 1, dx = tt & 1;
    int off = -(dy * 10 + dx) * 272 + (nk & 3) * 64;
#pragma unroll
    for (int ot = 0; ot < 4; ++ot)
      na[ot] = *(const short8*)(pAw + nk * 2048 + ot * 512);
#pragma unroll
    for (int nt = 0; nt < 4; ++nt)
      nb[nt] = *(const short8*)((const char*)sX + Bb[nt] + off);
#pragma unroll
    for (int ot = 0; ot < 4; ++ot)
#pragma unroll
      for (int nt = 0; nt < 4; ++nt)
        acc[ot][nt] = MFMA(a[ot], bfr[nt], acc[ot][nt]);
#pragma unroll
    for (int ot = 0; ot < 4; ++ot) a[ot] = na[ot];
#pragma unroll
    for (int nt = 0; nt < 4; ++nt) bfr[nt] = nb[nt];
  }
#pragma unroll
  for (int ot = 0; ot < 4; ++ot)
#pragma unroll
    for (int nt = 0; nt < 4; ++nt)
      acc[ot][nt] = MFMA(a[ot], bfr[nt], acc[ot][nt]);
  // epilogue: bias + relu + bf16 store
#pragma unroll
  for (int ot = 0; ot < 4; ++ot) {
    int o0 = ot * 16 + 4 * g;
    f32x4 b4 = *(const f32x4*)(bias + o0);
#pragma unroll
    for (int nt = 0; nt < 4; ++nt) {
      int p = nt * 16 + lr;
      int my = my0 + (p >> 3), mx = mx0 + (p & 7);
      int oy = 2 * my + pyr, ox = 2 * mx + pxr;
      short4v sv;
#pragma unroll
      for (int r = 0; r < 4; ++r)
        sv[r] = f2bf(fmaxf(acc[ot][nt][r] + b4[r], 0.f));
      *(short4v*)(T1 + ((b * 130 + oy + 1) * 130 + ox + 1) * 64 + o0) = sv;
    }
  }
}

// ============================================================================
// tconv2 VALU: T1[130,130,64] bf16 -> x_recon[32,256,256] f32
// ============================================================================
__global__ __launch_bounds__(256) void k_tconv2(const short* __restrict__ T1,
    const float* __restrict__ w, const float* __restrict__ bias,
    float* __restrict__ xrec) {
  __shared__ float sW[1024];
  int t = threadIdx.x;
  for (int e = t; e < 1024; e += 256) sW[e] = w[e];
  __syncthreads();
  int blk = blockIdx.x;
  int tx = blk & 15, ty = (blk >> 4) & 15, b = blk >> 8;
  int row = t >> 4, col = t & 15;
  int oy = ty * 16 + row, ox = tx * 16 + col;
  int pyr = oy & 1, pxr = ox & 1;
  int kye = 1 - pyr, kxe = 1 - pxr;
  int m = oy >> 1, n = ox >> 1;
  float acc = bias[0];
#pragma unroll
  for (int dy = 0; dy < 2; ++dy) {
#pragma unroll
    for (int dx = 0; dx < 2; ++dx) {
      const short* ip =
          T1 + ((b * 130 + m + pyr - dy + 1) * 130 + (n + pxr - dx + 1)) * 64;
      int tap = (kye + 2 * dy) * 4 + (kxe + 2 * dx);
#pragma unroll
      for (int c8 = 0; c8 < 8; ++c8) {
        short8 v = *(const short8*)(ip + c8 * 8);
#pragma unroll
        for (int i = 0; i < 8; ++i)
          acc = fmaf(bf2f(v[i]), sW[(c8 * 8 + i) * 16 + tap], acc);
      }
    }
  }
  xrec[(b * 256 + oy) * 256 + ox] = acc;
}

// ============================================================================
// finalize: loss from 1024 partials; perplexity from counts
// ============================================================================
__global__ __launch_bounds__(256) void k_final(const float* __restrict__ partials,
    const int* __restrict__ counts, float* __restrict__ out) {
  int t = threadIdx.x;
  float s = 0.f;
  for (int i = t; i < 1024; i += 256) s += partials[i];
#pragma unroll
  for (int m = 32; m >= 1; m >>= 1) s += __shfl_xor(s, m);
  __shared__ float sr[4];
  if ((t & 63) == 0) sr[t >> 6] = s;
  __syncthreads();
  if (t == 0) {
    float tot = sr[0] + sr[1] + sr[2] + sr[3];
    out[0] = 1.25f * tot / 16777216.0f;
  }
  float h = 0.f;
  for (int c = t; c < KC; c += 256) {
    float avg = (float)counts[c] / 131072.0f;
    h += avg * logf(avg + 1e-10f);
  }
#pragma unroll
  for (int m = 32; m >= 1; m >>= 1) h += __shfl_xor(h, m);
  __shared__ float sr2[4];
  if ((t & 63) == 0) sr2[t >> 6] = h;
  __syncthreads();
  if (t == 0) out[1 + 32 * 256 * 256] = expf(-(sr2[0] + sr2[1] + sr2[2] + sr2[3]));
}

// ============================================================================
extern "C" void kernel_launch(void* const* d_in, const int* in_sizes, int n_in,
                              void* d_out, int out_size, void* d_ws, size_t ws_size,
                              hipStream_t stream) {
  const float* x    = (const float*)d_in[0];
  const float* c1w  = (const float*)d_in[1];
  const float* c1b  = (const float*)d_in[2];
  const float* c2w  = (const float*)d_in[3];
  const float* c2b  = (const float*)d_in[4];
  const float* r1w3 = (const float*)d_in[5];
  const float* r1w1 = (const float*)d_in[6];
  const float* r2w3 = (const float*)d_in[7];
  const float* r2w1 = (const float*)d_in[8];
  const float* prew = (const float*)d_in[9];
  const float* preb = (const float*)d_in[10];
  const float* emb  = (const float*)d_in[11];
  const float* d1w3 = (const float*)d_in[12];
  const float* d1w1 = (const float*)d_in[13];
  const float* d2w3 = (const float*)d_in[14];
  const float* d2w1 = (const float*)d_in[15];
  const float* t1w  = (const float*)d_in[16];
  const float* t1b  = (const float*)d_in[17];
  const float* t2w  = (const float*)d_in[18];
  const float* t2b  = (const float*)d_in[19];
  float* out = (float*)d_out;

  char* ws = (char*)d_ws;
  short* buf0 = (short*)(ws);                      // A1 / T1 : 69,222,400 B
  float* bufX = (float*)(ws + 69222400);           // Xf / Zcat / Q : 67,108,864 B
  short* bufR = (short*)(ws + 136331264);          // XrP / QrP : 35,684,352 B
  short* Hr   = (short*)(ws + 172015616);          // 8,388,608 B -> ends 180404224
  int*   counts = (int*)(ws + 180928512);          // 2,048 B
  float* partials = (float*)(ws + 180930560);      // 8,192 B
  float* en   = (float*)(ws + 180938752);          // 2,048 B
  short* wAc2 = (short*)(ws + 180940800);          // 262,144 B
  short* wAr3 = (short*)(ws + 181202944);          // 294,912 B
  short* wAr1 = (short*)(ws + 181497856);          // 32,768 B
  short* wApre= (short*)(ws + 181530624);          // 32,768 B
  short* wAt1 = (short*)(ws + 181563392);          // 262,144 B
  short* Ecat = (short*)(ws + 181825536);          // 393,216 B -> ends 182,218,752

  short* Zcat = (short*)bufX;  // 67,108,864 B (Xf dead after enc res1addm#2;
                               // Q gather overwrites Zcat block-locally)

  short* wAr3_e1 = wAr3;
  short* wAr3_e2 = wAr3 + 36864;
  short* wAr3_d1 = wAr3 + 2 * 36864;
  short* wAr3_d2 = wAr3 + 3 * 36864;
  short* wAr1_e1 = wAr1;
  short* wAr1_e2 = wAr1 + 4096;
  short* wAr1_d1 = wAr1 + 2 * 4096;
  short* wAr1_d2 = wAr1 + 3 * 4096;

  hipMemsetAsync(counts, 0, KC * sizeof(int), stream);

  k_border  <<<256, 256, 0, stream>>>(buf0, bufR);
  k_perm_c2 <<<512, 256, 0, stream>>>(c2w, wAc2);
  k_perm_r3 <<<144, 256, 0, stream>>>(r1w3, wAr3_e1);
  k_perm_r3 <<<144, 256, 0, stream>>>(r2w3, wAr3_e2);
  k_perm_r3 <<<144, 256, 0, stream>>>(d1w3, wAr3_d1);
  k_perm_r3 <<<144, 256, 0, stream>>>(d2w3, wAr3_d2);
  k_perm_r1 <<<16, 256, 0, stream>>>(r1w1, wAr1_e1);
  k_perm_r1 <<<16, 256, 0, stream>>>(r2w1, wAr1_e2);
  k_perm_r1 <<<16, 256, 0, stream>>>(d1w1, wAr1_d1);
  k_perm_r1 <<<16, 256, 0, stream>>>(d2w1, wAr1_d2);
  k_perm_pre<<<64, 256, 0, stream>>>(prew, wApre);
  k_perm_t1 <<<512, 256, 0, stream>>>(t1w, wAt1);
  k_perm_E  <<<768, 256, 0, stream>>>(emb, Ecat);
  k_embnorm <<<512, 64, 0, stream>>>(emb, en);

  k_conv1   <<<4096, 256, 0, stream>>>(x, c1w, c1b, buf0);
  k_conv2m  <<<2048, 256, 0, stream>>>(buf0, wAc2, c2b, bufX, bufR);
  k_res3m   <<<1024, 256, 0, stream>>>(bufR, wAr3_e1, Hr);
  k_res1addm<<<2048, 256, 0, stream>>>(Hr, wAr1_e1, bufX, bufR);
  k_res3m   <<<1024, 256, 0, stream>>>(bufR, wAr3_e2, Hr);
  k_res1addm<<<2048, 256, 0, stream>>>(Hr, wAr1_e2, bufX, bufR);
  k_prem    <<<2048, 256, 0, stream>>>(bufR, wApre, preb, Zcat);
  k_vqm7    <<<1024, 256, 0, stream>>>(Zcat, Ecat, en, emb, counts, partials,
                                       bufX, bufR);
  k_res3m   <<<1024, 256, 0, stream>>>(bufR, wAr3_d1, Hr);
  k_res1addm<<<2048, 256, 0, stream>>>(Hr, wAr1_d1, bufX, bufR);
  k_res3m   <<<1024, 256, 0, stream>>>(bufR, wAr3_d2, Hr);
  k_res1addm<<<2048, 256, 0, stream>>>(Hr, wAr1_d2, bufX, bufR);
  k_tconv1m <<<2048, 256, 0, stream>>>(bufR, wAt1, t1b, buf0);
  k_tconv2  <<<8192, 256, 0, stream>>>(buf0, t2w, t2b, out + 1);
  k_final   <<<1, 256, 0, stream>>>(partials, counts, out);
}

// Round 8
// 680.969 us; speedup vs baseline: 1.1445x; 1.1441x over previous
//
#include <hip/hip_runtime.h>
#include <math.h>

#define KC 512
#define DD 128

typedef __attribute__((ext_vector_type(8))) short short8;
typedef __attribute__((ext_vector_type(4))) short short4v;
typedef __attribute__((ext_vector_type(4))) float f32x4;

#define MFMA(a, b, c) __builtin_amdgcn_mfma_f32_16x16x32_bf16(a, b, c, 0, 0, 0)

__device__ __forceinline__ short f2bf(float f) {
  unsigned u = __float_as_uint(f);
  u = (u + 0x7FFFu + ((u >> 16) & 1u)) >> 16;
  return (short)u;
}
__device__ __forceinline__ float bf2f(short s) {
  return __uint_as_float(((unsigned)(unsigned short)s) << 16);
}

// ============================================================================
// weight permutation kernels (A-fragment order)
// ============================================================================
__global__ __launch_bounds__(256) void k_perm_c2(const float* __restrict__ w,
                                                 short* __restrict__ dst) {
  int e = blockIdx.x * 256 + threadIdx.x;  // < 131072
  int j = e & 7, l = (e >> 3) & 63, ot = (e >> 9) & 7, kc = e >> 12;
  int o = ot * 16 + (l & 15), g = l >> 4;
  int tap = kc >> 1, ci = (kc & 1) * 32 + 8 * g + j;
  dst[e] = f2bf(w[(o * 64 + ci) * 16 + tap]);
}

__global__ __launch_bounds__(256) void k_perm_r3(const float* __restrict__ w,
                                                 short* __restrict__ dst) {
  int e = blockIdx.x * 256 + threadIdx.x;  // < 36864
  int j = e & 7, l = (e >> 3) & 63, ot = (e >> 9) & 1, kc = e >> 10;
  int o = ot * 16 + (l & 15), g = l >> 4;
  int tap = kc >> 2, ci = (kc & 3) * 32 + 8 * g + j;
  dst[e] = f2bf(w[(o * 128 + ci) * 9 + tap]);
}

__global__ __launch_bounds__(256) void k_perm_r1(const float* __restrict__ w,
                                                 short* __restrict__ dst) {
  int e = blockIdx.x * 256 + threadIdx.x;  // < 4096
  int j = e & 7, l = (e >> 3) & 63, ot = e >> 9;
  int o = ot * 16 + (l & 15), g = l >> 4;
  int ci = 8 * g + j;
  dst[e] = f2bf(w[o * 32 + ci]);
}

__global__ __launch_bounds__(256) void k_perm_pre(const float* __restrict__ w,
                                                  short* __restrict__ dst) {
  int e = blockIdx.x * 256 + threadIdx.x;  // < 16384
  int j = e & 7, l = (e >> 3) & 63, ot = (e >> 9) & 7, kc = e >> 12;
  int o = ot * 16 + (l & 15), g = l >> 4;
  int ci = kc * 32 + 8 * g + j;
  dst[e] = f2bf(w[o * 128 + ci]);
}

__global__ __launch_bounds__(256) void k_perm_t1(const float* __restrict__ w,
                                                 short* __restrict__ dst) {
  int e = blockIdx.x * 256 + threadIdx.x;  // < 131072
  int j = e & 7, l = (e >> 3) & 63, ot = (e >> 9) & 3, kc = (e >> 11) & 15,
      pp = e >> 15;
  int pyr = pp >> 1, pxr = pp & 1;
  int o = ot * 16 + (l & 15), g = l >> 4;
  int tt = kc >> 2, dy = tt >> 1, dx = tt & 1;
  int ky = (1 - pyr) + 2 * dy, kx = (1 - pxr) + 2 * dx;
  int ci = (kc & 3) * 32 + 8 * g + j;
  dst[e] = f2bf(w[(ci * 64 + o) * 16 + ky * 4 + kx]);
}

// ============================================================================
// Ecat permute: emb[512][128] f32 -> Ecat bf16 in A-fragment order over K=384:
// K [0:256) = eh (duplicated), [256:384) = el. e=((kc*32+ot)*64+l)*8+j
// grid 768 x 256 (196608 elems)
// ============================================================================
__global__ __launch_bounds__(256) void k_perm_E(const float* __restrict__ emb,
                                                short* __restrict__ dst) {
  int e = blockIdx.x * 256 + threadIdx.x;
  int j = e & 7, l = (e >> 3) & 63, ot = (e >> 9) & 31, kc = e >> 14;
  int c = ot * 16 + (l & 15);
  int k = kc * 32 + 8 * (l >> 4) + j;
  float v = emb[c * DD + (k & 127)];
  short hi = f2bf(v);
  dst[e] = (k < 256) ? hi : f2bf(v - bf2f(hi));
}

// ============================================================================
// emb norms (exact f32)
// ============================================================================
__global__ __launch_bounds__(64) void k_embnorm(const float* __restrict__ emb,
                                                float* __restrict__ en) {
  int c = blockIdx.x, l = threadIdx.x;
  float a = emb[c * DD + l], b = emb[c * DD + 64 + l];
  float s = a * a + b * b;
#pragma unroll
  for (int m = 32; m >= 1; m >>= 1) s += __shfl_xor(s, m);
  if (l == 0) en[c] = s;
}

// ============================================================================
// border zero: A1[32,130,130,64] and XrP[32,66,66,128] padding rings only
// (replaces 104 MB of full-buffer memset with 8.4 MB of border writes).
// grid 256 = 32 b x 8 slices, 256 thr.
// ============================================================================
__global__ __launch_bounds__(256) void k_border(short* __restrict__ A1,
                                                short* __restrict__ XrP) {
  int blk = blockIdx.x;
  int b = blk >> 3;
  int tid = ((blk & 7) << 8) + threadIdx.x;  // 0..2047
  short8 z8 = {};
  long baseA = (long)b * 1081600;  // 130*130*64
  // A1 top/bottom rows: 2 x 1040 short8
  for (int e = tid; e < 2080; e += 2048) {
    int r = e >= 1040;
    int rem = r ? e - 1040 : e;
    *(short8*)(A1 + baseA + (r ? 129L * 130 * 64 : 0) + rem * 8) = z8;
  }
  // A1 left/right cols, rows 1..128: 2048 short8 (exactly one per tid)
  {
    int c = tid >> 10, rem = tid & 1023;
    int row = 1 + (rem >> 3), s8 = rem & 7;
    *(short8*)(A1 + baseA + (row * 130L + (c ? 129 : 0)) * 64 + s8 * 8) = z8;
  }
  long baseX = (long)b * 557568;  // 66*66*128
  // XrP top/bottom rows: 2 x 1056 short8
  for (int e = tid; e < 2112; e += 2048) {
    int r = e >= 1056;
    int rem = r ? e - 1056 : e;
    *(short8*)(XrP + baseX + (r ? 65L * 66 * 128 : 0) + rem * 8) = z8;
  }
  // XrP left/right cols, rows 1..64: 2048 short8
  {
    int c = tid >> 10, rem = tid & 1023;
    int row = 1 + (rem >> 4), s8 = rem & 15;
    *(short8*)(XrP + baseX + (row * 66L + (c ? 65 : 0)) * 128 + s8 * 8) = z8;
  }
}

// ============================================================================
// conv1: x[32,1,256,256] f32 -> A1[32,130,130,64] bf16 relu (padded, ch-last)
// grid 4096 = 32 b x 128 y
// ============================================================================
__global__ __launch_bounds__(256) void k_conv1(const float* __restrict__ x,
    const float* __restrict__ w, const float* __restrict__ bias,
    short* __restrict__ A1) {
  __shared__ float sXp[4 * 260];
  __shared__ float sWt[16 * 64];
  int blk = blockIdx.x;
  int y = blk & 127, b = blk >> 7;
  int t = threadIdx.x;
  for (int e = t; e < 1024; e += 256) sWt[e] = w[(e & 63) * 16 + (e >> 6)];
  if (t < 4) {
    sXp[t * 260] = 0.f;
    sXp[t * 260 + 257] = 0.f;
    sXp[t * 260 + 258] = 0.f;
    sXp[t * 260 + 259] = 0.f;
  }
  for (int e = t; e < 1024; e += 256) {
    int r = e >> 8, col = e & 255;
    int giy = 2 * y - 1 + r;
    float v = 0.f;
    if ((unsigned)giy < 256u) v = x[(b * 256 + giy) * 256 + col];
    sXp[r * 260 + col + 1] = v;
  }
  __syncthreads();
  int og = t >> 6, l = t & 63, o0 = og * 16;
  float acc0[16], acc1[16];
#pragma unroll
  for (int oo = 0; oo < 16; ++oo) { acc0[oo] = 0.f; acc1[oo] = 0.f; }
  int xA = 2 * l, xB = 2 * l + 128;
#pragma unroll
  for (int ky = 0; ky < 4; ++ky) {
#pragma unroll
    for (int kx = 0; kx < 4; ++kx) {
      float a0 = sXp[ky * 260 + xA + kx];
      float a1 = sXp[ky * 260 + xB + kx];
      const float* wrow = &sWt[(ky * 4 + kx) * 64 + o0];
#pragma unroll
      for (int oo = 0; oo < 16; ++oo) {
        float wv = wrow[oo];
        acc0[oo] = fmaf(a0, wv, acc0[oo]);
        acc1[oo] = fmaf(a1, wv, acc1[oo]);
      }
    }
  }
  long base0 = (((long)(b * 130 + y + 1)) * 130 + l + 1) * 64 + o0;
  long base1 = base0 + 64 * 64;
  short8 s0a, s0b, s1a, s1b;
#pragma unroll
  for (int oo = 0; oo < 8; ++oo) {
    s0a[oo] = f2bf(fmaxf(acc0[oo] + bias[o0 + oo], 0.f));
    s0b[oo] = f2bf(fmaxf(acc0[oo + 8] + bias[o0 + oo + 8], 0.f));
    s1a[oo] = f2bf(fmaxf(acc1[oo] + bias[o0 + oo], 0.f));
    s1b[oo] = f2bf(fmaxf(acc1[oo + 8] + bias[o0 + oo + 8], 0.f));
  }
  *(short8*)(A1 + base0) = s0a;
  *(short8*)(A1 + base0 + 8) = s0b;
  *(short8*)(A1 + base1) = s1a;
  *(short8*)(A1 + base1 + 8) = s1b;
}

// ============================================================================
// conv2 MFMA v2 (LDS-staged): A1[130,130,64] bf16 -> relu -> Xf[64,64,128] f32
// + XrP[66,66,128] bf16. Block = 8x8 out-px, input tile 18x18x64 staged into
// LDS once (whole K-loop reuses it). Pixel stride 136 B -> conflict-free
// ds_read_b128 (bank = 2*pix+4g mod 32: 8 quads x 2-way).
// grid 2048 = 32 b x 8 by x 8 bx
// ============================================================================
__global__ __launch_bounds__(256) void k_conv2m(const short* __restrict__ A1,
    const short* __restrict__ wA, const float* __restrict__ bias,
    float* __restrict__ Xf, short* __restrict__ XrP) {
  __shared__ short sX[22032];  // 324 px * 68 shorts (136 B) = 44,064 B
  int blk = blockIdx.x;
  int bx = blk & 7, by = (blk >> 3) & 7, b = blk >> 6;
  int t = threadIdx.x;
  int R0 = by * 16, C0 = bx * 16;
  for (int q = t; q < 2592; q += 256) {
    int p = q >> 3, seg = q & 7;
    int iy = p / 18, ix = p - iy * 18;
    short8 v = *(const short8*)(A1 +
        (((long)b * 130 + R0 + iy) * 130 + C0 + ix) * 64 + seg * 8);
    *(short8*)((char*)sX + p * 136 + seg * 16) = v;
  }
  __syncthreads();
  int w = t >> 6, l = t & 63, lr = l & 15, g = l >> 4;
  int Bb[4];
#pragma unroll
  for (int pt = 0; pt < 4; ++pt) {
    int p = pt * 16 + lr;
    int lp = 2 * (p >> 3) * 18 + 2 * (p & 7);
    Bb[pt] = lp * 136 + g * 16;
  }
  const short* pA0 = wA + (2 * w * 64 + l) * 8;
  const short* pA1 = pA0 + 512;
  f32x4 acc[2][4] = {};
  short8 a0 = *(const short8*)pA0;
  short8 a1 = *(const short8*)pA1;
  short8 bv[4];
#pragma unroll
  for (int i = 0; i < 4; ++i)
    bv[i] = *(const short8*)((const char*)sX + Bb[i]);
  for (int kc = 0; kc < 31; ++kc) {
    int nk = kc + 1;
    int tap = nk >> 1;
    int off = ((tap >> 2) * 18 + (tap & 3)) * 136 + (nk & 1) * 64;
    short8 na0 = *(const short8*)(pA0 + nk * 4096);
    short8 na1 = *(const short8*)(pA1 + nk * 4096);
    short8 nb[4];
#pragma unroll
    for (int i = 0; i < 4; ++i)
      nb[i] = *(const short8*)((const char*)sX + Bb[i] + off);
#pragma unroll
    for (int i = 0; i < 4; ++i) {
      acc[0][i] = MFMA(a0, bv[i], acc[0][i]);
      acc[1][i] = MFMA(a1, bv[i], acc[1][i]);
    }
    a0 = na0; a1 = na1;
#pragma unroll
    for (int i = 0; i < 4; ++i) bv[i] = nb[i];
  }
#pragma unroll
  for (int i = 0; i < 4; ++i) {
    acc[0][i] = MFMA(a0, bv[i], acc[0][i]);
    acc[1][i] = MFMA(a1, bv[i], acc[1][i]);
  }
#pragma unroll
  for (int oi = 0; oi < 2; ++oi) {
    int o0 = (2 * w + oi) * 16 + 4 * g;
#pragma unroll
    for (int pt = 0; pt < 4; ++pt) {
      int p = pt * 16 + lr;
      int y = by * 8 + (p >> 3), x = bx * 8 + (p & 7);
      f32x4 nv; short4v sv;
#pragma unroll
      for (int r = 0; r < 4; ++r) {
        float v = fmaxf(acc[oi][pt][r] + bias[o0 + r], 0.f);
        nv[r] = v; sv[r] = f2bf(v);
      }
      *(f32x4*)(Xf + ((b * 64 + y) * 64 + x) * 128 + o0) = nv;
      *(short4v*)(XrP + ((b * 66 + y + 1) * 66 + x + 1) * 128 + o0) = sv;
    }
  }
}

// ============================================================================
// res3 MFMA v2 (LDS-staged): XrP[66,66,128] -> Hr[64,64,32] bf16 relu
// Block = 8x16 out-px; input tile 10x18x128 staged into LDS with XOR swizzle
// (inner ^ ((pix&7)<<4)) -> conflict-free ds_read_b128. Wave w owns rows
// 2w,2w+1; 4 MFMA / 2 ds_read per K-step, 36 steps.
// grid 1024 = 32 b x 8 yt x 4 tx
// ============================================================================
__global__ __launch_bounds__(256) void k_res3m(const short* __restrict__ XrP,
    const short* __restrict__ wA, short* __restrict__ Hr) {
  __shared__ short sX[23040];  // 180 px * 128 shorts (256 B swizzled) = 46,080 B
  int blk = blockIdx.x;
  int tx = blk & 3, yt = (blk >> 2) & 7, b = blk >> 5;
  int t = threadIdx.x;
  int r0 = yt * 8, c0 = tx * 16;
  for (int q = t; q < 2880; q += 256) {
    int p = q >> 4, seg = q & 15;
    int iy = p / 18, ix = p - iy * 18;
    short8 v = *(const short8*)(XrP +
        (((long)b * 66 + r0 + iy) * 66 + c0 + ix) * 128 + seg * 8);
    *(short8*)((char*)sX + p * 256 + ((seg * 16) ^ ((p & 7) << 4))) = v;
  }
  __syncthreads();
  int w = t >> 6, l = t & 63, lr = l & 15, g = l >> 4;
  const short* pA0 = wA + l * 8;
  const short* pA1 = pA0 + 512;
  f32x4 acc[2][2] = {};
  short8 a0 = *(const short8*)pA0;
  short8 a1 = *(const short8*)pA1;
  short8 bv[2];
#pragma unroll
  for (int j = 0; j < 2; ++j) {
    int lp = (2 * w + j) * 18 + lr;
    bv[j] = *(const short8*)((const char*)sX + lp * 256 +
                             ((g * 16) ^ ((lp & 7) << 4)));
  }
  for (int kc = 0; kc < 35; ++kc) {
    int nk = kc + 1;
    int tap = nk >> 2;
    int ky = tap / 3, kx = tap - ky * 3;
    int inner = g * 16 + (nk & 3) * 64;
    short8 na0 = *(const short8*)(pA0 + nk * 1024);
    short8 na1 = *(const short8*)(pA1 + nk * 1024);
    short8 nb[2];
#pragma unroll
    for (int j = 0; j < 2; ++j) {
      int lp = (2 * w + j + ky) * 18 + lr + kx;
      nb[j] = *(const short8*)((const char*)sX + lp * 256 +
                               (inner ^ ((lp & 7) << 4)));
    }
#pragma unroll
    for (int j = 0; j < 2; ++j) {
      acc[0][j] = MFMA(a0, bv[j], acc[0][j]);
      acc[1][j] = MFMA(a1, bv[j], acc[1][j]);
    }
    a0 = na0; a1 = na1;
    bv[0] = nb[0]; bv[1] = nb[1];
  }
#pragma unroll
  for (int j = 0; j < 2; ++j) {
    acc[0][j] = MFMA(a0, bv[j], acc[0][j]);
    acc[1][j] = MFMA(a1, bv[j], acc[1][j]);
  }
#pragma unroll
  for (int oi = 0; oi < 2; ++oi) {
    int o0 = oi * 16 + 4 * g;
#pragma unroll
    for (int j = 0; j < 2; ++j) {
      int y = r0 + 2 * w + j, x = c0 + lr;
      short4v sv;
#pragma unroll
      for (int r = 0; r < 4; ++r) sv[r] = f2bf(fmaxf(acc[oi][j][r], 0.f));
      *(short4v*)(Hr + ((b * 64 + y) * 64 + x) * 32 + o0) = sv;
    }
  }
}

// ============================================================================
// res1+add MFMA v2 (LDS-staged): Hr[64,64,32] -> Xf += conv1x1 ;
// XrP = relu(Xf) bf16. Hr tile (64 px x 32 ch = 4 KB) staged cooperatively
// (1 short8/thread, coalesced) with pixel stride 80 B -> quad (5p+g)%8
// uniform 8 lanes/quad = conflict-free b128.
// grid 2048 = 32 b x 8 by x 8 bx
// ============================================================================
__global__ __launch_bounds__(256) void k_res1addm(const short* __restrict__ Hr,
    const short* __restrict__ wA, float* __restrict__ Xf,
    short* __restrict__ XrP) {
  __shared__ short sH[64 * 40];  // 64 px * 40 sh (80 B stride) = 5,120 B
  int blk = blockIdx.x;
  int bx = blk & 7, by = (blk >> 3) & 7, b = blk >> 6;
  int t = threadIdx.x, w = t >> 6, l = t & 63, lr = l & 15, g = l >> 4;
  {
    int p = t >> 2, seg = t & 3;
    int y = by * 8 + (p >> 3), x = bx * 8 + (p & 7);
    short8 v = *(const short8*)(Hr + ((b * 64 + y) * 64 + x) * 32 + seg * 8);
    *(short8*)(sH + p * 40 + seg * 8) = v;
  }
  __syncthreads();
  f32x4 acc[2][4] = {};
  short8 a0 = *(const short8*)(wA + (2 * w * 64 + l) * 8);
  short8 a1 = *(const short8*)(wA + ((2 * w + 1) * 64 + l) * 8);
#pragma unroll
  for (int i = 0; i < 4; ++i) {
    int p = i * 16 + lr;
    short8 bv = *(const short8*)(sH + p * 40 + 8 * g);
    acc[0][i] = MFMA(a0, bv, acc[0][i]);
    acc[1][i] = MFMA(a1, bv, acc[1][i]);
  }
#pragma unroll
  for (int oi = 0; oi < 2; ++oi) {
    int o0 = (2 * w + oi) * 16 + 4 * g;
#pragma unroll
    for (int i = 0; i < 4; ++i) {
      int p = i * 16 + lr;
      int y = by * 8 + (p >> 3), x = bx * 8 + (p & 7);
      float* xp = Xf + ((b * 64 + y) * 64 + x) * 128 + o0;
      f32x4 old = *(f32x4*)xp;
      f32x4 nv; short4v sv;
#pragma unroll
      for (int r = 0; r < 4; ++r) {
        nv[r] = old[r] + acc[oi][i][r];
        sv[r] = f2bf(fmaxf(nv[r], 0.f));
      }
      *(f32x4*)xp = nv;
      *(short4v*)(XrP + ((b * 66 + y + 1) * 66 + x + 1) * 128 + o0) = sv;
    }
  }
}

// ============================================================================
// pre 1x1 MFMA v2 (LDS-staged): XrP[66,66,128] -> Zcat[pix][256] bf16 =
// [zhi(128) | zlo(128)]. XrP tile (64 px x 128 ch = 16 KB) staged with the
// res3m XOR swizzle -> conflict-free b128 reads. K=4 steps, register-light.
// grid 2048 (8x8 pixels).
// ============================================================================
__global__ __launch_bounds__(256) void k_prem(const short* __restrict__ XrP,
    const short* __restrict__ wA, const float* __restrict__ bias,
    short* __restrict__ Zc) {
  __shared__ short sX[8192];  // 64 px * 128 sh, swizzled = 16 KB
  int blk = blockIdx.x;
  int bx = blk & 7, by = (blk >> 3) & 7, b = blk >> 6;
  int t = threadIdx.x, w = t >> 6, l = t & 63, lr = l & 15, g = l >> 4;
  for (int q = t; q < 1024; q += 256) {
    int p = q >> 4, seg = q & 15;
    int y = by * 8 + (p >> 3), x = bx * 8 + (p & 7);
    short8 v = *(const short8*)(XrP +
        ((b * 66 + y + 1) * 66 + x + 1) * 128 + seg * 8);
    *(short8*)((char*)sX + p * 256 + ((seg * 16) ^ ((p & 7) << 4))) = v;
  }
  __syncthreads();
  const short* pA0 = wA + (2 * w * 64 + l) * 8;
  const short* pA1 = pA0 + 512;
  f32x4 acc[2][4] = {};
#pragma unroll
  for (int kc = 0; kc < 4; ++kc) {
    short8 a0 = *(const short8*)(pA0 + kc * 4096);
    short8 a1 = *(const short8*)(pA1 + kc * 4096);
#pragma unroll
    for (int i = 0; i < 4; ++i) {
      int p = i * 16 + lr;
      short8 bv = *(const short8*)((const char*)sX + p * 256 +
                                   ((kc * 64 + g * 16) ^ ((p & 7) << 4)));
      acc[0][i] = MFMA(a0, bv, acc[0][i]);
      acc[1][i] = MFMA(a1, bv, acc[1][i]);
    }
  }
#pragma unroll
  for (int oi = 0; oi < 2; ++oi) {
    int o0 = (2 * w + oi) * 16 + 4 * g;
#pragma unroll
    for (int pt = 0; pt < 4; ++pt) {
      int p = pt * 16 + lr;
      int y = by * 8 + (p >> 3), x = bx * 8 + (p & 7);
      long pix = (long)(b * 64 + y) * 64 + x;
      short4v hv, lv;
#pragma unroll
      for (int r = 0; r < 4; ++r) {
        float v = acc[oi][pt][r] + bias[o0 + r];
        short hi = f2bf(v);
        hv[r] = hi;
        lv[r] = f2bf(v - bf2f(hi));
      }
      *(short4v*)(Zc + pix * 256 + o0) = hv;
      *(short4v*)(Zc + pix * 256 + 128 + o0) = lv;
    }
  }
}

// ============================================================================
// VQ MFMA v5 (proven 132 us, clean counters): 64 px x 512 codes, Z tile in
// LDS (32 KB, XOR swizzle). Wave w: codes [w*128,(w+1)*128) as 2 chunks of
// 64 (acc[4][4]). Fully unrolled 12-step K-loop (compiler pipelines within
// its own reg budget - no launch-bounds cap, no explicit dbuf). Fused
// argmin + hist + loss (wave-0 shfl reduce) + gather.
// grid 2048 = 131072/64.
// ============================================================================
__global__ __launch_bounds__(256) void k_vqm5(const short* __restrict__ Zc,
    const short* __restrict__ Ec, const float* __restrict__ en,
    const float* __restrict__ emb, int* __restrict__ counts,
    float* __restrict__ partials, float* __restrict__ Q,
    short* __restrict__ QrP) {
  __shared__ short sZ[16384];  // 64 px * 256 sh, swizzled = 32 KB
  __shared__ float sV[4][64];
  __shared__ int sC[4][64];
  __shared__ float sZn[64];
  __shared__ int sIdx[64];
  __shared__ int sHist[KC];
  int blk = blockIdx.x;
  long pix0 = (long)blk * 64;
  int t = threadIdx.x, w = t >> 6, l = t & 63, c16 = l & 15, g = l >> 4;
  for (int e = t; e < KC; e += 256) sHist[e] = 0;

  // stage Z tile: swizzle inner-byte ^ ((pix&7)<<4)
  for (int q = t; q < 2048; q += 256) {
    int p = q >> 5, seg = q & 31;
    short8 v = *(const short8*)(Zc + (pix0 + p) * 256 + seg * 8);
    *(short8*)((char*)sZ + p * 512 + ((seg * 16) ^ ((p & 7) << 4))) = v;
  }
  __syncthreads();

  // ||z||^2 per pixel from LDS: 4 threads/pixel, each 32 dims
  {
    int pz = t >> 2, seg4 = t & 3;
    const char* zb = (const char*)sZ + pz * 512;
    int swp = (pz & 7) << 4;
    float s = 0.f;
#pragma unroll
    for (int qq = 0; qq < 4; ++qq) {
      int ih = seg4 * 64 + 16 * qq;  // zh inner byte
      short8 h8 = *(const short8*)(zb + (ih ^ swp));
      short8 l8 = *(const short8*)(zb + ((ih + 256) ^ swp));
#pragma unroll
      for (int j = 0; j < 8; ++j) {
        float zv = bf2f(h8[j]) + bf2f(l8[j]);
        s = fmaf(zv, zv, s);
      }
    }
    s += __shfl_xor(s, 1);
    s += __shfl_xor(s, 2);
    if (seg4 == 0) sZn[pz] = s;
  }

  // GEMM: 2 chunks of 64 codes; 12 K-steps of 32 each (fully unrolled).
  int sw = (c16 & 7) << 4;
  int zrow = c16 * 512;
  float bvv[4];
  int bcc[4];
#pragma unroll
  for (int pt = 0; pt < 4; ++pt) { bvv[pt] = 3.4e38f; bcc[pt] = 0; }
  const short* pE = Ec + (w * 8) * 512 + l * 8;
  for (int cc = 0; cc < 2; ++cc) {
    const short* pA = pE + cc * 2048;
    f32x4 acc[4][4] = {};
#pragma unroll
    for (int kc = 0; kc < 12; ++kc) {
      int koff = kc < 8 ? kc : kc - 8;
      int inn = ((koff * 64 + g * 16) ^ sw);
      const char* zb = (const char*)sZ + zrow + inn;
      short8 b0 = *(const short8*)zb;
      short8 b1 = *(const short8*)(zb + 8192);
      short8 b2 = *(const short8*)(zb + 16384);
      short8 b3 = *(const short8*)(zb + 24576);
      short8 a0 = *(const short8*)(pA + kc * 16384);
      short8 a1 = *(const short8*)(pA + kc * 16384 + 512);
      short8 a2 = *(const short8*)(pA + kc * 16384 + 1024);
      short8 a3 = *(const short8*)(pA + kc * 16384 + 1536);
      acc[0][0] = MFMA(a0, b0, acc[0][0]);
      acc[0][1] = MFMA(a0, b1, acc[0][1]);
      acc[0][2] = MFMA(a0, b2, acc[0][2]);
      acc[0][3] = MFMA(a0, b3, acc[0][3]);
      acc[1][0] = MFMA(a1, b0, acc[1][0]);
      acc[1][1] = MFMA(a1, b1, acc[1][1]);
      acc[1][2] = MFMA(a1, b2, acc[1][2]);
      acc[1][3] = MFMA(a1, b3, acc[1][3]);
      acc[2][0] = MFMA(a2, b0, acc[2][0]);
      acc[2][1] = MFMA(a2, b1, acc[2][1]);
      acc[2][2] = MFMA(a2, b2, acc[2][2]);
      acc[2][3] = MFMA(a2, b3, acc[2][3]);
      acc[3][0] = MFMA(a3, b0, acc[3][0]);
      acc[3][1] = MFMA(a3, b1, acc[3][1]);
      acc[3][2] = MFMA(a3, b2, acc[3][2]);
      acc[3][3] = MFMA(a3, b3, acc[3][3]);
    }
    // running argmin update for this chunk (codes ascend: cc, ct, r)
#pragma unroll
    for (int ct = 0; ct < 4; ++ct) {
      f32x4 en4 = *(const f32x4*)(en + w * 128 + cc * 64 + ct * 16 + 4 * g);
#pragma unroll
      for (int pt = 0; pt < 4; ++pt) {
#pragma unroll
        for (int r = 0; r < 4; ++r) {
          float d = en4[r] - 2.f * acc[ct][pt][r];
          int code = w * 128 + cc * 64 + ct * 16 + 4 * g + r;
          if (d < bvv[pt]) { bvv[pt] = d; bcc[pt] = code; }
        }
      }
    }
  }
  // cross-lane reduce (over g) per pixel
#pragma unroll
  for (int pt = 0; pt < 4; ++pt) {
    float bv = bvv[pt];
    int bc = bcc[pt];
#pragma unroll
    for (int m = 16; m <= 32; m <<= 1) {
      float ov = __shfl_xor(bv, m);
      int oc = __shfl_xor(bc, m);
      if (ov < bv || (ov == bv && oc < bc)) { bv = ov; bc = oc; }
    }
    if (g == 0) {
      sV[w][pt * 16 + c16] = bv;
      sC[w][pt * 16 + c16] = bc;
    }
  }
  __syncthreads();
  if (t < 64) {
    float bv = sV[0][t];
    int bc = sC[0][t];
#pragma unroll
    for (int w2 = 1; w2 < 4; ++w2) {
      float v = sV[w2][t];
      int c = sC[w2][t];
      if (v < bv || (v == bv && c < bc)) { bv = v; bc = c; }
    }
    sIdx[t] = bc;
    atomicAdd(&sHist[bc], 1);
    // loss partial: wave-0 parallel reduce
    float ls = bv + sZn[t];
#pragma unroll
    for (int m = 32; m >= 1; m >>= 1) ls += __shfl_xor(ls, m);
    if (t == 0) partials[blk] = ls;
  }
  __syncthreads();
  for (int e = t; e < KC; e += 256) {
    int c = sHist[e];
    if (c) atomicAdd(&counts[e], c);
  }
  // fused gather: Q = emb[idx] f32 (overwrites this block's Zc bytes),
  // QrP = relu bf16 (padded layout)
  for (int e = t; e < 2048; e += 256) {
    int p = e >> 5, d4 = (e & 31) << 2;
    int c = sIdx[p];
    f32x4 q = *(const f32x4*)(emb + c * DD + d4);
    *(f32x4*)(Q + (pix0 + p) * DD + d4) = q;
    short4v sv;
#pragma unroll
    for (int r = 0; r < 4; ++r) sv[r] = f2bf(fmaxf(q[r], 0.f));
    long pixg = pix0 + p;
    int xx = (int)(pixg & 63), yy = (int)((pixg >> 6) & 63),
        bb = (int)(pixg >> 12);
    *(short4v*)(QrP + (((long)(bb * 66 + yy + 1)) * 66 + xx + 1) * 128 + d4) =
        sv;
  }
}

// ============================================================================
// tconv1 MFMA v2 (LDS-staged): QrP[66,66,128] -> T1[130,130,64] bf16 relu
// Block = 8x8 m-tile, all 4 parities (wave = parity), all 64 out-ch.
// Input tile 10x10x128 staged coalesced into LDS, pixel stride padded to
// 272 B (conflict-free ds_read_b128). Per wave: acc[4 ot][4 nt], 16 MFMA
// per K-step, K = 16 steps of 32 (4 taps x 128 ch).
// grid 2048 = 32 b x 8 tyt x 8 txt
// ============================================================================
__global__ __launch_bounds__(256) void k_tconv1m(const short* __restrict__ QrP,
    const short* __restrict__ wA, const float* __restrict__ bias,
    short* __restrict__ T1) {
  __shared__ short sX[13600];  // 100 pixels x 136 shorts (128 + 8 pad) = 27.2 KB
  int blk = blockIdx.x;
  int txt = blk & 7, tyt = (blk >> 3) & 7, b = blk >> 6;
  int my0 = tyt * 8, mx0 = txt * 8;
  int t = threadIdx.x;
  // stage QrP rows my0..my0+9, cols mx0..mx0+9 (coalesced short8 reads)
  for (int q = t; q < 1600; q += 256) {
    int p = q >> 4, seg = q & 15;
    int iy = p / 10, ix = p - iy * 10;
    short8 v = *(const short8*)(QrP +
        ((b * 66 + my0 + iy) * 66 + mx0 + ix) * 128 + seg * 8);
    *(short8*)((char*)sX + p * 272 + seg * 16) = v;
  }
  __syncthreads();
  int w = t >> 6, l = t & 63, lr = l & 15, g = l >> 4;
  int pyr = w >> 1, pxr = w & 1;
  // per-nt LDS byte base (tap dy=dx=0, ch-group 0)
  int Bb[4];
#pragma unroll
  for (int nt = 0; nt < 4; ++nt) {
    int p = nt * 16 + lr;
    int my = p >> 3, mx = p & 7;
    Bb[nt] = ((my + pyr + 1) * 10 + (mx + pxr + 1)) * 272 + g * 16;
  }
  const short* pAw = wA + w * 32768 + l * 8;  // parity-major weight block
  f32x4 acc[4][4] = {};
  short8 a[4], bfr[4], na[4], nb[4];
#pragma unroll
  for (int ot = 0; ot < 4; ++ot) a[ot] = *(const short8*)(pAw + ot * 512);
#pragma unroll
  for (int nt = 0; nt < 4; ++nt)
    bfr[nt] = *(const short8*)((const char*)sX + Bb[nt]);
  for (int kc = 0; kc < 15; ++kc) {
    int nk = kc + 1;
    int tt = nk >> 2, dy = tt >> 1, dx = tt & 1;
    int off = -(dy * 10 + dx) * 272 + (nk & 3) * 64;
#pragma unroll
    for (int ot = 0; ot < 4; ++ot)
      na[ot] = *(const short8*)(pAw + nk * 2048 + ot * 512);
#pragma unroll
    for (int nt = 0; nt < 4; ++nt)
      nb[nt] = *(const short8*)((const char*)sX + Bb[nt] + off);
#pragma unroll
    for (int ot = 0; ot < 4; ++ot)
#pragma unroll
      for (int nt = 0; nt < 4; ++nt)
        acc[ot][nt] = MFMA(a[ot], bfr[nt], acc[ot][nt]);
#pragma unroll
    for (int ot = 0; ot < 4; ++ot) a[ot] = na[ot];
#pragma unroll
    for (int nt = 0; nt < 4; ++nt) bfr[nt] = nb[nt];
  }
#pragma unroll
  for (int ot = 0; ot < 4; ++ot)
#pragma unroll
    for (int nt = 0; nt < 4; ++nt)
      acc[ot][nt] = MFMA(a[ot], bfr[nt], acc[ot][nt]);
  // epilogue: bias + relu + bf16 store
#pragma unroll
  for (int ot = 0; ot < 4; ++ot) {
    int o0 = ot * 16 + 4 * g;
    f32x4 b4 = *(const f32x4*)(bias + o0);
#pragma unroll
    for (int nt = 0; nt < 4; ++nt) {
      int p = nt * 16 + lr;
      int my = my0 + (p >> 3), mx = mx0 + (p & 7);
      int oy = 2 * my + pyr, ox = 2 * mx + pxr;
      short4v sv;
#pragma unroll
      for (int r = 0; r < 4; ++r)
        sv[r] = f2bf(fmaxf(acc[ot][nt][r] + b4[r], 0.f));
      *(short4v*)(T1 + ((b * 130 + oy + 1) * 130 + ox + 1) * 64 + o0) = sv;
    }
  }
}

// ============================================================================
// tconv2 VALU: T1[130,130,64] bf16 -> x_recon[32,256,256] f32
// ============================================================================
__global__ __launch_bounds__(256) void k_tconv2(const short* __restrict__ T1,
    const float* __restrict__ w, const float* __restrict__ bias,
    float* __restrict__ xrec) {
  __shared__ float sW[1024];
  int t = threadIdx.x;
  for (int e = t; e < 1024; e += 256) sW[e] = w[e];
  __syncthreads();
  int blk = blockIdx.x;
  int tx = blk & 15, ty = (blk >> 4) & 15, b = blk >> 8;
  int row = t >> 4, col = t & 15;
  int oy = ty * 16 + row, ox = tx * 16 + col;
  int pyr = oy & 1, pxr = ox & 1;
  int kye = 1 - pyr, kxe = 1 - pxr;
  int m = oy >> 1, n = ox >> 1;
  float acc = bias[0];
#pragma unroll
  for (int dy = 0; dy < 2; ++dy) {
#pragma unroll
    for (int dx = 0; dx < 2; ++dx) {
      const short* ip =
          T1 + ((b * 130 + m + pyr - dy + 1) * 130 + (n + pxr - dx + 1)) * 64;
      int tap = (kye + 2 * dy) * 4 + (kxe + 2 * dx);
#pragma unroll
      for (int c8 = 0; c8 < 8; ++c8) {
        short8 v = *(const short8*)(ip + c8 * 8);
#pragma unroll
        for (int i = 0; i < 8; ++i)
          acc = fmaf(bf2f(v[i]), sW[(c8 * 8 + i) * 16 + tap], acc);
      }
    }
  }
  xrec[(b * 256 + oy) * 256 + ox] = acc;
}

// ============================================================================
// finalize: loss from 2048 partials; perplexity from counts
// ============================================================================
__global__ __launch_bounds__(256) void k_final(const float* __restrict__ partials,
    const int* __restrict__ counts, float* __restrict__ out) {
  int t = threadIdx.x;
  float s = 0.f;
  for (int i = t; i < 2048; i += 256) s += partials[i];
#pragma unroll
  for (int m = 32; m >= 1; m >>= 1) s += __shfl_xor(s, m);
  __shared__ float sr[4];
  if ((t & 63) == 0) sr[t >> 6] = s;
  __syncthreads();
  if (t == 0) {
    float tot = sr[0] + sr[1] + sr[2] + sr[3];
    out[0] = 1.25f * tot / 16777216.0f;
  }
  float h = 0.f;
  for (int c = t; c < KC; c += 256) {
    float avg = (float)counts[c] / 131072.0f;
    h += avg * logf(avg + 1e-10f);
  }
#pragma unroll
  for (int m = 32; m >= 1; m >>= 1) h += __shfl_xor(h, m);
  __shared__ float sr2[4];
  if ((t & 63) == 0) sr2[t >> 6] = h;
  __syncthreads();
  if (t == 0) out[1 + 32 * 256 * 256] = expf(-(sr2[0] + sr2[1] + sr2[2] + sr2[3]));
}

// ============================================================================
extern "C" void kernel_launch(void* const* d_in, const int* in_sizes, int n_in,
                              void* d_out, int out_size, void* d_ws, size_t ws_size,
                              hipStream_t stream) {
  const float* x    = (const float*)d_in[0];
  const float* c1w  = (const float*)d_in[1];
  const float* c1b  = (const float*)d_in[2];
  const float* c2w  = (const float*)d_in[3];
  const float* c2b  = (const float*)d_in[4];
  const float* r1w3 = (const float*)d_in[5];
  const float* r1w1 = (const float*)d_in[6];
  const float* r2w3 = (const float*)d_in[7];
  const float* r2w1 = (const float*)d_in[8];
  const float* prew = (const float*)d_in[9];
  const float* preb = (const float*)d_in[10];
  const float* emb  = (const float*)d_in[11];
  const float* d1w3 = (const float*)d_in[12];
  const float* d1w1 = (const float*)d_in[13];
  const float* d2w3 = (const float*)d_in[14];
  const float* d2w1 = (const float*)d_in[15];
  const float* t1w  = (const float*)d_in[16];
  const float* t1b  = (const float*)d_in[17];
  const float* t2w  = (const float*)d_in[18];
  const float* t2b  = (const float*)d_in[19];
  float* out = (float*)d_out;

  char* ws = (char*)d_ws;
  short* buf0 = (short*)(ws);                      // A1 / T1 : 69,222,400 B
  float* bufX = (float*)(ws + 69222400);           // Xf / Zcat / Q : 67,108,864 B
  short* bufR = (short*)(ws + 136331264);          // XrP / QrP : 35,684,352 B
  short* Hr   = (short*)(ws + 172015616);          // 8,388,608 B -> ends 180404224
  int*   counts = (int*)(ws + 180928512);          // 2,048 B
  float* partials = (float*)(ws + 180930560);      // 8,192 B
  float* en   = (float*)(ws + 180938752);          // 2,048 B
  short* wAc2 = (short*)(ws + 180940800);          // 262,144 B
  short* wAr3 = (short*)(ws + 181202944);          // 294,912 B
  short* wAr1 = (short*)(ws + 181497856);          // 32,768 B
  short* wApre= (short*)(ws + 181530624);          // 32,768 B
  short* wAt1 = (short*)(ws + 181563392);          // 262,144 B
  short* Ecat = (short*)(ws + 181825536);          // 393,216 B -> ends 182,218,752

  short* Zcat = (short*)bufX;  // 67,108,864 B (Xf dead after enc res1addm#2;
                               // Q gather overwrites Zcat block-locally)

  short* wAr3_e1 = wAr3;
  short* wAr3_e2 = wAr3 + 36864;
  short* wAr3_d1 = wAr3 + 2 * 36864;
  short* wAr3_d2 = wAr3 + 3 * 36864;
  short* wAr1_e1 = wAr1;
  short* wAr1_e2 = wAr1 + 4096;
  short* wAr1_d1 = wAr1 + 2 * 4096;
  short* wAr1_d2 = wAr1 + 3 * 4096;

  hipMemsetAsync(counts, 0, KC * sizeof(int), stream);

  k_border  <<<256, 256, 0, stream>>>(buf0, bufR);
  k_perm_c2 <<<512, 256, 0, stream>>>(c2w, wAc2);
  k_perm_r3 <<<144, 256, 0, stream>>>(r1w3, wAr3_e1);
  k_perm_r3 <<<144, 256, 0, stream>>>(r2w3, wAr3_e2);
  k_perm_r3 <<<144, 256, 0, stream>>>(d1w3, wAr3_d1);
  k_perm_r3 <<<144, 256, 0, stream>>>(d2w3, wAr3_d2);
  k_perm_r1 <<<16, 256, 0, stream>>>(r1w1, wAr1_e1);
  k_perm_r1 <<<16, 256, 0, stream>>>(r2w1, wAr1_e2);
  k_perm_r1 <<<16, 256, 0, stream>>>(d1w1, wAr1_d1);
  k_perm_r1 <<<16, 256, 0, stream>>>(d2w1, wAr1_d2);
  k_perm_pre<<<64, 256, 0, stream>>>(prew, wApre);
  k_perm_t1 <<<512, 256, 0, stream>>>(t1w, wAt1);
  k_perm_E  <<<768, 256, 0, stream>>>(emb, Ecat);
  k_embnorm <<<512, 64, 0, stream>>>(emb, en);

  k_conv1   <<<4096, 256, 0, stream>>>(x, c1w, c1b, buf0);
  k_conv2m  <<<2048, 256, 0, stream>>>(buf0, wAc2, c2b, bufX, bufR);
  k_res3m   <<<1024, 256, 0, stream>>>(bufR, wAr3_e1, Hr);
  k_res1addm<<<2048, 256, 0, stream>>>(Hr, wAr1_e1, bufX, bufR);
  k_res3m   <<<1024, 256, 0, stream>>>(bufR, wAr3_e2, Hr);
  k_res1addm<<<2048, 256, 0, stream>>>(Hr, wAr1_e2, bufX, bufR);
  k_prem    <<<2048, 256, 0, stream>>>(bufR, wApre, preb, Zcat);
  k_vqm5    <<<2048, 256, 0, stream>>>(Zcat, Ecat, en, emb, counts, partials,
                                       bufX, bufR);
  k_res3m   <<<1024, 256, 0, stream>>>(bufR, wAr3_d1, Hr);
  k_res1addm<<<2048, 256, 0, stream>>>(Hr, wAr1_d1, bufX, bufR);
  k_res3m   <<<1024, 256, 0, stream>>>(bufR, wAr3_d2, Hr);
  k_res1addm<<<2048, 256, 0, stream>>>(Hr, wAr1_d2, bufX, bufR);
  k_tconv1m <<<2048, 256, 0, stream>>>(bufR, wAt1, t1b, buf0);
  k_tconv2  <<<8192, 256, 0, stream>>>(buf0, t2w, t2b, out + 1);
  k_final   <<<1, 256, 0, stream>>>(partials, counts, out);
}

// Round 9
// 652.999 us; speedup vs baseline: 1.1935x; 1.0428x over previous
//
#include <hip/hip_runtime.h>
#include <math.h>

#define KC 512
#define DD 128

typedef __attribute__((ext_vector_type(8))) short short8;
typedef __attribute__((ext_vector_type(4))) short short4v;
typedef __attribute__((ext_vector_type(4))) float f32x4;

#define MFMA(a, b, c) __builtin_amdgcn_mfma_f32_16x16x32_bf16(a, b, c, 0, 0, 0)

#define GLOAD_LDS16(g, l)                                        \
  __builtin_amdgcn_global_load_lds(                              \
      (const __attribute__((address_space(1))) void*)(g),        \
      (__attribute__((address_space(3))) void*)(l), 16, 0, 0)

__device__ __forceinline__ short f2bf(float f) {
  unsigned u = __float_as_uint(f);
  u = (u + 0x7FFFu + ((u >> 16) & 1u)) >> 16;
  return (short)u;
}
__device__ __forceinline__ float bf2f(short s) {
  return __uint_as_float(((unsigned)(unsigned short)s) << 16);
}

// ============================================================================
// weight permutation kernels (A-fragment order)
// ============================================================================
__global__ __launch_bounds__(256) void k_perm_c2(const float* __restrict__ w,
                                                 short* __restrict__ dst) {
  int e = blockIdx.x * 256 + threadIdx.x;  // < 131072
  int j = e & 7, l = (e >> 3) & 63, ot = (e >> 9) & 7, kc = e >> 12;
  int o = ot * 16 + (l & 15), g = l >> 4;
  int tap = kc >> 1, ci = (kc & 1) * 32 + 8 * g + j;
  dst[e] = f2bf(w[(o * 64 + ci) * 16 + tap]);
}

__global__ __launch_bounds__(256) void k_perm_r3(const float* __restrict__ w,
                                                 short* __restrict__ dst) {
  int e = blockIdx.x * 256 + threadIdx.x;  // < 36864
  int j = e & 7, l = (e >> 3) & 63, ot = (e >> 9) & 1, kc = e >> 10;
  int o = ot * 16 + (l & 15), g = l >> 4;
  int tap = kc >> 2, ci = (kc & 3) * 32 + 8 * g + j;
  dst[e] = f2bf(w[(o * 128 + ci) * 9 + tap]);
}

__global__ __launch_bounds__(256) void k_perm_r1(const float* __restrict__ w,
                                                 short* __restrict__ dst) {
  int e = blockIdx.x * 256 + threadIdx.x;  // < 4096
  int j = e & 7, l = (e >> 3) & 63, ot = e >> 9;
  int o = ot * 16 + (l & 15), g = l >> 4;
  int ci = 8 * g + j;
  dst[e] = f2bf(w[o * 32 + ci]);
}

__global__ __launch_bounds__(256) void k_perm_pre(const float* __restrict__ w,
                                                  short* __restrict__ dst) {
  int e = blockIdx.x * 256 + threadIdx.x;  // < 16384
  int j = e & 7, l = (e >> 3) & 63, ot = (e >> 9) & 7, kc = e >> 12;
  int o = ot * 16 + (l & 15), g = l >> 4;
  int ci = kc * 32 + 8 * g + j;
  dst[e] = f2bf(w[o * 128 + ci]);
}

__global__ __launch_bounds__(256) void k_perm_t1(const float* __restrict__ w,
                                                 short* __restrict__ dst) {
  int e = blockIdx.x * 256 + threadIdx.x;  // < 131072
  int j = e & 7, l = (e >> 3) & 63, ot = (e >> 9) & 3, kc = (e >> 11) & 15,
      pp = e >> 15;
  int pyr = pp >> 1, pxr = pp & 1;
  int o = ot * 16 + (l & 15), g = l >> 4;
  int tt = kc >> 2, dy = tt >> 1, dx = tt & 1;
  int ky = (1 - pyr) + 2 * dy, kx = (1 - pxr) + 2 * dx;
  int ci = (kc & 3) * 32 + 8 * g + j;
  dst[e] = f2bf(w[(ci * 64 + o) * 16 + ky * 4 + kx]);
}

// ============================================================================
// Ecat permute: emb[512][128] f32 -> Ecat bf16 in A-fragment order over K=384:
// K [0:256) = eh (duplicated), [256:384) = el. e=((kc*32+ot)*64+l)*8+j
// grid 768 x 256 (196608 elems)
// ============================================================================
__global__ __launch_bounds__(256) void k_perm_E(const float* __restrict__ emb,
                                                short* __restrict__ dst) {
  int e = blockIdx.x * 256 + threadIdx.x;
  int j = e & 7, l = (e >> 3) & 63, ot = (e >> 9) & 31, kc = e >> 14;
  int c = ot * 16 + (l & 15);
  int k = kc * 32 + 8 * (l >> 4) + j;
  float v = emb[c * DD + (k & 127)];
  short hi = f2bf(v);
  dst[e] = (k < 256) ? hi : f2bf(v - bf2f(hi));
}

// ============================================================================
// emb norms (exact f32)
// ============================================================================
__global__ __launch_bounds__(64) void k_embnorm(const float* __restrict__ emb,
                                                float* __restrict__ en) {
  int c = blockIdx.x, l = threadIdx.x;
  float a = emb[c * DD + l], b = emb[c * DD + 64 + l];
  float s = a * a + b * b;
#pragma unroll
  for (int m = 32; m >= 1; m >>= 1) s += __shfl_xor(s, m);
  if (l == 0) en[c] = s;
}

// ============================================================================
// border zero: A1[32,130,130,64] and XrP[32,66,66,128] padding rings only
// grid 256 = 32 b x 8 slices, 256 thr.
// ============================================================================
__global__ __launch_bounds__(256) void k_border(short* __restrict__ A1,
                                                short* __restrict__ XrP) {
  int blk = blockIdx.x;
  int b = blk >> 3;
  int tid = ((blk & 7) << 8) + threadIdx.x;  // 0..2047
  short8 z8 = {};
  long baseA = (long)b * 1081600;  // 130*130*64
  for (int e = tid; e < 2080; e += 2048) {
    int r = e >= 1040;
    int rem = r ? e - 1040 : e;
    *(short8*)(A1 + baseA + (r ? 129L * 130 * 64 : 0) + rem * 8) = z8;
  }
  {
    int c = tid >> 10, rem = tid & 1023;
    int row = 1 + (rem >> 3), s8 = rem & 7;
    *(short8*)(A1 + baseA + (row * 130L + (c ? 129 : 0)) * 64 + s8 * 8) = z8;
  }
  long baseX = (long)b * 557568;  // 66*66*128
  for (int e = tid; e < 2112; e += 2048) {
    int r = e >= 1056;
    int rem = r ? e - 1056 : e;
    *(short8*)(XrP + baseX + (r ? 65L * 66 * 128 : 0) + rem * 8) = z8;
  }
  {
    int c = tid >> 10, rem = tid & 1023;
    int row = 1 + (rem >> 4), s8 = rem & 15;
    *(short8*)(XrP + baseX + (row * 66L + (c ? 65 : 0)) * 128 + s8 * 8) = z8;
  }
}

// ============================================================================
// conv1: x[32,1,256,256] f32 -> A1[32,130,130,64] bf16 relu (padded, ch-last)
// grid 4096 = 32 b x 128 y
// ============================================================================
__global__ __launch_bounds__(256) void k_conv1(const float* __restrict__ x,
    const float* __restrict__ w, const float* __restrict__ bias,
    short* __restrict__ A1) {
  __shared__ float sXp[4 * 260];
  __shared__ float sWt[16 * 64];
  int blk = blockIdx.x;
  int y = blk & 127, b = blk >> 7;
  int t = threadIdx.x;
  for (int e = t; e < 1024; e += 256) sWt[e] = w[(e & 63) * 16 + (e >> 6)];
  if (t < 4) {
    sXp[t * 260] = 0.f;
    sXp[t * 260 + 257] = 0.f;
    sXp[t * 260 + 258] = 0.f;
    sXp[t * 260 + 259] = 0.f;
  }
  for (int e = t; e < 1024; e += 256) {
    int r = e >> 8, col = e & 255;
    int giy = 2 * y - 1 + r;
    float v = 0.f;
    if ((unsigned)giy < 256u) v = x[(b * 256 + giy) * 256 + col];
    sXp[r * 260 + col + 1] = v;
  }
  __syncthreads();
  int og = t >> 6, l = t & 63, o0 = og * 16;
  float acc0[16], acc1[16];
#pragma unroll
  for (int oo = 0; oo < 16; ++oo) { acc0[oo] = 0.f; acc1[oo] = 0.f; }
  int xA = 2 * l, xB = 2 * l + 128;
#pragma unroll
  for (int ky = 0; ky < 4; ++ky) {
#pragma unroll
    for (int kx = 0; kx < 4; ++kx) {
      float a0 = sXp[ky * 260 + xA + kx];
      float a1 = sXp[ky * 260 + xB + kx];
      const float* wrow = &sWt[(ky * 4 + kx) * 64 + o0];
#pragma unroll
      for (int oo = 0; oo < 16; ++oo) {
        float wv = wrow[oo];
        acc0[oo] = fmaf(a0, wv, acc0[oo]);
        acc1[oo] = fmaf(a1, wv, acc1[oo]);
      }
    }
  }
  long base0 = (((long)(b * 130 + y + 1)) * 130 + l + 1) * 64 + o0;
  long base1 = base0 + 64 * 64;
  short8 s0a, s0b, s1a, s1b;
#pragma unroll
  for (int oo = 0; oo < 8; ++oo) {
    s0a[oo] = f2bf(fmaxf(acc0[oo] + bias[o0 + oo], 0.f));
    s0b[oo] = f2bf(fmaxf(acc0[oo + 8] + bias[o0 + oo + 8], 0.f));
    s1a[oo] = f2bf(fmaxf(acc1[oo] + bias[o0 + oo], 0.f));
    s1b[oo] = f2bf(fmaxf(acc1[oo + 8] + bias[o0 + oo + 8], 0.f));
  }
  *(short8*)(A1 + base0) = s0a;
  *(short8*)(A1 + base0 + 8) = s0b;
  *(short8*)(A1 + base1) = s1a;
  *(short8*)(A1 + base1 + 8) = s1b;
}

// ============================================================================
// conv2 MFMA v2 (LDS-staged): A1[130,130,64] bf16 -> relu -> Xf[64,64,128] f32
// + XrP[66,66,128] bf16. grid 2048 = 32 b x 8 by x 8 bx
// ============================================================================
__global__ __launch_bounds__(256) void k_conv2m(const short* __restrict__ A1,
    const short* __restrict__ wA, const float* __restrict__ bias,
    float* __restrict__ Xf, short* __restrict__ XrP) {
  __shared__ short sX[22032];  // 324 px * 68 shorts (136 B) = 44,064 B
  int blk = blockIdx.x;
  int bx = blk & 7, by = (blk >> 3) & 7, b = blk >> 6;
  int t = threadIdx.x;
  int R0 = by * 16, C0 = bx * 16;
  for (int q = t; q < 2592; q += 256) {
    int p = q >> 3, seg = q & 7;
    int iy = p / 18, ix = p - iy * 18;
    short8 v = *(const short8*)(A1 +
        (((long)b * 130 + R0 + iy) * 130 + C0 + ix) * 64 + seg * 8);
    *(short8*)((char*)sX + p * 136 + seg * 16) = v;
  }
  __syncthreads();
  int w = t >> 6, l = t & 63, lr = l & 15, g = l >> 4;
  int Bb[4];
#pragma unroll
  for (int pt = 0; pt < 4; ++pt) {
    int p = pt * 16 + lr;
    int lp = 2 * (p >> 3) * 18 + 2 * (p & 7);
    Bb[pt] = lp * 136 + g * 16;
  }
  const short* pA0 = wA + (2 * w * 64 + l) * 8;
  const short* pA1 = pA0 + 512;
  f32x4 acc[2][4] = {};
  short8 a0 = *(const short8*)pA0;
  short8 a1 = *(const short8*)pA1;
  short8 bv[4];
#pragma unroll
  for (int i = 0; i < 4; ++i)
    bv[i] = *(const short8*)((const char*)sX + Bb[i]);
  for (int kc = 0; kc < 31; ++kc) {
    int nk = kc + 1;
    int tap = nk >> 1;
    int off = ((tap >> 2) * 18 + (tap & 3)) * 136 + (nk & 1) * 64;
    short8 na0 = *(const short8*)(pA0 + nk * 4096);
    short8 na1 = *(const short8*)(pA1 + nk * 4096);
    short8 nb[4];
#pragma unroll
    for (int i = 0; i < 4; ++i)
      nb[i] = *(const short8*)((const char*)sX + Bb[i] + off);
#pragma unroll
    for (int i = 0; i < 4; ++i) {
      acc[0][i] = MFMA(a0, bv[i], acc[0][i]);
      acc[1][i] = MFMA(a1, bv[i], acc[1][i]);
    }
    a0 = na0; a1 = na1;
#pragma unroll
    for (int i = 0; i < 4; ++i) bv[i] = nb[i];
  }
#pragma unroll
  for (int i = 0; i < 4; ++i) {
    acc[0][i] = MFMA(a0, bv[i], acc[0][i]);
    acc[1][i] = MFMA(a1, bv[i], acc[1][i]);
  }
#pragma unroll
  for (int oi = 0; oi < 2; ++oi) {
    int o0 = (2 * w + oi) * 16 + 4 * g;
#pragma unroll
    for (int pt = 0; pt < 4; ++pt) {
      int p = pt * 16 + lr;
      int y = by * 8 + (p >> 3), x = bx * 8 + (p & 7);
      f32x4 nv; short4v sv;
#pragma unroll
      for (int r = 0; r < 4; ++r) {
        float v = fmaxf(acc[oi][pt][r] + bias[o0 + r], 0.f);
        nv[r] = v; sv[r] = f2bf(v);
      }
      *(f32x4*)(Xf + ((b * 64 + y) * 64 + x) * 128 + o0) = nv;
      *(short4v*)(XrP + ((b * 66 + y + 1) * 66 + x + 1) * 128 + o0) = sv;
    }
  }
}

// ============================================================================
// res3 MFMA v2 (LDS-staged): XrP[66,66,128] -> Hr[64,64,32] bf16 relu
// grid 1024 = 32 b x 8 yt x 4 tx
// ============================================================================
__global__ __launch_bounds__(256) void k_res3m(const short* __restrict__ XrP,
    const short* __restrict__ wA, short* __restrict__ Hr) {
  __shared__ short sX[23040];  // 180 px * 128 shorts (256 B swizzled)
  int blk = blockIdx.x;
  int tx = blk & 3, yt = (blk >> 2) & 7, b = blk >> 5;
  int t = threadIdx.x;
  int r0 = yt * 8, c0 = tx * 16;
  for (int q = t; q < 2880; q += 256) {
    int p = q >> 4, seg = q & 15;
    int iy = p / 18, ix = p - iy * 18;
    short8 v = *(const short8*)(XrP +
        (((long)b * 66 + r0 + iy) * 66 + c0 + ix) * 128 + seg * 8);
    *(short8*)((char*)sX + p * 256 + ((seg * 16) ^ ((p & 7) << 4))) = v;
  }
  __syncthreads();
  int w = t >> 6, l = t & 63, lr = l & 15, g = l >> 4;
  const short* pA0 = wA + l * 8;
  const short* pA1 = pA0 + 512;
  f32x4 acc[2][2] = {};
  short8 a0 = *(const short8*)pA0;
  short8 a1 = *(const short8*)pA1;
  short8 bv[2];
#pragma unroll
  for (int j = 0; j < 2; ++j) {
    int lp = (2 * w + j) * 18 + lr;
    bv[j] = *(const short8*)((const char*)sX + lp * 256 +
                             ((g * 16) ^ ((lp & 7) << 4)));
  }
  for (int kc = 0; kc < 35; ++kc) {
    int nk = kc + 1;
    int tap = nk >> 2;
    int ky = tap / 3, kx = tap - ky * 3;
    int inner = g * 16 + (nk & 3) * 64;
    short8 na0 = *(const short8*)(pA0 + nk * 1024);
    short8 na1 = *(const short8*)(pA1 + nk * 1024);
    short8 nb[2];
#pragma unroll
    for (int j = 0; j < 2; ++j) {
      int lp = (2 * w + j + ky) * 18 + lr + kx;
      nb[j] = *(const short8*)((const char*)sX + lp * 256 +
                               (inner ^ ((lp & 7) << 4)));
    }
#pragma unroll
    for (int j = 0; j < 2; ++j) {
      acc[0][j] = MFMA(a0, bv[j], acc[0][j]);
      acc[1][j] = MFMA(a1, bv[j], acc[1][j]);
    }
    a0 = na0; a1 = na1;
    bv[0] = nb[0]; bv[1] = nb[1];
  }
#pragma unroll
  for (int j = 0; j < 2; ++j) {
    acc[0][j] = MFMA(a0, bv[j], acc[0][j]);
    acc[1][j] = MFMA(a1, bv[j], acc[1][j]);
  }
#pragma unroll
  for (int oi = 0; oi < 2; ++oi) {
    int o0 = oi * 16 + 4 * g;
#pragma unroll
    for (int j = 0; j < 2; ++j) {
      int y = r0 + 2 * w + j, x = c0 + lr;
      short4v sv;
#pragma unroll
      for (int r = 0; r < 4; ++r) sv[r] = f2bf(fmaxf(acc[oi][j][r], 0.f));
      *(short4v*)(Hr + ((b * 64 + y) * 64 + x) * 32 + o0) = sv;
    }
  }
}

// ============================================================================
// res1+add MFMA v2 (LDS-staged): Hr[64,64,32] -> Xf += conv1x1 ;
// XrP = relu(Xf) bf16. grid 2048 = 32 b x 8 by x 8 bx
// ============================================================================
__global__ __launch_bounds__(256) void k_res1addm(const short* __restrict__ Hr,
    const short* __restrict__ wA, float* __restrict__ Xf,
    short* __restrict__ XrP) {
  __shared__ short sH[64 * 40];  // 64 px * 40 sh (80 B stride)
  int blk = blockIdx.x;
  int bx = blk & 7, by = (blk >> 3) & 7, b = blk >> 6;
  int t = threadIdx.x, w = t >> 6, l = t & 63, lr = l & 15, g = l >> 4;
  {
    int p = t >> 2, seg = t & 3;
    int y = by * 8 + (p >> 3), x = bx * 8 + (p & 7);
    short8 v = *(const short8*)(Hr + ((b * 64 + y) * 64 + x) * 32 + seg * 8);
    *(short8*)(sH + p * 40 + seg * 8) = v;
  }
  __syncthreads();
  f32x4 acc[2][4] = {};
  short8 a0 = *(const short8*)(wA + (2 * w * 64 + l) * 8);
  short8 a1 = *(const short8*)(wA + ((2 * w + 1) * 64 + l) * 8);
#pragma unroll
  for (int i = 0; i < 4; ++i) {
    int p = i * 16 + lr;
    short8 bv = *(const short8*)(sH + p * 40 + 8 * g);
    acc[0][i] = MFMA(a0, bv, acc[0][i]);
    acc[1][i] = MFMA(a1, bv, acc[1][i]);
  }
#pragma unroll
  for (int oi = 0; oi < 2; ++oi) {
    int o0 = (2 * w + oi) * 16 + 4 * g;
#pragma unroll
    for (int i = 0; i < 4; ++i) {
      int p = i * 16 + lr;
      int y = by * 8 + (p >> 3), x = bx * 8 + (p & 7);
      float* xp = Xf + ((b * 64 + y) * 64 + x) * 128 + o0;
      f32x4 old = *(f32x4*)xp;
      f32x4 nv; short4v sv;
#pragma unroll
      for (int r = 0; r < 4; ++r) {
        nv[r] = old[r] + acc[oi][i][r];
        sv[r] = f2bf(fmaxf(nv[r], 0.f));
      }
      *(f32x4*)xp = nv;
      *(short4v*)(XrP + ((b * 66 + y + 1) * 66 + x + 1) * 128 + o0) = sv;
    }
  }
}

// ============================================================================
// pre 1x1 MFMA v2 (LDS-staged): XrP[66,66,128] -> Zcat[pix][256] bf16 =
// [zhi(128) | zlo(128)]. grid 2048 (8x8 pixels).
// ============================================================================
__global__ __launch_bounds__(256) void k_prem(const short* __restrict__ XrP,
    const short* __restrict__ wA, const float* __restrict__ bias,
    short* __restrict__ Zc) {
  __shared__ short sX[8192];  // 64 px * 128 sh, swizzled = 16 KB
  int blk = blockIdx.x;
  int bx = blk & 7, by = (blk >> 3) & 7, b = blk >> 6;
  int t = threadIdx.x, w = t >> 6, l = t & 63, lr = l & 15, g = l >> 4;
  for (int q = t; q < 1024; q += 256) {
    int p = q >> 4, seg = q & 15;
    int y = by * 8 + (p >> 3), x = bx * 8 + (p & 7);
    short8 v = *(const short8*)(XrP +
        ((b * 66 + y + 1) * 66 + x + 1) * 128 + seg * 8);
    *(short8*)((char*)sX + p * 256 + ((seg * 16) ^ ((p & 7) << 4))) = v;
  }
  __syncthreads();
  const short* pA0 = wA + (2 * w * 64 + l) * 8;
  const short* pA1 = pA0 + 512;
  f32x4 acc[2][4] = {};
#pragma unroll
  for (int kc = 0; kc < 4; ++kc) {
    short8 a0 = *(const short8*)(pA0 + kc * 4096);
    short8 a1 = *(const short8*)(pA1 + kc * 4096);
#pragma unroll
    for (int i = 0; i < 4; ++i) {
      int p = i * 16 + lr;
      short8 bv = *(const short8*)((const char*)sX + p * 256 +
                                   ((kc * 64 + g * 16) ^ ((p & 7) << 4)));
      acc[0][i] = MFMA(a0, bv, acc[0][i]);
      acc[1][i] = MFMA(a1, bv, acc[1][i]);
    }
  }
#pragma unroll
  for (int oi = 0; oi < 2; ++oi) {
    int o0 = (2 * w + oi) * 16 + 4 * g;
#pragma unroll
    for (int pt = 0; pt < 4; ++pt) {
      int p = pt * 16 + lr;
      int y = by * 8 + (p >> 3), x = bx * 8 + (p & 7);
      long pix = (long)(b * 64 + y) * 64 + x;
      short4v hv, lv;
#pragma unroll
      for (int r = 0; r < 4; ++r) {
        float v = acc[oi][pt][r] + bias[o0 + r];
        short hi = f2bf(v);
        hv[r] = hi;
        lv[r] = f2bf(v - bf2f(hi));
      }
      *(short4v*)(Zc + pix * 256 + o0) = hv;
      *(short4v*)(Zc + pix * 256 + 128 + o0) = lv;
    }
  }
}

// ============================================================================
// VQ MFMA v8 (async E-staging): 64 px x 512 codes, 8 waves (512 thr).
// Wave w owns codes [w*64,(w+1)*64) -> acc[4][4] = 64 AGPR, NO chunk loop,
// no A-operand register arrays. Per K-step each wave stages its OWN 4 KB
// slab region of Ecat into sE via global_load_lds (async, VGPR-free),
// s_waitcnt vmcnt(0), then 4 LDS A-reads + 4 LDS B-reads + 16 MFMA.
// Per-wave regions -> ZERO barriers in the K-loop (lgkmcnt guard for the
// single-buffer WAR). Z tile in LDS (32 KB XOR swizzle) as before.
// Fused argmin + hist + loss + gather. grid 2048.
// ============================================================================
__global__ __launch_bounds__(512) void k_vqm8(const short* __restrict__ Zc,
    const short* __restrict__ Ec, const float* __restrict__ en,
    const float* __restrict__ emb, int* __restrict__ counts,
    float* __restrict__ partials, float* __restrict__ Q,
    short* __restrict__ QrP) {
  __shared__ short sZ[16384];  // 64 px * 256 sh, swizzled = 32 KB
  __shared__ short sE[16384];  // E slab: 8 wave-regions x 2048 sh = 32 KB
  __shared__ float sV[8][64];
  __shared__ int sC[8][64];
  __shared__ float sZn[64];
  __shared__ int sIdx[64];
  __shared__ int sHist[KC];
  int blk = blockIdx.x;
  long pix0 = (long)blk * 64;
  int t = threadIdx.x, w = t >> 6, l = t & 63, c16 = l & 15, g = (l >> 4) & 3;
  for (int e = t; e < KC; e += 512) sHist[e] = 0;

  // stage Z tile: swizzle inner-byte ^ ((pix&7)<<4)
  for (int q = t; q < 2048; q += 512) {
    int p = q >> 5, seg = q & 31;
    short8 v = *(const short8*)(Zc + (pix0 + p) * 256 + seg * 8);
    *(short8*)((char*)sZ + p * 512 + ((seg * 16) ^ ((p & 7) << 4))) = v;
  }
  __syncthreads();

  // ||z||^2 per pixel from LDS: 8 threads/pixel, each 16 dims
  {
    int pz = t >> 3, sg = t & 7;
    const char* zb = (const char*)sZ + pz * 512;
    int swp = (pz & 7) << 4;
    float s = 0.f;
#pragma unroll
    for (int qq = 0; qq < 2; ++qq) {
      int io = sg * 32 + 16 * qq;  // zh inner byte
      short8 h8 = *(const short8*)(zb + (io ^ swp));
      short8 l8 = *(const short8*)(zb + ((io + 256) ^ swp));
#pragma unroll
      for (int j = 0; j < 8; ++j) {
        float zv = bf2f(h8[j]) + bf2f(l8[j]);
        s = fmaf(zv, zv, s);
      }
    }
    s += __shfl_xor(s, 1);
    s += __shfl_xor(s, 2);
    s += __shfl_xor(s, 4);
    if (sg == 0) sZn[pz] = s;
  }

  // GEMM: 12 K-steps of 32; wave-local async E staging.
  int sw = (c16 & 7) << 4;
  int zrow = c16 * 512;
  short* sEw = sE + w * 2048;                   // wave-uniform LDS base
  const short* gEw = Ec + w * 2048 + l * 8;     // per-lane global src
  f32x4 acc[4][4] = {};
  for (int kc = 0; kc < 12; ++kc) {
    if (kc) asm volatile("s_waitcnt lgkmcnt(0)" ::: "memory");
#pragma unroll
    for (int i = 0; i < 4; ++i)
      GLOAD_LDS16(gEw + kc * 16384 + i * 512, sEw + i * 512);
    asm volatile("s_waitcnt vmcnt(0)" ::: "memory");
    int koff = kc < 8 ? kc : kc - 8;
    int inn = ((koff * 64 + g * 16) ^ sw);
    const char* zb = (const char*)sZ + zrow + inn;
    short8 b0 = *(const short8*)zb;
    short8 b1 = *(const short8*)(zb + 8192);
    short8 b2 = *(const short8*)(zb + 16384);
    short8 b3 = *(const short8*)(zb + 24576);
    short8 a0 = *(const short8*)(sEw + l * 8);
    short8 a1 = *(const short8*)(sEw + 512 + l * 8);
    short8 a2 = *(const short8*)(sEw + 1024 + l * 8);
    short8 a3 = *(const short8*)(sEw + 1536 + l * 8);
    acc[0][0] = MFMA(a0, b0, acc[0][0]);
    acc[0][1] = MFMA(a0, b1, acc[0][1]);
    acc[0][2] = MFMA(a0, b2, acc[0][2]);
    acc[0][3] = MFMA(a0, b3, acc[0][3]);
    acc[1][0] = MFMA(a1, b0, acc[1][0]);
    acc[1][1] = MFMA(a1, b1, acc[1][1]);
    acc[1][2] = MFMA(a1, b2, acc[1][2]);
    acc[1][3] = MFMA(a1, b3, acc[1][3]);
    acc[2][0] = MFMA(a2, b0, acc[2][0]);
    acc[2][1] = MFMA(a2, b1, acc[2][1]);
    acc[2][2] = MFMA(a2, b2, acc[2][2]);
    acc[2][3] = MFMA(a2, b3, acc[2][3]);
    acc[3][0] = MFMA(a3, b0, acc[3][0]);
    acc[3][1] = MFMA(a3, b1, acc[3][1]);
    acc[3][2] = MFMA(a3, b2, acc[3][2]);
    acc[3][3] = MFMA(a3, b3, acc[3][3]);
  }
  // running argmin over the wave's 64 codes (codes ascend: ct, r)
  float bvv[4];
  int bcc[4];
#pragma unroll
  for (int pt = 0; pt < 4; ++pt) { bvv[pt] = 3.4e38f; bcc[pt] = 0; }
#pragma unroll
  for (int ct = 0; ct < 4; ++ct) {
    f32x4 en4 = *(const f32x4*)(en + w * 64 + ct * 16 + 4 * g);
#pragma unroll
    for (int pt = 0; pt < 4; ++pt) {
#pragma unroll
      for (int r = 0; r < 4; ++r) {
        float d = en4[r] - 2.f * acc[ct][pt][r];
        int code = w * 64 + ct * 16 + 4 * g + r;
        if (d < bvv[pt]) { bvv[pt] = d; bcc[pt] = code; }
      }
    }
  }
  // cross-lane reduce (over g) per pixel
#pragma unroll
  for (int pt = 0; pt < 4; ++pt) {
    float bv = bvv[pt];
    int bc = bcc[pt];
#pragma unroll
    for (int m = 16; m <= 32; m <<= 1) {
      float ov = __shfl_xor(bv, m);
      int oc = __shfl_xor(bc, m);
      if (ov < bv || (ov == bv && oc < bc)) { bv = ov; bc = oc; }
    }
    if (g == 0) {
      sV[w][pt * 16 + c16] = bv;
      sC[w][pt * 16 + c16] = bc;
    }
  }
  __syncthreads();
  if (t < 64) {
    float bv = sV[0][t];
    int bc = sC[0][t];
#pragma unroll
    for (int w2 = 1; w2 < 8; ++w2) {
      float v = sV[w2][t];
      int c = sC[w2][t];
      if (v < bv || (v == bv && c < bc)) { bv = v; bc = c; }
    }
    sIdx[t] = bc;
    atomicAdd(&sHist[bc], 1);
    // loss partial: wave-0 parallel reduce
    float ls = bv + sZn[t];
#pragma unroll
    for (int m = 32; m >= 1; m >>= 1) ls += __shfl_xor(ls, m);
    if (t == 0) partials[blk] = ls;
  }
  __syncthreads();
  for (int e = t; e < KC; e += 512) {
    int c = sHist[e];
    if (c) atomicAdd(&counts[e], c);
  }
  // fused gather: Q = emb[idx] f32 (overwrites this block's Zc bytes),
  // QrP = relu bf16 (padded layout)
  for (int e = t; e < 2048; e += 512) {
    int p = e >> 5, d4 = (e & 31) << 2;
    int c = sIdx[p];
    f32x4 q = *(const f32x4*)(emb + c * DD + d4);
    *(f32x4*)(Q + (pix0 + p) * DD + d4) = q;
    short4v sv;
#pragma unroll
    for (int r = 0; r < 4; ++r) sv[r] = f2bf(fmaxf(q[r], 0.f));
    long pixg = pix0 + p;
    int xx = (int)(pixg & 63), yy = (int)((pixg >> 6) & 63),
        bb = (int)(pixg >> 12);
    *(short4v*)(QrP + (((long)(bb * 66 + yy + 1)) * 66 + xx + 1) * 128 + d4) =
        sv;
  }
}

// ============================================================================
// tconv1 MFMA v2 (LDS-staged): QrP[66,66,128] -> T1[130,130,64] bf16 relu
// grid 2048 = 32 b x 8 tyt x 8 txt
// ============================================================================
__global__ __launch_bounds__(256) void k_tconv1m(const short* __restrict__ QrP,
    const short* __restrict__ wA, const float* __restrict__ bias,
    short* __restrict__ T1) {
  __shared__ short sX[13600];  // 100 pixels x 136 shorts
  int blk = blockIdx.x;
  int txt = blk & 7, tyt = (blk >> 3) & 7, b = blk >> 6;
  int my0 = tyt * 8, mx0 = txt * 8;
  int t = threadIdx.x;
  for (int q = t; q < 1600; q += 256) {
    int p = q >> 4, seg = q & 15;
    int iy = p / 10, ix = p - iy * 10;
    short8 v = *(const short8*)(QrP +
        ((b * 66 + my0 + iy) * 66 + mx0 + ix) * 128 + seg * 8);
    *(short8*)((char*)sX + p * 272 + seg * 16) = v;
  }
  __syncthreads();
  int w = t >> 6, l = t & 63, lr = l & 15, g = l >> 4;
  int pyr = w >> 1, pxr = w & 1;
  int Bb[4];
#pragma unroll
  for (int nt = 0; nt < 4; ++nt) {
    int p = nt * 16 + lr;
    int my = p >> 3, mx = p & 7;
    Bb[nt] = ((my + pyr + 1) * 10 + (mx + pxr + 1)) * 272 + g * 16;
  }
  const short* pAw = wA + w * 32768 + l * 8;
  f32x4 acc[4][4] = {};
  short8 a[4], bfr[4], na[4], nb[4];
#pragma unroll
  for (int ot = 0; ot < 4; ++ot) a[ot] = *(const short8*)(pAw + ot * 512);
#pragma unroll
  for (int nt = 0; nt < 4; ++nt)
    bfr[nt] = *(const short8*)((const char*)sX + Bb[nt]);
  for (int kc = 0; kc < 15; ++kc) {
    int nk = kc + 1;
    int tt = nk >> 2, dy = tt >> 1, dx = tt & 1;
    int off = -(dy * 10 + dx) * 272 + (nk & 3) * 64;
#pragma unroll
    for (int ot = 0; ot < 4; ++ot)
      na[ot] = *(const short8*)(pAw + nk * 2048 + ot * 512);
#pragma unroll
    for (int nt = 0; nt < 4; ++nt)
      nb[nt] = *(const short8*)((const char*)sX + Bb[nt] + off);
#pragma unroll
    for (int ot = 0; ot < 4; ++ot)
#pragma unroll
      for (int nt = 0; nt < 4; ++nt)
        acc[ot][nt] = MFMA(a[ot], bfr[nt], acc[ot][nt]);
#pragma unroll
    for (int ot = 0; ot < 4; ++ot) a[ot] = na[ot];
#pragma unroll
    for (int nt = 0; nt < 4; ++nt) bfr[nt] = nb[nt];
  }
#pragma unroll
  for (int ot = 0; ot < 4; ++ot)
#pragma unroll
    for (int nt = 0; nt < 4; ++nt)
      acc[ot][nt] = MFMA(a[ot], bfr[nt], acc[ot][nt]);
#pragma unroll
  for (int ot = 0; ot < 4; ++ot) {
    int o0 = ot * 16 + 4 * g;
    f32x4 b4 = *(const f32x4*)(bias + o0);
#pragma unroll
    for (int nt = 0; nt < 4; ++nt) {
      int p = nt * 16 + lr;
      int my = my0 + (p >> 3), mx = mx0 + (p & 7);
      int oy = 2 * my + pyr, ox = 2 * mx + pxr;
      short4v sv;
#pragma unroll
      for (int r = 0; r < 4; ++r)
        sv[r] = f2bf(fmaxf(acc[ot][nt][r] + b4[r], 0.f));
      *(short4v*)(T1 + ((b * 130 + oy + 1) * 130 + ox + 1) * 64 + o0) = sv;
    }
  }
}

// ============================================================================
// tconv2 VALU: T1[130,130,64] bf16 -> x_recon[32,256,256] f32
// ============================================================================
__global__ __launch_bounds__(256) void k_tconv2(const short* __restrict__ T1,
    const float* __restrict__ w, const float* __restrict__ bias,
    float* __restrict__ xrec) {
  __shared__ float sW[1024];
  int t = threadIdx.x;
  for (int e = t; e < 1024; e += 256) sW[e] = w[e];
  __syncthreads();
  int blk = blockIdx.x;
  int tx = blk & 15, ty = (blk >> 4) & 15, b = blk >> 8;
  int row = t >> 4, col = t & 15;
  int oy = ty * 16 + row, ox = tx * 16 + col;
  int pyr = oy & 1, pxr = ox & 1;
  int kye = 1 - pyr, kxe = 1 - pxr;
  int m = oy >> 1, n = ox >> 1;
  float acc = bias[0];
#pragma unroll
  for (int dy = 0; dy < 2; ++dy) {
#pragma unroll
    for (int dx = 0; dx < 2; ++dx) {
      const short* ip =
          T1 + ((b * 130 + m + pyr - dy + 1) * 130 + (n + pxr - dx + 1)) * 64;
      int tap = (kye + 2 * dy) * 4 + (kxe + 2 * dx);
#pragma unroll
      for (int c8 = 0; c8 < 8; ++c8) {
        short8 v = *(const short8*)(ip + c8 * 8);
#pragma unroll
        for (int i = 0; i < 8; ++i)
          acc = fmaf(bf2f(v[i]), sW[(c8 * 8 + i) * 16 + tap], acc);
      }
    }
  }
  xrec[(b * 256 + oy) * 256 + ox] = acc;
}

// ============================================================================
// finalize: loss from 2048 partials; perplexity from counts
// ============================================================================
__global__ __launch_bounds__(256) void k_final(const float* __restrict__ partials,
    const int* __restrict__ counts, float* __restrict__ out) {
  int t = threadIdx.x;
  float s = 0.f;
  for (int i = t; i < 2048; i += 256) s += partials[i];
#pragma unroll
  for (int m = 32; m >= 1; m >>= 1) s += __shfl_xor(s, m);
  __shared__ float sr[4];
  if ((t & 63) == 0) sr[t >> 6] = s;
  __syncthreads();
  if (t == 0) {
    float tot = sr[0] + sr[1] + sr[2] + sr[3];
    out[0] = 1.25f * tot / 16777216.0f;
  }
  float h = 0.f;
  for (int c = t; c < KC; c += 256) {
    float avg = (float)counts[c] / 131072.0f;
    h += avg * logf(avg + 1e-10f);
  }
#pragma unroll
  for (int m = 32; m >= 1; m >>= 1) h += __shfl_xor(h, m);
  __shared__ float sr2[4];
  if ((t & 63) == 0) sr2[t >> 6] = h;
  __syncthreads();
  if (t == 0) out[1 + 32 * 256 * 256] = expf(-(sr2[0] + sr2[1] + sr2[2] + sr2[3]));
}

// ============================================================================
extern "C" void kernel_launch(void* const* d_in, const int* in_sizes, int n_in,
                              void* d_out, int out_size, void* d_ws, size_t ws_size,
                              hipStream_t stream) {
  const float* x    = (const float*)d_in[0];
  const float* c1w  = (const float*)d_in[1];
  const float* c1b  = (const float*)d_in[2];
  const float* c2w  = (const float*)d_in[3];
  const float* c2b  = (const float*)d_in[4];
  const float* r1w3 = (const float*)d_in[5];
  const float* r1w1 = (const float*)d_in[6];
  const float* r2w3 = (const float*)d_in[7];
  const float* r2w1 = (const float*)d_in[8];
  const float* prew = (const float*)d_in[9];
  const float* preb = (const float*)d_in[10];
  const float* emb  = (const float*)d_in[11];
  const float* d1w3 = (const float*)d_in[12];
  const float* d1w1 = (const float*)d_in[13];
  const float* d2w3 = (const float*)d_in[14];
  const float* d2w1 = (const float*)d_in[15];
  const float* t1w  = (const float*)d_in[16];
  const float* t1b  = (const float*)d_in[17];
  const float* t2w  = (const float*)d_in[18];
  const float* t2b  = (const float*)d_in[19];
  float* out = (float*)d_out;

  char* ws = (char*)d_ws;
  short* buf0 = (short*)(ws);                      // A1 / T1 : 69,222,400 B
  float* bufX = (float*)(ws + 69222400);           // Xf / Zcat / Q : 67,108,864 B
  short* bufR = (short*)(ws + 136331264);          // XrP / QrP : 35,684,352 B
  short* Hr   = (short*)(ws + 172015616);          // 8,388,608 B -> ends 180404224
  int*   counts = (int*)(ws + 180928512);          // 2,048 B
  float* partials = (float*)(ws + 180930560);      // 8,192 B
  float* en   = (float*)(ws + 180938752);          // 2,048 B
  short* wAc2 = (short*)(ws + 180940800);          // 262,144 B
  short* wAr3 = (short*)(ws + 181202944);          // 294,912 B
  short* wAr1 = (short*)(ws + 181497856);          // 32,768 B
  short* wApre= (short*)(ws + 181530624);          // 32,768 B
  short* wAt1 = (short*)(ws + 181563392);          // 262,144 B
  short* Ecat = (short*)(ws + 181825536);          // 393,216 B -> ends 182,218,752

  short* Zcat = (short*)bufX;  // 67,108,864 B (Xf dead after enc res1addm#2;
                               // Q gather overwrites Zcat block-locally)

  short* wAr3_e1 = wAr3;
  short* wAr3_e2 = wAr3 + 36864;
  short* wAr3_d1 = wAr3 + 2 * 36864;
  short* wAr3_d2 = wAr3 + 3 * 36864;
  short* wAr1_e1 = wAr1;
  short* wAr1_e2 = wAr1 + 4096;
  short* wAr1_d1 = wAr1 + 2 * 4096;
  short* wAr1_d2 = wAr1 + 3 * 4096;

  hipMemsetAsync(counts, 0, KC * sizeof(int), stream);

  k_border  <<<256, 256, 0, stream>>>(buf0, bufR);
  k_perm_c2 <<<512, 256, 0, stream>>>(c2w, wAc2);
  k_perm_r3 <<<144, 256, 0, stream>>>(r1w3, wAr3_e1);
  k_perm_r3 <<<144, 256, 0, stream>>>(r2w3, wAr3_e2);
  k_perm_r3 <<<144, 256, 0, stream>>>(d1w3, wAr3_d1);
  k_perm_r3 <<<144, 256, 0, stream>>>(d2w3, wAr3_d2);
  k_perm_r1 <<<16, 256, 0, stream>>>(r1w1, wAr1_e1);
  k_perm_r1 <<<16, 256, 0, stream>>>(r2w1, wAr1_e2);
  k_perm_r1 <<<16, 256, 0, stream>>>(d1w1, wAr1_d1);
  k_perm_r1 <<<16, 256, 0, stream>>>(d2w1, wAr1_d2);
  k_perm_pre<<<64, 256, 0, stream>>>(prew, wApre);
  k_perm_t1 <<<512, 256, 0, stream>>>(t1w, wAt1);
  k_perm_E  <<<768, 256, 0, stream>>>(emb, Ecat);
  k_embnorm <<<512, 64, 0, stream>>>(emb, en);

  k_conv1   <<<4096, 256, 0, stream>>>(x, c1w, c1b, buf0);
  k_conv2m  <<<2048, 256, 0, stream>>>(buf0, wAc2, c2b, bufX, bufR);
  k_res3m   <<<1024, 256, 0, stream>>>(bufR, wAr3_e1, Hr);
  k_res1addm<<<2048, 256, 0, stream>>>(Hr, wAr1_e1, bufX, bufR);
  k_res3m   <<<1024, 256, 0, stream>>>(bufR, wAr3_e2, Hr);
  k_res1addm<<<2048, 256, 0, stream>>>(Hr, wAr1_e2, bufX, bufR);
  k_prem    <<<2048, 256, 0, stream>>>(bufR, wApre, preb, Zcat);
  k_vqm8    <<<2048, 512, 0, stream>>>(Zcat, Ecat, en, emb, counts, partials,
                                       bufX, bufR);
  k_res3m   <<<1024, 256, 0, stream>>>(bufR, wAr3_d1, Hr);
  k_res1addm<<<2048, 256, 0, stream>>>(Hr, wAr1_d1, bufX, bufR);
  k_res3m   <<<1024, 256, 0, stream>>>(bufR, wAr3_d2, Hr);
  k_res1addm<<<2048, 256, 0, stream>>>(Hr, wAr1_d2, bufX, bufR);
  k_tconv1m <<<2048, 256, 0, stream>>>(bufR, wAt1, t1b, buf0);
  k_tconv2  <<<8192, 256, 0, stream>>>(buf0, t2w, t2b, out + 1);
  k_final   <<<1, 256, 0, stream>>>(partials, counts, out);
}

// Round 10
// 618.068 us; speedup vs baseline: 1.2610x; 1.0565x over previous
//
#include <hip/hip_runtime.h>
#include <math.h>

#define KC 512
#define DD 128

typedef __attribute__((ext_vector_type(8))) short short8;
typedef __attribute__((ext_vector_type(4))) short short4v;
typedef __attribute__((ext_vector_type(4))) float f32x4;

#define MFMA(a, b, c) __builtin_amdgcn_mfma_f32_16x16x32_bf16(a, b, c, 0, 0, 0)

#define GLOAD_LDS16(g, l)                                        \
  __builtin_amdgcn_global_load_lds(                              \
      (const __attribute__((address_space(1))) void*)(g),        \
      (__attribute__((address_space(3))) void*)(l), 16, 0, 0)

__device__ __forceinline__ short f2bf(float f) {
  unsigned u = __float_as_uint(f);
  u = (u + 0x7FFFu + ((u >> 16) & 1u)) >> 16;
  return (short)u;
}
__device__ __forceinline__ float bf2f(short s) {
  return __uint_as_float(((unsigned)(unsigned short)s) << 16);
}

// ============================================================================
// k_prep: ALL weight permutations + embnorm + border-zero in ONE dispatch
// (was 13 separate launches; saves ~12 inter-dispatch gaps).
// Block ranges:
//   [0,512)      perm_c2      [512,1088)   perm_r3 x4   [1088,1152) perm_r1 x4
//   [1152,1216)  perm_pre     [1216,1728)  perm_t1      [1728,2496) perm_E
//   [2496,2624)  embnorm (4 codes/blk)     [2624,2880)  border
// grid 2880 x 256
// ============================================================================
__global__ __launch_bounds__(256) void k_prep(
    const float* __restrict__ c2w,
    const float* __restrict__ r1w3, const float* __restrict__ r2w3,
    const float* __restrict__ d1w3, const float* __restrict__ d2w3,
    const float* __restrict__ r1w1, const float* __restrict__ r2w1,
    const float* __restrict__ d1w1, const float* __restrict__ d2w1,
    const float* __restrict__ prew, const float* __restrict__ t1w,
    const float* __restrict__ emb,
    short* __restrict__ wAc2, short* __restrict__ wAr3,
    short* __restrict__ wAr1, short* __restrict__ wApre,
    short* __restrict__ wAt1, short* __restrict__ Ecat,
    float* __restrict__ en, short* __restrict__ A1,
    short* __restrict__ XrP) {
  int blk = blockIdx.x, t = threadIdx.x;
  if (blk < 512) {  // perm_c2
    int e = blk * 256 + t;
    int j = e & 7, l = (e >> 3) & 63, ot = (e >> 9) & 7, kc = e >> 12;
    int o = ot * 16 + (l & 15), g = l >> 4;
    int tap = kc >> 1, ci = (kc & 1) * 32 + 8 * g + j;
    wAc2[e] = f2bf(c2w[(o * 64 + ci) * 16 + tap]);
  } else if (blk < 1088) {  // perm_r3 x4
    int sub = blk - 512;
    int which = sub / 144, bb = sub - which * 144;
    const float* w = which == 0 ? r1w3 : which == 1 ? r2w3
                     : which == 2 ? d1w3 : d2w3;
    short* dst = wAr3 + which * 36864;
    int e = bb * 256 + t;
    int j = e & 7, l = (e >> 3) & 63, ot = (e >> 9) & 1, kc = e >> 10;
    int o = ot * 16 + (l & 15), g = l >> 4;
    int tap = kc >> 2, ci = (kc & 3) * 32 + 8 * g + j;
    dst[e] = f2bf(w[(o * 128 + ci) * 9 + tap]);
  } else if (blk < 1152) {  // perm_r1 x4
    int sub = blk - 1088;
    int which = sub >> 4, bb = sub & 15;
    const float* w = which == 0 ? r1w1 : which == 1 ? r2w1
                     : which == 2 ? d1w1 : d2w1;
    short* dst = wAr1 + which * 4096;
    int e = bb * 256 + t;
    int j = e & 7, l = (e >> 3) & 63, ot = e >> 9;
    int o = ot * 16 + (l & 15), g = l >> 4;
    int ci = 8 * g + j;
    dst[e] = f2bf(w[o * 32 + ci]);
  } else if (blk < 1216) {  // perm_pre
    int e = (blk - 1152) * 256 + t;
    int j = e & 7, l = (e >> 3) & 63, ot = (e >> 9) & 7, kc = e >> 12;
    int o = ot * 16 + (l & 15), g = l >> 4;
    int ci = kc * 32 + 8 * g + j;
    wApre[e] = f2bf(prew[o * 128 + ci]);
  } else if (blk < 1728) {  // perm_t1
    int e = (blk - 1216) * 256 + t;
    int j = e & 7, l = (e >> 3) & 63, ot = (e >> 9) & 3, kc = (e >> 11) & 15,
        pp = e >> 15;
    int pyr = pp >> 1, pxr = pp & 1;
    int o = ot * 16 + (l & 15), g = l >> 4;
    int tt = kc >> 2, dy = tt >> 1, dx = tt & 1;
    int ky = (1 - pyr) + 2 * dy, kx = (1 - pxr) + 2 * dx;
    int ci = (kc & 3) * 32 + 8 * g + j;
    wAt1[e] = f2bf(t1w[(ci * 64 + o) * 16 + ky * 4 + kx]);
  } else if (blk < 2496) {  // perm_E
    int e = (blk - 1728) * 256 + t;
    int j = e & 7, l = (e >> 3) & 63, ot = (e >> 9) & 31, kc = e >> 14;
    int c = ot * 16 + (l & 15);
    int k = kc * 32 + 8 * (l >> 4) + j;
    float v = emb[c * DD + (k & 127)];
    short hi = f2bf(v);
    Ecat[e] = (k < 256) ? hi : f2bf(v - bf2f(hi));
  } else if (blk < 2624) {  // embnorm: 4 codes per block (wave = code)
    int c = (blk - 2496) * 4 + (t >> 6), l = t & 63;
    float a = emb[c * DD + l], b2 = emb[c * DD + 64 + l];
    float s = a * a + b2 * b2;
#pragma unroll
    for (int m = 32; m >= 1; m >>= 1) s += __shfl_xor(s, m);
    if (l == 0) en[c] = s;
  } else {  // border zero
    int bb = blk - 2624;
    int b = bb >> 3;
    int tid = ((bb & 7) << 8) + t;  // 0..2047
    short8 z8 = {};
    long baseA = (long)b * 1081600;  // 130*130*64
    for (int e = tid; e < 2080; e += 2048) {
      int r = e >= 1040;
      int rem = r ? e - 1040 : e;
      *(short8*)(A1 + baseA + (r ? 129L * 130 * 64 : 0) + rem * 8) = z8;
    }
    {
      int c = tid >> 10, rem = tid & 1023;
      int row = 1 + (rem >> 3), s8 = rem & 7;
      *(short8*)(A1 + baseA + (row * 130L + (c ? 129 : 0)) * 64 + s8 * 8) = z8;
    }
    long baseX = (long)b * 557568;  // 66*66*128
    for (int e = tid; e < 2112; e += 2048) {
      int r = e >= 1056;
      int rem = r ? e - 1056 : e;
      *(short8*)(XrP + baseX + (r ? 65L * 66 * 128 : 0) + rem * 8) = z8;
    }
    {
      int c = tid >> 10, rem = tid & 1023;
      int row = 1 + (rem >> 4), s8 = rem & 15;
      *(short8*)(XrP + baseX + (row * 66L + (c ? 65 : 0)) * 128 + s8 * 8) = z8;
    }
  }
}

// ============================================================================
// conv1: x[32,1,256,256] f32 -> A1[32,130,130,64] bf16 relu (padded, ch-last)
// grid 4096 = 32 b x 128 y
// ============================================================================
__global__ __launch_bounds__(256) void k_conv1(const float* __restrict__ x,
    const float* __restrict__ w, const float* __restrict__ bias,
    short* __restrict__ A1) {
  __shared__ float sXp[4 * 260];
  __shared__ float sWt[16 * 64];
  int blk = blockIdx.x;
  int y = blk & 127, b = blk >> 7;
  int t = threadIdx.x;
  for (int e = t; e < 1024; e += 256) sWt[e] = w[(e & 63) * 16 + (e >> 6)];
  if (t < 4) {
    sXp[t * 260] = 0.f;
    sXp[t * 260 + 257] = 0.f;
    sXp[t * 260 + 258] = 0.f;
    sXp[t * 260 + 259] = 0.f;
  }
  for (int e = t; e < 1024; e += 256) {
    int r = e >> 8, col = e & 255;
    int giy = 2 * y - 1 + r;
    float v = 0.f;
    if ((unsigned)giy < 256u) v = x[(b * 256 + giy) * 256 + col];
    sXp[r * 260 + col + 1] = v;
  }
  __syncthreads();
  int og = t >> 6, l = t & 63, o0 = og * 16;
  float acc0[16], acc1[16];
#pragma unroll
  for (int oo = 0; oo < 16; ++oo) { acc0[oo] = 0.f; acc1[oo] = 0.f; }
  int xA = 2 * l, xB = 2 * l + 128;
#pragma unroll
  for (int ky = 0; ky < 4; ++ky) {
#pragma unroll
    for (int kx = 0; kx < 4; ++kx) {
      float a0 = sXp[ky * 260 + xA + kx];
      float a1 = sXp[ky * 260 + xB + kx];
      const float* wrow = &sWt[(ky * 4 + kx) * 64 + o0];
#pragma unroll
      for (int oo = 0; oo < 16; ++oo) {
        float wv = wrow[oo];
        acc0[oo] = fmaf(a0, wv, acc0[oo]);
        acc1[oo] = fmaf(a1, wv, acc1[oo]);
      }
    }
  }
  long base0 = (((long)(b * 130 + y + 1)) * 130 + l + 1) * 64 + o0;
  long base1 = base0 + 64 * 64;
  short8 s0a, s0b, s1a, s1b;
#pragma unroll
  for (int oo = 0; oo < 8; ++oo) {
    s0a[oo] = f2bf(fmaxf(acc0[oo] + bias[o0 + oo], 0.f));
    s0b[oo] = f2bf(fmaxf(acc0[oo + 8] + bias[o0 + oo + 8], 0.f));
    s1a[oo] = f2bf(fmaxf(acc1[oo] + bias[o0 + oo], 0.f));
    s1b[oo] = f2bf(fmaxf(acc1[oo + 8] + bias[o0 + oo + 8], 0.f));
  }
  *(short8*)(A1 + base0) = s0a;
  *(short8*)(A1 + base0 + 8) = s0b;
  *(short8*)(A1 + base1) = s1a;
  *(short8*)(A1 + base1 + 8) = s1b;
}

// ============================================================================
// conv2 MFMA v2 (LDS-staged): A1[130,130,64] bf16 -> relu -> Xf[64,64,128] f32
// + XrP[66,66,128] bf16. grid 2048 = 32 b x 8 by x 8 bx
// ============================================================================
__global__ __launch_bounds__(256) void k_conv2m(const short* __restrict__ A1,
    const short* __restrict__ wA, const float* __restrict__ bias,
    float* __restrict__ Xf, short* __restrict__ XrP) {
  __shared__ short sX[22032];  // 324 px * 68 shorts (136 B) = 44,064 B
  int blk = blockIdx.x;
  int bx = blk & 7, by = (blk >> 3) & 7, b = blk >> 6;
  int t = threadIdx.x;
  int R0 = by * 16, C0 = bx * 16;
  for (int q = t; q < 2592; q += 256) {
    int p = q >> 3, seg = q & 7;
    int iy = p / 18, ix = p - iy * 18;
    short8 v = *(const short8*)(A1 +
        (((long)b * 130 + R0 + iy) * 130 + C0 + ix) * 64 + seg * 8);
    *(short8*)((char*)sX + p * 136 + seg * 16) = v;
  }
  __syncthreads();
  int w = t >> 6, l = t & 63, lr = l & 15, g = l >> 4;
  int Bb[4];
#pragma unroll
  for (int pt = 0; pt < 4; ++pt) {
    int p = pt * 16 + lr;
    int lp = 2 * (p >> 3) * 18 + 2 * (p & 7);
    Bb[pt] = lp * 136 + g * 16;
  }
  const short* pA0 = wA + (2 * w * 64 + l) * 8;
  const short* pA1 = pA0 + 512;
  f32x4 acc[2][4] = {};
  short8 a0 = *(const short8*)pA0;
  short8 a1 = *(const short8*)pA1;
  short8 bv[4];
#pragma unroll
  for (int i = 0; i < 4; ++i)
    bv[i] = *(const short8*)((const char*)sX + Bb[i]);
  for (int kc = 0; kc < 31; ++kc) {
    int nk = kc + 1;
    int tap = nk >> 1;
    int off = ((tap >> 2) * 18 + (tap & 3)) * 136 + (nk & 1) * 64;
    short8 na0 = *(const short8*)(pA0 + nk * 4096);
    short8 na1 = *(const short8*)(pA1 + nk * 4096);
    short8 nb[4];
#pragma unroll
    for (int i = 0; i < 4; ++i)
      nb[i] = *(const short8*)((const char*)sX + Bb[i] + off);
#pragma unroll
    for (int i = 0; i < 4; ++i) {
      acc[0][i] = MFMA(a0, bv[i], acc[0][i]);
      acc[1][i] = MFMA(a1, bv[i], acc[1][i]);
    }
    a0 = na0; a1 = na1;
#pragma unroll
    for (int i = 0; i < 4; ++i) bv[i] = nb[i];
  }
#pragma unroll
  for (int i = 0; i < 4; ++i) {
    acc[0][i] = MFMA(a0, bv[i], acc[0][i]);
    acc[1][i] = MFMA(a1, bv[i], acc[1][i]);
  }
#pragma unroll
  for (int oi = 0; oi < 2; ++oi) {
    int o0 = (2 * w + oi) * 16 + 4 * g;
#pragma unroll
    for (int pt = 0; pt < 4; ++pt) {
      int p = pt * 16 + lr;
      int y = by * 8 + (p >> 3), x = bx * 8 + (p & 7);
      f32x4 nv; short4v sv;
#pragma unroll
      for (int r = 0; r < 4; ++r) {
        float v = fmaxf(acc[oi][pt][r] + bias[o0 + r], 0.f);
        nv[r] = v; sv[r] = f2bf(v);
      }
      *(f32x4*)(Xf + ((b * 64 + y) * 64 + x) * 128 + o0) = nv;
      *(short4v*)(XrP + ((b * 66 + y + 1) * 66 + x + 1) * 128 + o0) = sv;
    }
  }
}

// ============================================================================
// res3 MFMA v2 (LDS-staged): XrP[66,66,128] -> Hr[64,64,32] bf16 relu
// grid 1024 = 32 b x 8 yt x 4 tx
// ============================================================================
__global__ __launch_bounds__(256) void k_res3m(const short* __restrict__ XrP,
    const short* __restrict__ wA, short* __restrict__ Hr) {
  __shared__ short sX[23040];  // 180 px * 128 shorts (256 B swizzled)
  int blk = blockIdx.x;
  int tx = blk & 3, yt = (blk >> 2) & 7, b = blk >> 5;
  int t = threadIdx.x;
  int r0 = yt * 8, c0 = tx * 16;
  for (int q = t; q < 2880; q += 256) {
    int p = q >> 4, seg = q & 15;
    int iy = p / 18, ix = p - iy * 18;
    short8 v = *(const short8*)(XrP +
        (((long)b * 66 + r0 + iy) * 66 + c0 + ix) * 128 + seg * 8);
    *(short8*)((char*)sX + p * 256 + ((seg * 16) ^ ((p & 7) << 4))) = v;
  }
  __syncthreads();
  int w = t >> 6, l = t & 63, lr = l & 15, g = l >> 4;
  const short* pA0 = wA + l * 8;
  const short* pA1 = pA0 + 512;
  f32x4 acc[2][2] = {};
  short8 a0 = *(const short8*)pA0;
  short8 a1 = *(const short8*)pA1;
  short8 bv[2];
#pragma unroll
  for (int j = 0; j < 2; ++j) {
    int lp = (2 * w + j) * 18 + lr;
    bv[j] = *(const short8*)((const char*)sX + lp * 256 +
                             ((g * 16) ^ ((lp & 7) << 4)));
  }
  for (int kc = 0; kc < 35; ++kc) {
    int nk = kc + 1;
    int tap = nk >> 2;
    int ky = tap / 3, kx = tap - ky * 3;
    int inner = g * 16 + (nk & 3) * 64;
    short8 na0 = *(const short8*)(pA0 + nk * 1024);
    short8 na1 = *(const short8*)(pA1 + nk * 1024);
    short8 nb[2];
#pragma unroll
    for (int j = 0; j < 2; ++j) {
      int lp = (2 * w + j + ky) * 18 + lr + kx;
      nb[j] = *(const short8*)((const char*)sX + lp * 256 +
                               (inner ^ ((lp & 7) << 4)));
    }
#pragma unroll
    for (int j = 0; j < 2; ++j) {
      acc[0][j] = MFMA(a0, bv[j], acc[0][j]);
      acc[1][j] = MFMA(a1, bv[j], acc[1][j]);
    }
    a0 = na0; a1 = na1;
    bv[0] = nb[0]; bv[1] = nb[1];
  }
#pragma unroll
  for (int j = 0; j < 2; ++j) {
    acc[0][j] = MFMA(a0, bv[j], acc[0][j]);
    acc[1][j] = MFMA(a1, bv[j], acc[1][j]);
  }
#pragma unroll
  for (int oi = 0; oi < 2; ++oi) {
    int o0 = oi * 16 + 4 * g;
#pragma unroll
    for (int j = 0; j < 2; ++j) {
      int y = r0 + 2 * w + j, x = c0 + lr;
      short4v sv;
#pragma unroll
      for (int r = 0; r < 4; ++r) sv[r] = f2bf(fmaxf(acc[oi][j][r], 0.f));
      *(short4v*)(Hr + ((b * 64 + y) * 64 + x) * 32 + o0) = sv;
    }
  }
}

// ============================================================================
// res1+add MFMA v2 (LDS-staged): Hr[64,64,32] -> Xf += conv1x1 ;
// XrP = relu(Xf) bf16. grid 2048 = 32 b x 8 by x 8 bx
// ============================================================================
__global__ __launch_bounds__(256) void k_res1addm(const short* __restrict__ Hr,
    const short* __restrict__ wA, float* __restrict__ Xf,
    short* __restrict__ XrP) {
  __shared__ short sH[64 * 40];  // 64 px * 40 sh (80 B stride)
  int blk = blockIdx.x;
  int bx = blk & 7, by = (blk >> 3) & 7, b = blk >> 6;
  int t = threadIdx.x, w = t >> 6, l = t & 63, lr = l & 15, g = l >> 4;
  {
    int p = t >> 2, seg = t & 3;
    int y = by * 8 + (p >> 3), x = bx * 8 + (p & 7);
    short8 v = *(const short8*)(Hr + ((b * 64 + y) * 64 + x) * 32 + seg * 8);
    *(short8*)(sH + p * 40 + seg * 8) = v;
  }
  __syncthreads();
  f32x4 acc[2][4] = {};
  short8 a0 = *(const short8*)(wA + (2 * w * 64 + l) * 8);
  short8 a1 = *(const short8*)(wA + ((2 * w + 1) * 64 + l) * 8);
#pragma unroll
  for (int i = 0; i < 4; ++i) {
    int p = i * 16 + lr;
    short8 bv = *(const short8*)(sH + p * 40 + 8 * g);
    acc[0][i] = MFMA(a0, bv, acc[0][i]);
    acc[1][i] = MFMA(a1, bv, acc[1][i]);
  }
#pragma unroll
  for (int oi = 0; oi < 2; ++oi) {
    int o0 = (2 * w + oi) * 16 + 4 * g;
#pragma unroll
    for (int i = 0; i < 4; ++i) {
      int p = i * 16 + lr;
      int y = by * 8 + (p >> 3), x = bx * 8 + (p & 7);
      float* xp = Xf + ((b * 64 + y) * 64 + x) * 128 + o0;
      f32x4 old = *(f32x4*)xp;
      f32x4 nv; short4v sv;
#pragma unroll
      for (int r = 0; r < 4; ++r) {
        nv[r] = old[r] + acc[oi][i][r];
        sv[r] = f2bf(fmaxf(nv[r], 0.f));
      }
      *(f32x4*)xp = nv;
      *(short4v*)(XrP + ((b * 66 + y + 1) * 66 + x + 1) * 128 + o0) = sv;
    }
  }
}

// ============================================================================
// pre 1x1 MFMA v2 (LDS-staged): XrP[66,66,128] -> Zcat[pix][256] bf16 =
// [zhi(128) | zlo(128)]. grid 2048 (8x8 pixels).
// ============================================================================
__global__ __launch_bounds__(256) void k_prem(const short* __restrict__ XrP,
    const short* __restrict__ wA, const float* __restrict__ bias,
    short* __restrict__ Zc) {
  __shared__ short sX[8192];  // 64 px * 128 sh, swizzled = 16 KB
  int blk = blockIdx.x;
  int bx = blk & 7, by = (blk >> 3) & 7, b = blk >> 6;
  int t = threadIdx.x, w = t >> 6, l = t & 63, lr = l & 15, g = l >> 4;
  for (int q = t; q < 1024; q += 256) {
    int p = q >> 4, seg = q & 15;
    int y = by * 8 + (p >> 3), x = bx * 8 + (p & 7);
    short8 v = *(const short8*)(XrP +
        ((b * 66 + y + 1) * 66 + x + 1) * 128 + seg * 8);
    *(short8*)((char*)sX + p * 256 + ((seg * 16) ^ ((p & 7) << 4))) = v;
  }
  __syncthreads();
  const short* pA0 = wA + (2 * w * 64 + l) * 8;
  const short* pA1 = pA0 + 512;
  f32x4 acc[2][4] = {};
#pragma unroll
  for (int kc = 0; kc < 4; ++kc) {
    short8 a0 = *(const short8*)(pA0 + kc * 4096);
    short8 a1 = *(const short8*)(pA1 + kc * 4096);
#pragma unroll
    for (int i = 0; i < 4; ++i) {
      int p = i * 16 + lr;
      short8 bv = *(const short8*)((const char*)sX + p * 256 +
                                   ((kc * 64 + g * 16) ^ ((p & 7) << 4)));
      acc[0][i] = MFMA(a0, bv, acc[0][i]);
      acc[1][i] = MFMA(a1, bv, acc[1][i]);
    }
  }
#pragma unroll
  for (int oi = 0; oi < 2; ++oi) {
    int o0 = (2 * w + oi) * 16 + 4 * g;
#pragma unroll
    for (int pt = 0; pt < 4; ++pt) {
      int p = pt * 16 + lr;
      int y = by * 8 + (p >> 3), x = bx * 8 + (p & 7);
      long pix = (long)(b * 64 + y) * 64 + x;
      short4v hv, lv;
#pragma unroll
      for (int r = 0; r < 4; ++r) {
        float v = acc[oi][pt][r] + bias[o0 + r];
        short hi = f2bf(v);
        hv[r] = hi;
        lv[r] = f2bf(v - bf2f(hi));
      }
      *(short4v*)(Zc + pix * 256 + o0) = hv;
      *(short4v*)(Zc + pix * 256 + 128 + o0) = lv;
    }
  }
}

// ============================================================================
// VQ MFMA v9 (async E-staging, 128 px): 128 px x 512 codes, 8 waves (512 thr),
// grid 1024. Halves Ecat L2 stream vs vqm8 (805->402 MB) and doubles MFMA per
// staging batch (32 per step ~ 155 cyc > L2 latency cover with 2 waves/SIMD).
// Wave w owns 64 codes -> acc[4][8] = 128 AGPR; A operands from LDS (sE slab,
// global_load_lds) -> low VGPR side, total ~205 unified (fits, no spill).
// Z tile 64 KB LDS (XOR swizzle). Fused argmin + hist + loss + gather.
// ============================================================================
__global__ __launch_bounds__(512) void k_vqm9(const short* __restrict__ Zc,
    const short* __restrict__ Ec, const float* __restrict__ en,
    const float* __restrict__ emb, int* __restrict__ counts,
    float* __restrict__ partials, float* __restrict__ Q,
    short* __restrict__ QrP) {
  __shared__ short sZ[32768];  // 128 px * 256 sh, swizzled = 64 KB
  __shared__ short sE[16384];  // E slab: 8 wave-regions x 2048 sh = 32 KB
  __shared__ float sV[8][128];
  __shared__ int sC[8][128];
  __shared__ float sZn[128];
  __shared__ int sIdx[128];
  __shared__ int sHist[KC];
  int blk = blockIdx.x;
  long pix0 = (long)blk * 128;
  int t = threadIdx.x, w = t >> 6, l = t & 63, c16 = l & 15, g = (l >> 4) & 3;
  for (int e = t; e < KC; e += 512) sHist[e] = 0;

  // stage Z tile: swizzle inner-byte ^ ((pix&7)<<4)
  for (int q = t; q < 4096; q += 512) {
    int p = q >> 5, seg = q & 31;
    short8 v = *(const short8*)(Zc + (pix0 + p) * 256 + seg * 8);
    *(short8*)((char*)sZ + p * 512 + ((seg * 16) ^ ((p & 7) << 4))) = v;
  }
  __syncthreads();

  // ||z||^2 per pixel from LDS: 4 threads/pixel, each 32 dims (128 px)
  {
    int pz = t >> 2, seg4 = t & 3;
    const char* zb = (const char*)sZ + pz * 512;
    int swp = (pz & 7) << 4;
    float s = 0.f;
#pragma unroll
    for (int qq = 0; qq < 4; ++qq) {
      int ih = seg4 * 64 + 16 * qq;  // zh inner byte
      short8 h8 = *(const short8*)(zb + (ih ^ swp));
      short8 l8 = *(const short8*)(zb + ((ih + 256) ^ swp));
#pragma unroll
      for (int j = 0; j < 8; ++j) {
        float zv = bf2f(h8[j]) + bf2f(l8[j]);
        s = fmaf(zv, zv, s);
      }
    }
    s += __shfl_xor(s, 1);
    s += __shfl_xor(s, 2);
    if (seg4 == 0) sZn[pz] = s;
  }

  // GEMM: 12 K-steps of 32; wave-local async E staging; 8 pixel-tiles.
  int sw = (c16 & 7) << 4;
  int zrow = c16 * 512;
  short* sEw = sE + w * 2048;                   // wave-uniform LDS base
  const short* gEw = Ec + w * 2048 + l * 8;     // per-lane global src
  f32x4 acc[4][8] = {};
  for (int kc = 0; kc < 12; ++kc) {
    if (kc) asm volatile("s_waitcnt lgkmcnt(0)" ::: "memory");
#pragma unroll
    for (int i = 0; i < 4; ++i)
      GLOAD_LDS16(gEw + kc * 16384 + i * 512, sEw + i * 512);
    asm volatile("s_waitcnt vmcnt(0)" ::: "memory");
    int koff = kc < 8 ? kc : kc - 8;
    int inn = ((koff * 64 + g * 16) ^ sw);
    const char* zb = (const char*)sZ + zrow + inn;
    short8 a0 = *(const short8*)(sEw + l * 8);
    short8 a1 = *(const short8*)(sEw + 512 + l * 8);
    short8 a2 = *(const short8*)(sEw + 1024 + l * 8);
    short8 a3 = *(const short8*)(sEw + 1536 + l * 8);
#pragma unroll
    for (int pt = 0; pt < 8; ++pt) {
      short8 bb = *(const short8*)(zb + pt * 8192);
      acc[0][pt] = MFMA(a0, bb, acc[0][pt]);
      acc[1][pt] = MFMA(a1, bb, acc[1][pt]);
      acc[2][pt] = MFMA(a2, bb, acc[2][pt]);
      acc[3][pt] = MFMA(a3, bb, acc[3][pt]);
    }
  }
  // running argmin over the wave's 64 codes (codes ascend: ct, r)
  float bvv[8];
  int bcc[8];
#pragma unroll
  for (int pt = 0; pt < 8; ++pt) { bvv[pt] = 3.4e38f; bcc[pt] = 0; }
#pragma unroll
  for (int ct = 0; ct < 4; ++ct) {
    f32x4 en4 = *(const f32x4*)(en + w * 64 + ct * 16 + 4 * g);
#pragma unroll
    for (int pt = 0; pt < 8; ++pt) {
#pragma unroll
      for (int r = 0; r < 4; ++r) {
        float d = en4[r] - 2.f * acc[ct][pt][r];
        int code = w * 64 + ct * 16 + 4 * g + r;
        if (d < bvv[pt]) { bvv[pt] = d; bcc[pt] = code; }
      }
    }
  }
  // cross-lane reduce (over g) per pixel
#pragma unroll
  for (int pt = 0; pt < 8; ++pt) {
    float bv = bvv[pt];
    int bc = bcc[pt];
#pragma unroll
    for (int m = 16; m <= 32; m <<= 1) {
      float ov = __shfl_xor(bv, m);
      int oc = __shfl_xor(bc, m);
      if (ov < bv || (ov == bv && oc < bc)) { bv = ov; bc = oc; }
    }
    if (g == 0) {
      sV[w][pt * 16 + c16] = bv;
      sC[w][pt * 16 + c16] = bc;
    }
  }
  __syncthreads();
  if (t < 128) {
    float bv = sV[0][t];
    int bc = sC[0][t];
#pragma unroll
    for (int w2 = 1; w2 < 8; ++w2) {
      float v = sV[w2][t];
      int c = sC[w2][t];
      if (v < bv || (v == bv && c < bc)) { bv = v; bc = c; }
    }
    sIdx[t] = bc;
    atomicAdd(&sHist[bc], 1);
    sV[0][t] = bv + sZn[t];
  }
  __syncthreads();
  if (t < 64) {
    float ls = sV[0][t] + sV[0][t + 64];
#pragma unroll
    for (int m = 32; m >= 1; m >>= 1) ls += __shfl_xor(ls, m);
    if (t == 0) partials[blk] = ls;
  }
  for (int e = t; e < KC; e += 512) {
    int c = sHist[e];
    if (c) atomicAdd(&counts[e], c);
  }
  // fused gather: Q = emb[idx] f32 (overwrites this block's Zc bytes),
  // QrP = relu bf16 (padded layout)
  for (int e = t; e < 4096; e += 512) {
    int p = e >> 5, d4 = (e & 31) << 2;
    int c = sIdx[p];
    f32x4 q = *(const f32x4*)(emb + c * DD + d4);
    *(f32x4*)(Q + (pix0 + p) * DD + d4) = q;
    short4v sv;
#pragma unroll
    for (int r = 0; r < 4; ++r) sv[r] = f2bf(fmaxf(q[r], 0.f));
    long pixg = pix0 + p;
    int xx = (int)(pixg & 63), yy = (int)((pixg >> 6) & 63),
        bb = (int)(pixg >> 12);
    *(short4v*)(QrP + (((long)(bb * 66 + yy + 1)) * 66 + xx + 1) * 128 + d4) =
        sv;
  }
}

// ============================================================================
// tconv1 MFMA v2 (LDS-staged): QrP[66,66,128] -> T1[130,130,64] bf16 relu
// grid 2048 = 32 b x 8 tyt x 8 txt
// ============================================================================
__global__ __launch_bounds__(256) void k_tconv1m(const short* __restrict__ QrP,
    const short* __restrict__ wA, const float* __restrict__ bias,
    short* __restrict__ T1) {
  __shared__ short sX[13600];  // 100 pixels x 136 shorts
  int blk = blockIdx.x;
  int txt = blk & 7, tyt = (blk >> 3) & 7, b = blk >> 6;
  int my0 = tyt * 8, mx0 = txt * 8;
  int t = threadIdx.x;
  for (int q = t; q < 1600; q += 256) {
    int p = q >> 4, seg = q & 15;
    int iy = p / 10, ix = p - iy * 10;
    short8 v = *(const short8*)(QrP +
        ((b * 66 + my0 + iy) * 66 + mx0 + ix) * 128 + seg * 8);
    *(short8*)((char*)sX + p * 272 + seg * 16) = v;
  }
  __syncthreads();
  int w = t >> 6, l = t & 63, lr = l & 15, g = l >> 4;
  int pyr = w >> 1, pxr = w & 1;
  int Bb[4];
#pragma unroll
  for (int nt = 0; nt < 4; ++nt) {
    int p = nt * 16 + lr;
    int my = p >> 3, mx = p & 7;
    Bb[nt] = ((my + pyr + 1) * 10 + (mx + pxr + 1)) * 272 + g * 16;
  }
  const short* pAw = wA + w * 32768 + l * 8;
  f32x4 acc[4][4] = {};
  short8 a[4], bfr[4], na[4], nb[4];
#pragma unroll
  for (int ot = 0; ot < 4; ++ot) a[ot] = *(const short8*)(pAw + ot * 512);
#pragma unroll
  for (int nt = 0; nt < 4; ++nt)
    bfr[nt] = *(const short8*)((const char*)sX + Bb[nt]);
  for (int kc = 0; kc < 15; ++kc) {
    int nk = kc + 1;
    int tt = nk >> 2, dy = tt >> 1, dx = tt & 1;
    int off = -(dy * 10 + dx) * 272 + (nk & 3) * 64;
#pragma unroll
    for (int ot = 0; ot < 4; ++ot)
      na[ot] = *(const short8*)(pAw + nk * 2048 + ot * 512);
#pragma unroll
    for (int nt = 0; nt < 4; ++nt)
      nb[nt] = *(const short8*)((const char*)sX + Bb[nt] + off);
#pragma unroll
    for (int ot = 0; ot < 4; ++ot)
#pragma unroll
      for (int nt = 0; nt < 4; ++nt)
        acc[ot][nt] = MFMA(a[ot], bfr[nt], acc[ot][nt]);
#pragma unroll
    for (int ot = 0; ot < 4; ++ot) a[ot] = na[ot];
#pragma unroll
    for (int nt = 0; nt < 4; ++nt) bfr[nt] = nb[nt];
  }
#pragma unroll
  for (int ot = 0; ot < 4; ++ot)
#pragma unroll
    for (int nt = 0; nt < 4; ++nt)
      acc[ot][nt] = MFMA(a[ot], bfr[nt], acc[ot][nt]);
#pragma unroll
  for (int ot = 0; ot < 4; ++ot) {
    int o0 = ot * 16 + 4 * g;
    f32x4 b4 = *(const f32x4*)(bias + o0);
#pragma unroll
    for (int nt = 0; nt < 4; ++nt) {
      int p = nt * 16 + lr;
      int my = my0 + (p >> 3), mx = mx0 + (p & 7);
      int oy = 2 * my + pyr, ox = 2 * mx + pxr;
      short4v sv;
#pragma unroll
      for (int r = 0; r < 4; ++r)
        sv[r] = f2bf(fmaxf(acc[ot][nt][r] + b4[r], 0.f));
      *(short4v*)(T1 + ((b * 130 + oy + 1) * 130 + ox + 1) * 64 + o0) = sv;
    }
  }
}

// ============================================================================
// tconv2 VALU: T1[130,130,64] bf16 -> x_recon[32,256,256] f32
// ============================================================================
__global__ __launch_bounds__(256) void k_tconv2(const short* __restrict__ T1,
    const float* __restrict__ w, const float* __restrict__ bias,
    float* __restrict__ xrec) {
  __shared__ float sW[1024];
  int t = threadIdx.x;
  for (int e = t; e < 1024; e += 256) sW[e] = w[e];
  __syncthreads();
  int blk = blockIdx.x;
  int tx = blk & 15, ty = (blk >> 4) & 15, b = blk >> 8;
  int row = t >> 4, col = t & 15;
  int oy = ty * 16 + row, ox = tx * 16 + col;
  int pyr = oy & 1, pxr = ox & 1;
  int kye = 1 - pyr, kxe = 1 - pxr;
  int m = oy >> 1, n = ox >> 1;
  float acc = bias[0];
#pragma unroll
  for (int dy = 0; dy < 2; ++dy) {
#pragma unroll
    for (int dx = 0; dx < 2; ++dx) {
      const short* ip =
          T1 + ((b * 130 + m + pyr - dy + 1) * 130 + (n + pxr - dx + 1)) * 64;
      int tap = (kye + 2 * dy) * 4 + (kxe + 2 * dx);
#pragma unroll
      for (int c8 = 0; c8 < 8; ++c8) {
        short8 v = *(const short8*)(ip + c8 * 8);
#pragma unroll
        for (int i = 0; i < 8; ++i)
          acc = fmaf(bf2f(v[i]), sW[(c8 * 8 + i) * 16 + tap], acc);
      }
    }
  }
  xrec[(b * 256 + oy) * 256 + ox] = acc;
}

// ============================================================================
// finalize: loss from 1024 partials; perplexity from counts
// ============================================================================
__global__ __launch_bounds__(256) void k_final(const float* __restrict__ partials,
    const int* __restrict__ counts, float* __restrict__ out) {
  int t = threadIdx.x;
  float s = 0.f;
  for (int i = t; i < 1024; i += 256) s += partials[i];
#pragma unroll
  for (int m = 32; m >= 1; m >>= 1) s += __shfl_xor(s, m);
  __shared__ float sr[4];
  if ((t & 63) == 0) sr[t >> 6] = s;
  __syncthreads();
  if (t == 0) {
    float tot = sr[0] + sr[1] + sr[2] + sr[3];
    out[0] = 1.25f * tot / 16777216.0f;
  }
  float h = 0.f;
  for (int c = t; c < KC; c += 256) {
    float avg = (float)counts[c] / 131072.0f;
    h += avg * logf(avg + 1e-10f);
  }
#pragma unroll
  for (int m = 32; m >= 1; m >>= 1) h += __shfl_xor(h, m);
  __shared__ float sr2[4];
  if ((t & 63) == 0) sr2[t >> 6] = h;
  __syncthreads();
  if (t == 0) out[1 + 32 * 256 * 256] = expf(-(sr2[0] + sr2[1] + sr2[2] + sr2[3]));
}

// ============================================================================
extern "C" void kernel_launch(void* const* d_in, const int* in_sizes, int n_in,
                              void* d_out, int out_size, void* d_ws, size_t ws_size,
                              hipStream_t stream) {
  const float* x    = (const float*)d_in[0];
  const float* c1w  = (const float*)d_in[1];
  const float* c1b  = (const float*)d_in[2];
  const float* c2w  = (const float*)d_in[3];
  const float* c2b  = (const float*)d_in[4];
  const float* r1w3 = (const float*)d_in[5];
  const float* r1w1 = (const float*)d_in[6];
  const float* r2w3 = (const float*)d_in[7];
  const float* r2w1 = (const float*)d_in[8];
  const float* prew = (const float*)d_in[9];
  const float* preb = (const float*)d_in[10];
  const float* emb  = (const float*)d_in[11];
  const float* d1w3 = (const float*)d_in[12];
  const float* d1w1 = (const float*)d_in[13];
  const float* d2w3 = (const float*)d_in[14];
  const float* d2w1 = (const float*)d_in[15];
  const float* t1w  = (const float*)d_in[16];
  const float* t1b  = (const float*)d_in[17];
  const float* t2w  = (const float*)d_in[18];
  const float* t2b  = (const float*)d_in[19];
  float* out = (float*)d_out;

  char* ws = (char*)d_ws;
  short* buf0 = (short*)(ws);                      // A1 / T1 : 69,222,400 B
  float* bufX = (float*)(ws + 69222400);           // Xf / Zcat / Q : 67,108,864 B
  short* bufR = (short*)(ws + 136331264);          // XrP / QrP : 35,684,352 B
  short* Hr   = (short*)(ws + 172015616);          // 8,388,608 B -> ends 180404224
  int*   counts = (int*)(ws + 180928512);          // 2,048 B
  float* partials = (float*)(ws + 180930560);      // 8,192 B
  float* en   = (float*)(ws + 180938752);          // 2,048 B
  short* wAc2 = (short*)(ws + 180940800);          // 262,144 B
  short* wAr3 = (short*)(ws + 181202944);          // 294,912 B
  short* wAr1 = (short*)(ws + 181497856);          // 32,768 B
  short* wApre= (short*)(ws + 181530624);          // 32,768 B
  short* wAt1 = (short*)(ws + 181563392);          // 262,144 B
  short* Ecat = (short*)(ws + 181825536);          // 393,216 B -> ends 182,218,752

  short* Zcat = (short*)bufX;  // 67,108,864 B (Xf dead after enc res1addm#2;
                               // Q gather overwrites Zcat block-locally)

  short* wAr3_e1 = wAr3;
  short* wAr3_e2 = wAr3 + 36864;
  short* wAr3_d1 = wAr3 + 2 * 36864;
  short* wAr3_d2 = wAr3 + 3 * 36864;
  short* wAr1_e1 = wAr1;
  short* wAr1_e2 = wAr1 + 4096;
  short* wAr1_d1 = wAr1 + 2 * 4096;
  short* wAr1_d2 = wAr1 + 3 * 4096;

  hipMemsetAsync(counts, 0, KC * sizeof(int), stream);

  k_prep <<<2880, 256, 0, stream>>>(c2w, r1w3, r2w3, d1w3, d2w3,
                                    r1w1, r2w1, d1w1, d2w1, prew, t1w, emb,
                                    wAc2, wAr3, wAr1, wApre, wAt1, Ecat,
                                    en, buf0, bufR);

  k_conv1   <<<4096, 256, 0, stream>>>(x, c1w, c1b, buf0);
  k_conv2m  <<<2048, 256, 0, stream>>>(buf0, wAc2, c2b, bufX, bufR);
  k_res3m   <<<1024, 256, 0, stream>>>(bufR, wAr3_e1, Hr);
  k_res1addm<<<2048, 256, 0, stream>>>(Hr, wAr1_e1, bufX, bufR);
  k_res3m   <<<1024, 256, 0, stream>>>(bufR, wAr3_e2, Hr);
  k_res1addm<<<2048, 256, 0, stream>>>(Hr, wAr1_e2, bufX, bufR);
  k_prem    <<<2048, 256, 0, stream>>>(bufR, wApre, preb, Zcat);
  k_vqm9    <<<1024, 512, 0, stream>>>(Zcat, Ecat, en, emb, counts, partials,
                                       bufX, bufR);
  k_res3m   <<<1024, 256, 0, stream>>>(bufR, wAr3_d1, Hr);
  k_res1addm<<<2048, 256, 0, stream>>>(Hr, wAr1_d1, bufX, bufR);
  k_res3m   <<<1024, 256, 0, stream>>>(bufR, wAr3_d2, Hr);
  k_res1addm<<<2048, 256, 0, stream>>>(Hr, wAr1_d2, bufX, bufR);
  k_tconv1m <<<2048, 256, 0, stream>>>(bufR, wAt1, t1b, buf0);
  k_tconv2  <<<8192, 256, 0, stream>>>(buf0, t2w, t2b, out + 1);
  k_final   <<<1, 256, 0, stream>>>(partials, counts, out);
}

// Round 11
// 543.849 us; speedup vs baseline: 1.4331x; 1.1365x over previous
//
#include <hip/hip_runtime.h>
#include <math.h>

#define KC 512
#define DD 128

typedef __attribute__((ext_vector_type(8))) short short8;
typedef __attribute__((ext_vector_type(4))) short short4v;
typedef __attribute__((ext_vector_type(4))) float f32x4;

#define MFMA(a, b, c) __builtin_amdgcn_mfma_f32_16x16x32_bf16(a, b, c, 0, 0, 0)

#define GLOAD_LDS16(g, l)                                        \
  __builtin_amdgcn_global_load_lds(                              \
      (const __attribute__((address_space(1))) void*)(g),        \
      (__attribute__((address_space(3))) void*)(l), 16, 0, 0)

__device__ __forceinline__ short f2bf(float f) {
  unsigned u = __float_as_uint(f);
  u = (u + 0x7FFFu + ((u >> 16) & 1u)) >> 16;
  return (short)u;
}
__device__ __forceinline__ float bf2f(short s) {
  return __uint_as_float(((unsigned)(unsigned short)s) << 16);
}

// ============================================================================
// k_prep: ALL weight permutations + embnorm + border-zero + counts-zero in
// ONE dispatch. Block ranges:
//   [0,512)      perm_c2      [512,1088)   perm_r3 x4   [1088,1152) perm_r1 x4
//   [1152,1216)  perm_pre     [1216,1728)  perm_t1      [1728,2496) perm_E
//   [2496,2624)  embnorm (4 codes/blk)     [2624,2880)  border
//   [2880]       counts zero
// grid 2881 x 256
// ============================================================================
__global__ __launch_bounds__(256) void k_prep(
    const float* __restrict__ c2w,
    const float* __restrict__ r1w3, const float* __restrict__ r2w3,
    const float* __restrict__ d1w3, const float* __restrict__ d2w3,
    const float* __restrict__ r1w1, const float* __restrict__ r2w1,
    const float* __restrict__ d1w1, const float* __restrict__ d2w1,
    const float* __restrict__ prew, const float* __restrict__ t1w,
    const float* __restrict__ emb,
    short* __restrict__ wAc2, short* __restrict__ wAr3,
    short* __restrict__ wAr1, short* __restrict__ wApre,
    short* __restrict__ wAt1, short* __restrict__ Ecat,
    float* __restrict__ en, short* __restrict__ A1,
    short* __restrict__ XrP, int* __restrict__ counts) {
  int blk = blockIdx.x, t = threadIdx.x;
  if (blk < 512) {  // perm_c2
    int e = blk * 256 + t;
    int j = e & 7, l = (e >> 3) & 63, ot = (e >> 9) & 7, kc = e >> 12;
    int o = ot * 16 + (l & 15), g = l >> 4;
    int tap = kc >> 1, ci = (kc & 1) * 32 + 8 * g + j;
    wAc2[e] = f2bf(c2w[(o * 64 + ci) * 16 + tap]);
  } else if (blk < 1088) {  // perm_r3 x4
    int sub = blk - 512;
    int which = sub / 144, bb = sub - which * 144;
    const float* w = which == 0 ? r1w3 : which == 1 ? r2w3
                     : which == 2 ? d1w3 : d2w3;
    short* dst = wAr3 + which * 36864;
    int e = bb * 256 + t;
    int j = e & 7, l = (e >> 3) & 63, ot = (e >> 9) & 1, kc = e >> 10;
    int o = ot * 16 + (l & 15), g = l >> 4;
    int tap = kc >> 2, ci = (kc & 3) * 32 + 8 * g + j;
    dst[e] = f2bf(w[(o * 128 + ci) * 9 + tap]);
  } else if (blk < 1152) {  // perm_r1 x4
    int sub = blk - 1088;
    int which = sub >> 4, bb = sub & 15;
    const float* w = which == 0 ? r1w1 : which == 1 ? r2w1
                     : which == 2 ? d1w1 : d2w1;
    short* dst = wAr1 + which * 4096;
    int e = bb * 256 + t;
    int j = e & 7, l = (e >> 3) & 63, ot = e >> 9;
    int o = ot * 16 + (l & 15), g = l >> 4;
    int ci = 8 * g + j;
    dst[e] = f2bf(w[o * 32 + ci]);
  } else if (blk < 1216) {  // perm_pre
    int e = (blk - 1152) * 256 + t;
    int j = e & 7, l = (e >> 3) & 63, ot = (e >> 9) & 7, kc = e >> 12;
    int o = ot * 16 + (l & 15), g = l >> 4;
    int ci = kc * 32 + 8 * g + j;
    wApre[e] = f2bf(prew[o * 128 + ci]);
  } else if (blk < 1728) {  // perm_t1
    int e = (blk - 1216) * 256 + t;
    int j = e & 7, l = (e >> 3) & 63, ot = (e >> 9) & 3, kc = (e >> 11) & 15,
        pp = e >> 15;
    int pyr = pp >> 1, pxr = pp & 1;
    int o = ot * 16 + (l & 15), g = l >> 4;
    int tt = kc >> 2, dy = tt >> 1, dx = tt & 1;
    int ky = (1 - pyr) + 2 * dy, kx = (1 - pxr) + 2 * dx;
    int ci = (kc & 3) * 32 + 8 * g + j;
    wAt1[e] = f2bf(t1w[(ci * 64 + o) * 16 + ky * 4 + kx]);
  } else if (blk < 2496) {  // perm_E
    int e = (blk - 1728) * 256 + t;
    int j = e & 7, l = (e >> 3) & 63, ot = (e >> 9) & 31, kc = e >> 14;
    int c = ot * 16 + (l & 15);
    int k = kc * 32 + 8 * (l >> 4) + j;
    float v = emb[c * DD + (k & 127)];
    short hi = f2bf(v);
    Ecat[e] = (k < 256) ? hi : f2bf(v - bf2f(hi));
  } else if (blk < 2624) {  // embnorm: 4 codes per block (wave = code)
    int c = (blk - 2496) * 4 + (t >> 6), l = t & 63;
    float a = emb[c * DD + l], b2 = emb[c * DD + 64 + l];
    float s = a * a + b2 * b2;
#pragma unroll
    for (int m = 32; m >= 1; m >>= 1) s += __shfl_xor(s, m);
    if (l == 0) en[c] = s;
  } else if (blk < 2880) {  // border zero
    int bb = blk - 2624;
    int b = bb >> 3;
    int tid = ((bb & 7) << 8) + t;  // 0..2047
    short8 z8 = {};
    long baseA = (long)b * 1081600;  // 130*130*64
    for (int e = tid; e < 2080; e += 2048) {
      int r = e >= 1040;
      int rem = r ? e - 1040 : e;
      *(short8*)(A1 + baseA + (r ? 129L * 130 * 64 : 0) + rem * 8) = z8;
    }
    {
      int c = tid >> 10, rem = tid & 1023;
      int row = 1 + (rem >> 3), s8 = rem & 7;
      *(short8*)(A1 + baseA + (row * 130L + (c ? 129 : 0)) * 64 + s8 * 8) = z8;
    }
    long baseX = (long)b * 557568;  // 66*66*128
    for (int e = tid; e < 2112; e += 2048) {
      int r = e >= 1056;
      int rem = r ? e - 1056 : e;
      *(short8*)(XrP + baseX + (r ? 65L * 66 * 128 : 0) + rem * 8) = z8;
    }
    {
      int c = tid >> 10, rem = tid & 1023;
      int row = 1 + (rem >> 4), s8 = rem & 15;
      *(short8*)(XrP + baseX + (row * 66L + (c ? 65 : 0)) * 128 + s8 * 8) = z8;
    }
  } else {  // counts zero
    counts[t] = 0;
    counts[t + 256] = 0;
  }
}

// ============================================================================
// conv1: x[32,1,256,256] f32 -> A1[32,130,130,64] bf16 relu (padded, ch-last)
// grid 4096 = 32 b x 128 y
// ============================================================================
__global__ __launch_bounds__(256) void k_conv1(const float* __restrict__ x,
    const float* __restrict__ w, const float* __restrict__ bias,
    short* __restrict__ A1) {
  __shared__ float sXp[4 * 260];
  __shared__ float sWt[16 * 64];
  int blk = blockIdx.x;
  int y = blk & 127, b = blk >> 7;
  int t = threadIdx.x;
  for (int e = t; e < 1024; e += 256) sWt[e] = w[(e & 63) * 16 + (e >> 6)];
  if (t < 4) {
    sXp[t * 260] = 0.f;
    sXp[t * 260 + 257] = 0.f;
    sXp[t * 260 + 258] = 0.f;
    sXp[t * 260 + 259] = 0.f;
  }
  for (int e = t; e < 1024; e += 256) {
    int r = e >> 8, col = e & 255;
    int giy = 2 * y - 1 + r;
    float v = 0.f;
    if ((unsigned)giy < 256u) v = x[(b * 256 + giy) * 256 + col];
    sXp[r * 260 + col + 1] = v;
  }
  __syncthreads();
  int og = t >> 6, l = t & 63, o0 = og * 16;
  float acc0[16], acc1[16];
#pragma unroll
  for (int oo = 0; oo < 16; ++oo) { acc0[oo] = 0.f; acc1[oo] = 0.f; }
  int xA = 2 * l, xB = 2 * l + 128;
#pragma unroll
  for (int ky = 0; ky < 4; ++ky) {
#pragma unroll
    for (int kx = 0; kx < 4; ++kx) {
      float a0 = sXp[ky * 260 + xA + kx];
      float a1 = sXp[ky * 260 + xB + kx];
      const float* wrow = &sWt[(ky * 4 + kx) * 64 + o0];
#pragma unroll
      for (int oo = 0; oo < 16; ++oo) {
        float wv = wrow[oo];
        acc0[oo] = fmaf(a0, wv, acc0[oo]);
        acc1[oo] = fmaf(a1, wv, acc1[oo]);
      }
    }
  }
  long base0 = (((long)(b * 130 + y + 1)) * 130 + l + 1) * 64 + o0;
  long base1 = base0 + 64 * 64;
  short8 s0a, s0b, s1a, s1b;
#pragma unroll
  for (int oo = 0; oo < 8; ++oo) {
    s0a[oo] = f2bf(fmaxf(acc0[oo] + bias[o0 + oo], 0.f));
    s0b[oo] = f2bf(fmaxf(acc0[oo + 8] + bias[o0 + oo + 8], 0.f));
    s1a[oo] = f2bf(fmaxf(acc1[oo] + bias[o0 + oo], 0.f));
    s1b[oo] = f2bf(fmaxf(acc1[oo + 8] + bias[o0 + oo + 8], 0.f));
  }
  *(short8*)(A1 + base0) = s0a;
  *(short8*)(A1 + base0 + 8) = s0b;
  *(short8*)(A1 + base1) = s1a;
  *(short8*)(A1 + base1 + 8) = s1b;
}

// ============================================================================
// conv2 MFMA v2 (LDS-staged): A1[130,130,64] bf16 -> relu -> Xf[64,64,128] f32
// + XrP[66,66,128] bf16. grid 2048 = 32 b x 8 by x 8 bx
// ============================================================================
__global__ __launch_bounds__(256) void k_conv2m(const short* __restrict__ A1,
    const short* __restrict__ wA, const float* __restrict__ bias,
    float* __restrict__ Xf, short* __restrict__ XrP) {
  __shared__ short sX[22032];  // 324 px * 68 shorts (136 B) = 44,064 B
  int blk = blockIdx.x;
  int bx = blk & 7, by = (blk >> 3) & 7, b = blk >> 6;
  int t = threadIdx.x;
  int R0 = by * 16, C0 = bx * 16;
  for (int q = t; q < 2592; q += 256) {
    int p = q >> 3, seg = q & 7;
    int iy = p / 18, ix = p - iy * 18;
    short8 v = *(const short8*)(A1 +
        (((long)b * 130 + R0 + iy) * 130 + C0 + ix) * 64 + seg * 8);
    *(short8*)((char*)sX + p * 136 + seg * 16) = v;
  }
  __syncthreads();
  int w = t >> 6, l = t & 63, lr = l & 15, g = l >> 4;
  int Bb[4];
#pragma unroll
  for (int pt = 0; pt < 4; ++pt) {
    int p = pt * 16 + lr;
    int lp = 2 * (p >> 3) * 18 + 2 * (p & 7);
    Bb[pt] = lp * 136 + g * 16;
  }
  const short* pA0 = wA + (2 * w * 64 + l) * 8;
  const short* pA1 = pA0 + 512;
  f32x4 acc[2][4] = {};
  short8 a0 = *(const short8*)pA0;
  short8 a1 = *(const short8*)pA1;
  short8 bv[4];
#pragma unroll
  for (int i = 0; i < 4; ++i)
    bv[i] = *(const short8*)((const char*)sX + Bb[i]);
  for (int kc = 0; kc < 31; ++kc) {
    int nk = kc + 1;
    int tap = nk >> 1;
    int off = ((tap >> 2) * 18 + (tap & 3)) * 136 + (nk & 1) * 64;
    short8 na0 = *(const short8*)(pA0 + nk * 4096);
    short8 na1 = *(const short8*)(pA1 + nk * 4096);
    short8 nb[4];
#pragma unroll
    for (int i = 0; i < 4; ++i)
      nb[i] = *(const short8*)((const char*)sX + Bb[i] + off);
#pragma unroll
    for (int i = 0; i < 4; ++i) {
      acc[0][i] = MFMA(a0, bv[i], acc[0][i]);
      acc[1][i] = MFMA(a1, bv[i], acc[1][i]);
    }
    a0 = na0; a1 = na1;
#pragma unroll
    for (int i = 0; i < 4; ++i) bv[i] = nb[i];
  }
#pragma unroll
  for (int i = 0; i < 4; ++i) {
    acc[0][i] = MFMA(a0, bv[i], acc[0][i]);
    acc[1][i] = MFMA(a1, bv[i], acc[1][i]);
  }
#pragma unroll
  for (int oi = 0; oi < 2; ++oi) {
    int o0 = (2 * w + oi) * 16 + 4 * g;
#pragma unroll
    for (int pt = 0; pt < 4; ++pt) {
      int p = pt * 16 + lr;
      int y = by * 8 + (p >> 3), x = bx * 8 + (p & 7);
      f32x4 nv; short4v sv;
#pragma unroll
      for (int r = 0; r < 4; ++r) {
        float v = fmaxf(acc[oi][pt][r] + bias[o0 + r], 0.f);
        nv[r] = v; sv[r] = f2bf(v);
      }
      *(f32x4*)(Xf + ((b * 64 + y) * 64 + x) * 128 + o0) = nv;
      *(short4v*)(XrP + ((b * 66 + y + 1) * 66 + x + 1) * 128 + o0) = sv;
    }
  }
}

// ============================================================================
// res3 MFMA v2 (LDS-staged): XrP[66,66,128] -> Hr[64,64,32] bf16 relu
// grid 1024 = 32 b x 8 yt x 4 tx
// ============================================================================
__global__ __launch_bounds__(256) void k_res3m(const short* __restrict__ XrP,
    const short* __restrict__ wA, short* __restrict__ Hr) {
  __shared__ short sX[23040];  // 180 px * 128 shorts (256 B swizzled)
  int blk = blockIdx.x;
  int tx = blk & 3, yt = (blk >> 2) & 7, b = blk >> 5;
  int t = threadIdx.x;
  int r0 = yt * 8, c0 = tx * 16;
  for (int q = t; q < 2880; q += 256) {
    int p = q >> 4, seg = q & 15;
    int iy = p / 18, ix = p - iy * 18;
    short8 v = *(const short8*)(XrP +
        (((long)b * 66 + r0 + iy) * 66 + c0 + ix) * 128 + seg * 8);
    *(short8*)((char*)sX + p * 256 + ((seg * 16) ^ ((p & 7) << 4))) = v;
  }
  __syncthreads();
  int w = t >> 6, l = t & 63, lr = l & 15, g = l >> 4;
  const short* pA0 = wA + l * 8;
  const short* pA1 = pA0 + 512;
  f32x4 acc[2][2] = {};
  short8 a0 = *(const short8*)pA0;
  short8 a1 = *(const short8*)pA1;
  short8 bv[2];
#pragma unroll
  for (int j = 0; j < 2; ++j) {
    int lp = (2 * w + j) * 18 + lr;
    bv[j] = *(const short8*)((const char*)sX + lp * 256 +
                             ((g * 16) ^ ((lp & 7) << 4)));
  }
  for (int kc = 0; kc < 35; ++kc) {
    int nk = kc + 1;
    int tap = nk >> 2;
    int ky = tap / 3, kx = tap - ky * 3;
    int inner = g * 16 + (nk & 3) * 64;
    short8 na0 = *(const short8*)(pA0 + nk * 1024);
    short8 na1 = *(const short8*)(pA1 + nk * 1024);
    short8 nb[2];
#pragma unroll
    for (int j = 0; j < 2; ++j) {
      int lp = (2 * w + j + ky) * 18 + lr + kx;
      nb[j] = *(const short8*)((const char*)sX + lp * 256 +
                               (inner ^ ((lp & 7) << 4)));
    }
#pragma unroll
    for (int j = 0; j < 2; ++j) {
      acc[0][j] = MFMA(a0, bv[j], acc[0][j]);
      acc[1][j] = MFMA(a1, bv[j], acc[1][j]);
    }
    a0 = na0; a1 = na1;
    bv[0] = nb[0]; bv[1] = nb[1];
  }
#pragma unroll
  for (int j = 0; j < 2; ++j) {
    acc[0][j] = MFMA(a0, bv[j], acc[0][j]);
    acc[1][j] = MFMA(a1, bv[j], acc[1][j]);
  }
#pragma unroll
  for (int oi = 0; oi < 2; ++oi) {
    int o0 = oi * 16 + 4 * g;
#pragma unroll
    for (int j = 0; j < 2; ++j) {
      int y = r0 + 2 * w + j, x = c0 + lr;
      short4v sv;
#pragma unroll
      for (int r = 0; r < 4; ++r) sv[r] = f2bf(fmaxf(acc[oi][j][r], 0.f));
      *(short4v*)(Hr + ((b * 64 + y) * 64 + x) * 32 + o0) = sv;
    }
  }
}

// ============================================================================
// res1+add MFMA v2 (LDS-staged): Hr[64,64,32] -> Xf += conv1x1 ;
// XrP = relu(Xf) bf16. grid 2048 = 32 b x 8 by x 8 bx
// ============================================================================
__global__ __launch_bounds__(256) void k_res1addm(const short* __restrict__ Hr,
    const short* __restrict__ wA, float* __restrict__ Xf,
    short* __restrict__ XrP) {
  __shared__ short sH[64 * 40];  // 64 px * 40 sh (80 B stride)
  int blk = blockIdx.x;
  int bx = blk & 7, by = (blk >> 3) & 7, b = blk >> 6;
  int t = threadIdx.x, w = t >> 6, l = t & 63, lr = l & 15, g = l >> 4;
  {
    int p = t >> 2, seg = t & 3;
    int y = by * 8 + (p >> 3), x = bx * 8 + (p & 7);
    short8 v = *(const short8*)(Hr + ((b * 64 + y) * 64 + x) * 32 + seg * 8);
    *(short8*)(sH + p * 40 + seg * 8) = v;
  }
  __syncthreads();
  f32x4 acc[2][4] = {};
  short8 a0 = *(const short8*)(wA + (2 * w * 64 + l) * 8);
  short8 a1 = *(const short8*)(wA + ((2 * w + 1) * 64 + l) * 8);
#pragma unroll
  for (int i = 0; i < 4; ++i) {
    int p = i * 16 + lr;
    short8 bv = *(const short8*)(sH + p * 40 + 8 * g);
    acc[0][i] = MFMA(a0, bv, acc[0][i]);
    acc[1][i] = MFMA(a1, bv, acc[1][i]);
  }
#pragma unroll
  for (int oi = 0; oi < 2; ++oi) {
    int o0 = (2 * w + oi) * 16 + 4 * g;
#pragma unroll
    for (int i = 0; i < 4; ++i) {
      int p = i * 16 + lr;
      int y = by * 8 + (p >> 3), x = bx * 8 + (p & 7);
      float* xp = Xf + ((b * 64 + y) * 64 + x) * 128 + o0;
      f32x4 old = *(f32x4*)xp;
      f32x4 nv; short4v sv;
#pragma unroll
      for (int r = 0; r < 4; ++r) {
        nv[r] = old[r] + acc[oi][i][r];
        sv[r] = f2bf(fmaxf(nv[r], 0.f));
      }
      *(f32x4*)xp = nv;
      *(short4v*)(XrP + ((b * 66 + y + 1) * 66 + x + 1) * 128 + o0) = sv;
    }
  }
}

// ============================================================================
// pre 1x1 MFMA v2 (LDS-staged): XrP[66,66,128] -> Zcat[pix][256] bf16 =
// [zhi(128) | zlo(128)]. grid 2048 (8x8 pixels).
// ============================================================================
__global__ __launch_bounds__(256) void k_prem(const short* __restrict__ XrP,
    const short* __restrict__ wA, const float* __restrict__ bias,
    short* __restrict__ Zc) {
  __shared__ short sX[8192];  // 64 px * 128 sh, swizzled = 16 KB
  int blk = blockIdx.x;
  int bx = blk & 7, by = (blk >> 3) & 7, b = blk >> 6;
  int t = threadIdx.x, w = t >> 6, l = t & 63, lr = l & 15, g = l >> 4;
  for (int q = t; q < 1024; q += 256) {
    int p = q >> 4, seg = q & 15;
    int y = by * 8 + (p >> 3), x = bx * 8 + (p & 7);
    short8 v = *(const short8*)(XrP +
        ((b * 66 + y + 1) * 66 + x + 1) * 128 + seg * 8);
    *(short8*)((char*)sX + p * 256 + ((seg * 16) ^ ((p & 7) << 4))) = v;
  }
  __syncthreads();
  const short* pA0 = wA + (2 * w * 64 + l) * 8;
  const short* pA1 = pA0 + 512;
  f32x4 acc[2][4] = {};
#pragma unroll
  for (int kc = 0; kc < 4; ++kc) {
    short8 a0 = *(const short8*)(pA0 + kc * 4096);
    short8 a1 = *(const short8*)(pA1 + kc * 4096);
#pragma unroll
    for (int i = 0; i < 4; ++i) {
      int p = i * 16 + lr;
      short8 bv = *(const short8*)((const char*)sX + p * 256 +
                                   ((kc * 64 + g * 16) ^ ((p & 7) << 4)));
      acc[0][i] = MFMA(a0, bv, acc[0][i]);
      acc[1][i] = MFMA(a1, bv, acc[1][i]);
    }
  }
#pragma unroll
  for (int oi = 0; oi < 2; ++oi) {
    int o0 = (2 * w + oi) * 16 + 4 * g;
#pragma unroll
    for (int pt = 0; pt < 4; ++pt) {
      int p = pt * 16 + lr;
      int y = by * 8 + (p >> 3), x = bx * 8 + (p & 7);
      long pix = (long)(b * 64 + y) * 64 + x;
      short4v hv, lv;
#pragma unroll
      for (int r = 0; r < 4; ++r) {
        float v = acc[oi][pt][r] + bias[o0 + r];
        short hi = f2bf(v);
        hv[r] = hi;
        lv[r] = f2bf(v - bf2f(hi));
      }
      *(short4v*)(Zc + pix * 256 + o0) = hv;
      *(short4v*)(Zc + pix * 256 + 128 + o0) = lv;
    }
  }
}

// ============================================================================
// VQ MFMA v9 (async E-staging, 128 px): 128 px x 512 codes, 8 waves (512 thr),
// grid 1024. Wave w owns 64 codes -> acc[4][8] = 128 AGPR; A operands via
// global_load_lds slab. Z tile 64 KB LDS (XOR swizzle). Fused argmin + hist +
// loss + gather.
// ============================================================================
__global__ __launch_bounds__(512) void k_vqm9(const short* __restrict__ Zc,
    const short* __restrict__ Ec, const float* __restrict__ en,
    const float* __restrict__ emb, int* __restrict__ counts,
    float* __restrict__ partials, float* __restrict__ Q,
    short* __restrict__ QrP) {
  __shared__ short sZ[32768];  // 128 px * 256 sh, swizzled = 64 KB
  __shared__ short sE[16384];  // E slab: 8 wave-regions x 2048 sh = 32 KB
  __shared__ float sV[8][128];
  __shared__ int sC[8][128];
  __shared__ float sZn[128];
  __shared__ int sIdx[128];
  __shared__ int sHist[KC];
  int blk = blockIdx.x;
  long pix0 = (long)blk * 128;
  int t = threadIdx.x, w = t >> 6, l = t & 63, c16 = l & 15, g = (l >> 4) & 3;
  for (int e = t; e < KC; e += 512) sHist[e] = 0;

  // stage Z tile: swizzle inner-byte ^ ((pix&7)<<4)
  for (int q = t; q < 4096; q += 512) {
    int p = q >> 5, seg = q & 31;
    short8 v = *(const short8*)(Zc + (pix0 + p) * 256 + seg * 8);
    *(short8*)((char*)sZ + p * 512 + ((seg * 16) ^ ((p & 7) << 4))) = v;
  }
  __syncthreads();

  // ||z||^2 per pixel from LDS: 4 threads/pixel, each 32 dims (128 px)
  {
    int pz = t >> 2, seg4 = t & 3;
    const char* zb = (const char*)sZ + pz * 512;
    int swp = (pz & 7) << 4;
    float s = 0.f;
#pragma unroll
    for (int qq = 0; qq < 4; ++qq) {
      int ih = seg4 * 64 + 16 * qq;  // zh inner byte
      short8 h8 = *(const short8*)(zb + (ih ^ swp));
      short8 l8 = *(const short8*)(zb + ((ih + 256) ^ swp));
#pragma unroll
      for (int j = 0; j < 8; ++j) {
        float zv = bf2f(h8[j]) + bf2f(l8[j]);
        s = fmaf(zv, zv, s);
      }
    }
    s += __shfl_xor(s, 1);
    s += __shfl_xor(s, 2);
    if (seg4 == 0) sZn[pz] = s;
  }

  // GEMM: 12 K-steps of 32; wave-local async E staging; 8 pixel-tiles.
  int sw = (c16 & 7) << 4;
  int zrow = c16 * 512;
  short* sEw = sE + w * 2048;                   // wave-uniform LDS base
  const short* gEw = Ec + w * 2048 + l * 8;     // per-lane global src
  f32x4 acc[4][8] = {};
  for (int kc = 0; kc < 12; ++kc) {
    if (kc) asm volatile("s_waitcnt lgkmcnt(0)" ::: "memory");
#pragma unroll
    for (int i = 0; i < 4; ++i)
      GLOAD_LDS16(gEw + kc * 16384 + i * 512, sEw + i * 512);
    asm volatile("s_waitcnt vmcnt(0)" ::: "memory");
    int koff = kc < 8 ? kc : kc - 8;
    int inn = ((koff * 64 + g * 16) ^ sw);
    const char* zb = (const char*)sZ + zrow + inn;
    short8 a0 = *(const short8*)(sEw + l * 8);
    short8 a1 = *(const short8*)(sEw + 512 + l * 8);
    short8 a2 = *(const short8*)(sEw + 1024 + l * 8);
    short8 a3 = *(const short8*)(sEw + 1536 + l * 8);
#pragma unroll
    for (int pt = 0; pt < 8; ++pt) {
      short8 bb = *(const short8*)(zb + pt * 8192);
      acc[0][pt] = MFMA(a0, bb, acc[0][pt]);
      acc[1][pt] = MFMA(a1, bb, acc[1][pt]);
      acc[2][pt] = MFMA(a2, bb, acc[2][pt]);
      acc[3][pt] = MFMA(a3, bb, acc[3][pt]);
    }
  }
  // running argmin over the wave's 64 codes (codes ascend: ct, r)
  float bvv[8];
  int bcc[8];
#pragma unroll
  for (int pt = 0; pt < 8; ++pt) { bvv[pt] = 3.4e38f; bcc[pt] = 0; }
#pragma unroll
  for (int ct = 0; ct < 4; ++ct) {
    f32x4 en4 = *(const f32x4*)(en + w * 64 + ct * 16 + 4 * g);
#pragma unroll
    for (int pt = 0; pt < 8; ++pt) {
#pragma unroll
      for (int r = 0; r < 4; ++r) {
        float d = en4[r] - 2.f * acc[ct][pt][r];
        int code = w * 64 + ct * 16 + 4 * g + r;
        if (d < bvv[pt]) { bvv[pt] = d; bcc[pt] = code; }
      }
    }
  }
  // cross-lane reduce (over g) per pixel
#pragma unroll
  for (int pt = 0; pt < 8; ++pt) {
    float bv = bvv[pt];
    int bc = bcc[pt];
#pragma unroll
    for (int m = 16; m <= 32; m <<= 1) {
      float ov = __shfl_xor(bv, m);
      int oc = __shfl_xor(bc, m);
      if (ov < bv || (ov == bv && oc < bc)) { bv = ov; bc = oc; }
    }
    if (g == 0) {
      sV[w][pt * 16 + c16] = bv;
      sC[w][pt * 16 + c16] = bc;
    }
  }
  __syncthreads();
  if (t < 128) {
    float bv = sV[0][t];
    int bc = sC[0][t];
#pragma unroll
    for (int w2 = 1; w2 < 8; ++w2) {
      float v = sV[w2][t];
      int c = sC[w2][t];
      if (v < bv || (v == bv && c < bc)) { bv = v; bc = c; }
    }
    sIdx[t] = bc;
    atomicAdd(&sHist[bc], 1);
    sV[0][t] = bv + sZn[t];
  }
  __syncthreads();
  if (t < 64) {
    float ls = sV[0][t] + sV[0][t + 64];
#pragma unroll
    for (int m = 32; m >= 1; m >>= 1) ls += __shfl_xor(ls, m);
    if (t == 0) partials[blk] = ls;
  }
  for (int e = t; e < KC; e += 512) {
    int c = sHist[e];
    if (c) atomicAdd(&counts[e], c);
  }
  // fused gather: Q = emb[idx] f32 (overwrites this block's Zc bytes),
  // QrP = relu bf16 (padded layout)
  for (int e = t; e < 4096; e += 512) {
    int p = e >> 5, d4 = (e & 31) << 2;
    int c = sIdx[p];
    f32x4 q = *(const f32x4*)(emb + c * DD + d4);
    *(f32x4*)(Q + (pix0 + p) * DD + d4) = q;
    short4v sv;
#pragma unroll
    for (int r = 0; r < 4; ++r) sv[r] = f2bf(fmaxf(q[r], 0.f));
    long pixg = pix0 + p;
    int xx = (int)(pixg & 63), yy = (int)((pixg >> 6) & 63),
        bb = (int)(pixg >> 12);
    *(short4v*)(QrP + (((long)(bb * 66 + yy + 1)) * 66 + xx + 1) * 128 + d4) =
        sv;
  }
}

// ============================================================================
// tconv1 MFMA v2 (LDS-staged): QrP[66,66,128] -> T1[130,130,64] bf16 relu
// grid 2048 = 32 b x 8 tyt x 8 txt
// ============================================================================
__global__ __launch_bounds__(256) void k_tconv1m(const short* __restrict__ QrP,
    const short* __restrict__ wA, const float* __restrict__ bias,
    short* __restrict__ T1) {
  __shared__ short sX[13600];  // 100 pixels x 136 shorts
  int blk = blockIdx.x;
  int txt = blk & 7, tyt = (blk >> 3) & 7, b = blk >> 6;
  int my0 = tyt * 8, mx0 = txt * 8;
  int t = threadIdx.x;
  for (int q = t; q < 1600; q += 256) {
    int p = q >> 4, seg = q & 15;
    int iy = p / 10, ix = p - iy * 10;
    short8 v = *(const short8*)(QrP +
        ((b * 66 + my0 + iy) * 66 + mx0 + ix) * 128 + seg * 8);
    *(short8*)((char*)sX + p * 272 + seg * 16) = v;
  }
  __syncthreads();
  int w = t >> 6, l = t & 63, lr = l & 15, g = l >> 4;
  int pyr = w >> 1, pxr = w & 1;
  int Bb[4];
#pragma unroll
  for (int nt = 0; nt < 4; ++nt) {
    int p = nt * 16 + lr;
    int my = p >> 3, mx = p & 7;
    Bb[nt] = ((my + pyr + 1) * 10 + (mx + pxr + 1)) * 272 + g * 16;
  }
  const short* pAw = wA + w * 32768 + l * 8;
  f32x4 acc[4][4] = {};
  short8 a[4], bfr[4], na[4], nb[4];
#pragma unroll
  for (int ot = 0; ot < 4; ++ot) a[ot] = *(const short8*)(pAw + ot * 512);
#pragma unroll
  for (int nt = 0; nt < 4; ++nt)
    bfr[nt] = *(const short8*)((const char*)sX + Bb[nt]);
  for (int kc = 0; kc < 15; ++kc) {
    int nk = kc + 1;
    int tt = nk >> 2, dy = tt >> 1, dx = tt & 1;
    int off = -(dy * 10 + dx) * 272 + (nk & 3) * 64;
#pragma unroll
    for (int ot = 0; ot < 4; ++ot)
      na[ot] = *(const short8*)(pAw + nk * 2048 + ot * 512);
#pragma unroll
    for (int nt = 0; nt < 4; ++nt)
      nb[nt] = *(const short8*)((const char*)sX + Bb[nt] + off);
#pragma unroll
    for (int ot = 0; ot < 4; ++ot)
#pragma unroll
      for (int nt = 0; nt < 4; ++nt)
        acc[ot][nt] = MFMA(a[ot], bfr[nt], acc[ot][nt]);
#pragma unroll
    for (int ot = 0; ot < 4; ++ot) a[ot] = na[ot];
#pragma unroll
    for (int nt = 0; nt < 4; ++nt) bfr[nt] = nb[nt];
  }
#pragma unroll
  for (int ot = 0; ot < 4; ++ot)
#pragma unroll
    for (int nt = 0; nt < 4; ++nt)
      acc[ot][nt] = MFMA(a[ot], bfr[nt], acc[ot][nt]);
#pragma unroll
  for (int ot = 0; ot < 4; ++ot) {
    int o0 = ot * 16 + 4 * g;
    f32x4 b4 = *(const f32x4*)(bias + o0);
#pragma unroll
    for (int nt = 0; nt < 4; ++nt) {
      int p = nt * 16 + lr;
      int my = my0 + (p >> 3), mx = mx0 + (p & 7);
      int oy = 2 * my + pyr, ox = 2 * mx + pxr;
      short4v sv;
#pragma unroll
      for (int r = 0; r < 4; ++r)
        sv[r] = f2bf(fmaxf(acc[ot][nt][r] + b4[r], 0.f));
      *(short4v*)(T1 + ((b * 130 + oy + 1) * 130 + ox + 1) * 64 + o0) = sv;
    }
  }
}

// ============================================================================
// tconv2 MFMA v2: T1[130,130,64] bf16 -> x_recon[32,256,256] f32.
// Factorization: each (input px, tap) pair feeds exactly ONE output, so
// compute c[tap][px] = W^T * T1 via MFMA (M=16 taps, N=112 px, K=128 with
// exact [w_hi|w_lo] bf16 split of the f32 weights), then a 4-entry LDS
// gather per output. Replaces the serial 256-deep scalar fmaf chain.
// Input tile 10x10x64 at 144-B px stride (aligned, conflict-free).
// grid 8192 = 32 b x 16 ty x 16 tx.
// ============================================================================
__global__ __launch_bounds__(256) void k_tconv2m(const short* __restrict__ T1,
    const float* __restrict__ w, const float* __restrict__ bias,
    float* __restrict__ xrec) {
  __shared__ short sT[112 * 72];  // 112 px * 144 B = 16,128 B
  __shared__ float sW[1024];
  __shared__ float sC[112 * 20];  // px stride 80 B (16-B aligned) = 8,960 B
  int blk = blockIdx.x;
  int tx = blk & 15, ty = (blk >> 4) & 15, b = blk >> 8;
  int t = threadIdx.x;
  for (int e = t; e < 1024; e += 256) sW[e] = w[e];
  // stage T1 10x10 px tile (rows ty*8..ty*8+9, cols tx*8..tx*8+9; borders of
  // T1 are zeroed by k_prep and never overwritten)
  for (int q = t; q < 800; q += 256) {
    int p = q >> 3, seg = q & 7;
    int iy = p / 10, ix = p - iy * 10;
    short8 v = *(const short8*)(T1 +
        (((long)b * 130 + ty * 8 + iy) * 130 + tx * 8 + ix) * 64 + seg * 8);
    *(short8*)((char*)sT + p * 144 + seg * 16) = v;
  }
  __syncthreads();
  int wv = t >> 6, l = t & 63, lr = l & 15, g = l >> 4;
  // build A-frags: 16 taps x K=128 ([w_hi | w_lo]); lane row = tap = lr
  short8 af[4];
#pragma unroll
  for (int kc = 0; kc < 4; ++kc) {
#pragma unroll
    for (int j = 0; j < 8; ++j) {
      int k = kc * 32 + 8 * g + j;
      float val = sW[(k & 63) * 16 + lr];
      short hi = f2bf(val);
      af[kc][j] = (k < 64) ? hi : f2bf(val - bf2f(hi));
    }
  }
  // GEMM: wave wv computes pixel-tiles {wv, wv+4}; tile 7 unused
#pragma unroll
  for (int ti = 0; ti < 2; ++ti) {
    int tile = wv + 4 * ti;
    if (tile < 7) {
      f32x4 acc = {};
#pragma unroll
      for (int kc = 0; kc < 4; ++kc) {
        short8 bf = *(const short8*)((const char*)sT +
            (tile * 16 + lr) * 144 + ((kc & 1) * 64 + g * 16));
        acc = MFMA(af[kc], bf, acc);
      }
      *(f32x4*)(sC + (tile * 16 + lr) * 20 + g * 4) = acc;
    }
  }
  __syncthreads();
  // epilogue: one output px per thread; 4 c-entries + bias
  int row = t >> 4, col = t & 15;
  int pyr = row & 1, pxr = col & 1;
  int ml = row >> 1, nl = col >> 1;
  int kye = 1 - pyr, kxe = 1 - pxr;
  float acc = bias[0];
#pragma unroll
  for (int dy = 0; dy < 2; ++dy)
#pragma unroll
    for (int dx = 0; dx < 2; ++dx) {
      int px = (ml + pyr - dy + 1) * 10 + (nl + pxr - dx + 1);
      int tap = (kye + 2 * dy) * 4 + (kxe + 2 * dx);
      acc += sC[px * 20 + tap];
    }
  int oy = ty * 16 + row, ox = tx * 16 + col;
  xrec[((long)b * 256 + oy) * 256 + ox] = acc;
}

// ============================================================================
// finalize: loss from 1024 partials; perplexity from counts
// ============================================================================
__global__ __launch_bounds__(256) void k_final(const float* __restrict__ partials,
    const int* __restrict__ counts, float* __restrict__ out) {
  int t = threadIdx.x;
  float s = 0.f;
  for (int i = t; i < 1024; i += 256) s += partials[i];
#pragma unroll
  for (int m = 32; m >= 1; m >>= 1) s += __shfl_xor(s, m);
  __shared__ float sr[4];
  if ((t & 63) == 0) sr[t >> 6] = s;
  __syncthreads();
  if (t == 0) {
    float tot = sr[0] + sr[1] + sr[2] + sr[3];
    out[0] = 1.25f * tot / 16777216.0f;
  }
  float h = 0.f;
  for (int c = t; c < KC; c += 256) {
    float avg = (float)counts[c] / 131072.0f;
    h += avg * logf(avg + 1e-10f);
  }
#pragma unroll
  for (int m = 32; m >= 1; m >>= 1) h += __shfl_xor(h, m);
  __shared__ float sr2[4];
  if ((t & 63) == 0) sr2[t >> 6] = h;
  __syncthreads();
  if (t == 0) out[1 + 32 * 256 * 256] = expf(-(sr2[0] + sr2[1] + sr2[2] + sr2[3]));
}

// ============================================================================
extern "C" void kernel_launch(void* const* d_in, const int* in_sizes, int n_in,
                              void* d_out, int out_size, void* d_ws, size_t ws_size,
                              hipStream_t stream) {
  const float* x    = (const float*)d_in[0];
  const float* c1w  = (const float*)d_in[1];
  const float* c1b  = (const float*)d_in[2];
  const float* c2w  = (const float*)d_in[3];
  const float* c2b  = (const float*)d_in[4];
  const float* r1w3 = (const float*)d_in[5];
  const float* r1w1 = (const float*)d_in[6];
  const float* r2w3 = (const float*)d_in[7];
  const float* r2w1 = (const float*)d_in[8];
  const float* prew = (const float*)d_in[9];
  const float* preb = (const float*)d_in[10];
  const float* emb  = (const float*)d_in[11];
  const float* d1w3 = (const float*)d_in[12];
  const float* d1w1 = (const float*)d_in[13];
  const float* d2w3 = (const float*)d_in[14];
  const float* d2w1 = (const float*)d_in[15];
  const float* t1w  = (const float*)d_in[16];
  const float* t1b  = (const float*)d_in[17];
  const float* t2w  = (const float*)d_in[18];
  const float* t2b  = (const float*)d_in[19];
  float* out = (float*)d_out;

  char* ws = (char*)d_ws;
  short* buf0 = (short*)(ws);                      // A1 / T1 : 69,222,400 B
  float* bufX = (float*)(ws + 69222400);           // Xf / Zcat / Q : 67,108,864 B
  short* bufR = (short*)(ws + 136331264);          // XrP / QrP : 35,684,352 B
  short* Hr   = (short*)(ws + 172015616);          // 8,388,608 B -> ends 180404224
  int*   counts = (int*)(ws + 180928512);          // 2,048 B
  float* partials = (float*)(ws + 180930560);      // 8,192 B
  float* en   = (float*)(ws + 180938752);          // 2,048 B
  short* wAc2 = (short*)(ws + 180940800);          // 262,144 B
  short* wAr3 = (short*)(ws + 181202944);          // 294,912 B
  short* wAr1 = (short*)(ws + 181497856);          // 32,768 B
  short* wApre= (short*)(ws + 181530624);          // 32,768 B
  short* wAt1 = (short*)(ws + 181563392);          // 262,144 B
  short* Ecat = (short*)(ws + 181825536);          // 393,216 B -> ends 182,218,752

  short* Zcat = (short*)bufX;  // 67,108,864 B (Xf dead after enc res1addm#2;
                               // Q gather overwrites Zcat block-locally)

  short* wAr3_e1 = wAr3;
  short* wAr3_e2 = wAr3 + 36864;
  short* wAr3_d1 = wAr3 + 2 * 36864;
  short* wAr3_d2 = wAr3 + 3 * 36864;
  short* wAr1_e1 = wAr1;
  short* wAr1_e2 = wAr1 + 4096;
  short* wAr1_d1 = wAr1 + 2 * 4096;
  short* wAr1_d2 = wAr1 + 3 * 4096;

  k_prep <<<2881, 256, 0, stream>>>(c2w, r1w3, r2w3, d1w3, d2w3,
                                    r1w1, r2w1, d1w1, d2w1, prew, t1w, emb,
                                    wAc2, wAr3, wAr1, wApre, wAt1, Ecat,
                                    en, buf0, bufR, counts);

  k_conv1   <<<4096, 256, 0, stream>>>(x, c1w, c1b, buf0);
  k_conv2m  <<<2048, 256, 0, stream>>>(buf0, wAc2, c2b, bufX, bufR);
  k_res3m   <<<1024, 256, 0, stream>>>(bufR, wAr3_e1, Hr);
  k_res1addm<<<2048, 256, 0, stream>>>(Hr, wAr1_e1, bufX, bufR);
  k_res3m   <<<1024, 256, 0, stream>>>(bufR, wAr3_e2, Hr);
  k_res1addm<<<2048, 256, 0, stream>>>(Hr, wAr1_e2, bufX, bufR);
  k_prem    <<<2048, 256, 0, stream>>>(bufR, wApre, preb, Zcat);
  k_vqm9    <<<1024, 512, 0, stream>>>(Zcat, Ecat, en, emb, counts, partials,
                                       bufX, bufR);
  k_res3m   <<<1024, 256, 0, stream>>>(bufR, wAr3_d1, Hr);
  k_res1addm<<<2048, 256, 0, stream>>>(Hr, wAr1_d1, bufX, bufR);
  k_res3m   <<<1024, 256, 0, stream>>>(bufR, wAr3_d2, Hr);
  k_res1addm<<<2048, 256, 0, stream>>>(Hr, wAr1_d2, bufX, bufR);
  k_tconv1m <<<2048, 256, 0, stream>>>(bufR, wAt1, t1b, buf0);
  k_tconv2m <<<8192, 256, 0, stream>>>(buf0, t2w, t2b, out + 1);
  k_final   <<<1, 256, 0, stream>>>(partials, counts, out);
}